// Round 21
// baseline (5634.615 us; speedup 1.0000x reference)
//
#include <hip/hip_runtime.h>
#include <hip/hip_bf16.h>
#include <stdint.h>
#include <string.h>

// ---------------------------------------------------------------------------
// Problem constants
// ---------------------------------------------------------------------------
#define NB   8
#define NV   2048
#define NN   20      // NEIGHBOR_NUM
#define SUP  7       // SUPPORT
#define K0   32
#define C1   64
#define C2   256
#define NV2  256     // vertices after pooling 1
#define NP2  16      // vertices after pooling 2

// ---------------------------------------------------------------------------
// Permutations: PCG64 + masked rejection + subtract-mix SeedSequence —
// bit-proven identical to the container's np.random.default_rng (R4≡R5).
// ---------------------------------------------------------------------------
typedef unsigned __int128 u128;

struct CPcg { u128 state; u128 inc; bool has32; uint32_t cached; };

constexpr u128 PCG_MULT = (((u128)2549297995355413924ULL) << 64) | 4865540595714422341ULL;

constexpr uint64_t c_rotr64(uint64_t v, unsigned r) {
    return (v >> (r & 63u)) | (v << ((64u - r) & 63u));
}
constexpr uint64_t pcg_next64(CPcg& g) {
    g.state = g.state * PCG_MULT + g.inc;
    uint64_t hi = (uint64_t)(g.state >> 64);
    uint64_t lo = (uint64_t)g.state;
    return c_rotr64(hi ^ lo, (unsigned)(hi >> 58));
}
constexpr uint32_t pcg_next32(CPcg& g) {
    if (g.has32) { g.has32 = false; return g.cached; }
    uint64_t n = pcg_next64(g);
    g.has32 = true;
    g.cached = (uint32_t)(n >> 32);
    return (uint32_t)n;
}
constexpr uint64_t rand_interval(CPcg& g, uint64_t mx) {
    if (mx == 0) return 0;
    uint64_t mask = mx;
    mask |= mask >> 1; mask |= mask >> 2; mask |= mask >> 4;
    mask |= mask >> 8; mask |= mask >> 16; mask |= mask >> 32;
    uint64_t v = 0;
    while ((v = ((uint64_t)pcg_next32(g) & mask)) > mx) {
    }
    return v;
}
constexpr uint32_t hashmix(uint32_t value, uint32_t& hc) {
    value ^= hc; hc *= 0x931e8875u; value *= hc; value ^= value >> 16; return value;
}
constexpr uint32_t mixpool(uint32_t x, uint32_t y) {
    uint32_t r = (x * 0xca01f9ddu) - (y * 0x4973f715u);
    r ^= r >> 16; return r;
}
constexpr CPcg make_rng(uint32_t entropy) {
    uint32_t pool[4] = {0, 0, 0, 0};
    uint32_t hc = 0x43b0d7e5u;
    for (int i = 0; i < 4; i++) {
        uint32_t v = (i == 0) ? entropy : 0u;
        pool[i] = hashmix(v, hc);
    }
    for (int isrc = 0; isrc < 4; isrc++)
        for (int idst = 0; idst < 4; idst++)
            if (isrc != idst) pool[idst] = mixpool(pool[idst], hashmix(pool[isrc], hc));
    uint32_t w[8] = {};
    uint32_t hb = 0x8b51f9ddu;
    for (int i = 0; i < 8; i++) {
        uint32_t dv = pool[i & 3];
        dv ^= hb; hb *= 0x58f38dedu; dv *= hb; dv ^= dv >> 16; w[i] = dv;
    }
    uint64_t sd[4] = {};
    for (int k = 0; k < 4; k++) sd[k] = (uint64_t)w[2 * k] | ((uint64_t)w[2 * k + 1] << 32);
    u128 s = (((u128)sd[0]) << 64) | sd[1];
    u128 iq = (((u128)sd[2]) << 64) | sd[3];
    CPcg g{};
    g.state = 0;
    g.inc = (iq << 1) | 1;
    g.state = g.state * PCG_MULT + g.inc;
    g.state += s;
    g.state = g.state * PCG_MULT + g.inc;
    g.has32 = false; g.cached = 0;
    return g;
}

struct PermOut { int p1[256]; int p2[16]; };

constexpr PermOut compute_perms() {
    PermOut o{};
    {
        CPcg g = make_rng(1u);
        int arr[2048] = {};
        for (int i = 0; i < 2048; i++) arr[i] = i;
        for (int i = 2047; i >= 1; i--) {
            int j = (int)rand_interval(g, (uint64_t)i);
            int t = arr[i]; arr[i] = arr[j]; arr[j] = t;
        }
        for (int i = 0; i < 256; i++) o.p1[i] = arr[i];
    }
    {
        CPcg g = make_rng(2u);
        int arr[256] = {};
        for (int i = 0; i < 256; i++) arr[i] = i;
        for (int i = 255; i >= 1; i--) {
            int j = (int)rand_interval(g, (uint64_t)i);
            int t = arr[i]; arr[i] = arr[j]; arr[j] = t;
        }
        for (int i = 0; i < 16; i++) o.p2[i] = arr[i];
    }
    return o;
}

struct PermArg1 { int v[256]; };
struct PermArg2 { int v[16]; };

// ---------------------------------------------------------------------------
// K0: v2 (outputs[0]) = verts[:, p1[p2[j]], :] — FLOAT32 output.
// ---------------------------------------------------------------------------
__global__ __launch_bounds__(384) void v2_kernel(const float* __restrict__ verts,
                                                 float* __restrict__ out,
                                                 PermArg2 cidx) {
    int t = threadIdx.x;  // 0..383
    if (t < NB * NP2 * 3) {
        int b = t / (NP2 * 3);
        int rem = t - b * (NP2 * 3);
        int j = rem / 3;
        int c = rem - j * 3;
        out[t] = verts[(b * NV + cidx.v[j]) * 3 + c];
    }
}

// ---------------------------------------------------------------------------
// K1: KNN over full vertex set (N=2048). 4 threads/row, top-20 + 4-way merge.
// ---------------------------------------------------------------------------
__global__ __launch_bounds__(256) void knn1_kernel(const float* __restrict__ verts,
                                                   int* __restrict__ nbr) {
    __shared__ float sv[NV * 3];
    __shared__ float sd[256 * NN];
    __shared__ int   si[256 * NN];

    int b = blockIdx.x >> 5;
    int rbase = (blockIdx.x & 31) * 64;
    const float* vb = verts + b * NV * 3;
    for (int t = threadIdx.x; t < NV * 3; t += 256) sv[t] = vb[t];

    int r = threadIdx.x >> 2;
    int q = threadIdx.x & 3;
    int i = rbase + r;

    float* ld = sd + threadIdx.x * NN;
    int*   li = si + threadIdx.x * NN;
    for (int t = 0; t < NN; t++) { ld[t] = 3.4e38f; li[t] = 0x7fffffff; }
    __syncthreads();

    float vx = sv[i * 3 + 0], vy = sv[i * 3 + 1], vz = sv[i * 3 + 2];
    float qi = vx * vx + vy * vy + vz * vz;

    float thr_d = 3.4e38f;
    int   thr_i = 0x7fffffff;

    for (int jj = 0; jj < 512; jj++) {
        int j = q * 512 + ((jj + q * 8) & 511);
        float xj = sv[j * 3 + 0], yj = sv[j * 3 + 1], zj = sv[j * 3 + 2];
        float inner = vx * xj + vy * yj + vz * zj;
        float qj = xj * xj + yj * yj + zj * zj;
        float dist = (-2.0f * inner + qi) + qj;
        bool acc = (dist < thr_d) || (dist == thr_d && j < thr_i);
        if (j != i && acc) {
            int p = NN - 1;
            while (p > 0 && (ld[p - 1] > dist || (ld[p - 1] == dist && li[p - 1] > j))) {
                ld[p] = ld[p - 1]; li[p] = li[p - 1]; p--;
            }
            ld[p] = dist; li[p] = j;
            thr_d = ld[NN - 1]; thr_i = li[NN - 1];
        }
    }
    __syncthreads();

    if (threadIdx.x < 64) {
        int r2 = threadIdx.x;
        int base = r2 * 4;
        int p[4] = {0, 0, 0, 0};
        int* dst = nbr + (b * NV + rbase + r2) * NN;
        for (int t = 0; t < NN; t++) {
            float bd = 3.5e38f; int bi = 0x7fffffff; int bq = 0;
            #pragma unroll
            for (int qq = 0; qq < 4; qq++) {
                float d = sd[(base + qq) * NN + p[qq]];
                int  ix = si[(base + qq) * NN + p[qq]];
                if (d < bd || (d == bd && ix < bi)) { bd = d; bi = ix; bq = qq; }
            }
            dst[t] = bi;
            p[bq]++;
        }
    }
}

// ---------------------------------------------------------------------------
// K6: KNN over pooled vertices (N=256), one thread per row
// ---------------------------------------------------------------------------
__global__ __launch_bounds__(256) void knn2_kernel(const float* __restrict__ v1,
                                                   int* __restrict__ nbr2) {
    __shared__ float sv[NV2 * 3];
    __shared__ float sd[256 * NN];
    __shared__ int   si[256 * NN];
    int b = blockIdx.x;
    for (int t = threadIdx.x; t < NV2 * 3; t += 256) sv[t] = v1[b * NV2 * 3 + t];
    int i = threadIdx.x;
    float* ld = sd + i * NN;
    int*   li = si + i * NN;
    for (int t = 0; t < NN; t++) { ld[t] = 3.4e38f; li[t] = 0x7fffffff; }
    __syncthreads();

    float vx = sv[i * 3 + 0], vy = sv[i * 3 + 1], vz = sv[i * 3 + 2];
    float qi = vx * vx + vy * vy + vz * vz;
    float thr_d = 3.4e38f;
    int   thr_i = 0x7fffffff;
    for (int j = 0; j < NV2; j++) {
        float xj = sv[j * 3 + 0], yj = sv[j * 3 + 1], zj = sv[j * 3 + 2];
        float inner = vx * xj + vy * yj + vz * zj;
        float qj = xj * xj + yj * yj + zj * zj;
        float dist = (-2.0f * inner + qi) + qj;
        bool acc = (dist < thr_d) || (dist == thr_d && j < thr_i);
        if (j != i && acc) {
            int p = NN - 1;
            while (p > 0 && (ld[p - 1] > dist || (ld[p - 1] == dist && li[p - 1] > j))) {
                ld[p] = ld[p - 1]; li[p] = li[p - 1]; p--;
            }
            ld[p] = dist; li[p] = j;
            thr_d = ld[NN - 1]; thr_i = li[NN - 1];
        }
    }
    int* dst = nbr2 + (b * NV2 + i) * NN;
    for (int t = 0; t < NN; t++) dst[t] = li[t];
}

// ---------------------------------------------------------------------------
// K2: operator3d + relu -> fm0 (8,2048,32). One thread per vertex.
// ---------------------------------------------------------------------------
__global__ __launch_bounds__(256) void op3d_kernel(const float* __restrict__ verts,
                                                   const int* __restrict__ nbr,
                                                   const float* __restrict__ w0w,
                                                   const float* __restrict__ w0d,
                                                   float* __restrict__ fm0) {
    __shared__ float swd[3 * SUP * K0];
    __shared__ float sww[SUP * K0];
    for (int t = threadIdx.x; t < 3 * SUP * K0; t += 256) swd[t] = w0d[t];
    for (int t = threadIdx.x; t < SUP * K0; t += 256) sww[t] = w0w[t];
    __syncthreads();

    int gid = blockIdx.x * 256 + threadIdx.x;
    int b = gid >> 11, v = gid & (NV - 1);
    const float* vb = verts + b * NV * 3;
    float vx = vb[v * 3], vy = vb[v * 3 + 1], vz = vb[v * 3 + 2];

    const int* nb = nbr + gid * NN;
    float dx[NN], dy[NN], dz[NN];
    #pragma unroll
    for (int n = 0; n < NN; n++) {
        int j = nb[n];
        dx[n] = vb[j * 3 + 0] - vx;
        dy[n] = vb[j * 3 + 1] - vy;
        dz[n] = vb[j * 3 + 2] - vz;
    }
    float* out = fm0 + gid * K0;
    #pragma unroll 1
    for (int k = 0; k < K0; k++) {
        float acc = 0.f;
        #pragma unroll
        for (int s = 0; s < SUP; s++) {
            float w0 = swd[0 * 224 + s * K0 + k];
            float w1 = swd[1 * 224 + s * K0 + k];
            float w2 = swd[2 * 224 + s * K0 + k];
            float m = 0.f;
            #pragma unroll
            for (int n = 0; n < NN; n++) {
                float t = dx[n] * w0 + dy[n] * w1 + dz[n] * w2;
                t = fmaxf(t, 0.f);
                m = fmaxf(m, t);
            }
            acc += m * sww[s * K0 + k];
        }
        out[k] = fmaxf(acc, 0.f);
    }
}

// ---------------------------------------------------------------------------
// K4: FUSED operator_nd #1 (+relu) -> fm1 (8,2048,64).
// ---------------------------------------------------------------------------
__global__ __launch_bounds__(256, 2) void opnd1_fused(const float* __restrict__ verts,
                                                      const int* __restrict__ nbr,
                                                      const float* __restrict__ fm0,
                                                      const float* __restrict__ w1w,
                                                      const float* __restrict__ w1b,
                                                      const float* __restrict__ w1d,
                                                      float* __restrict__ fm1) {
    __shared__ float swd[3 * SUP * C1];
    __shared__ float sm[4][21][K0];
    for (int t = threadIdx.x; t < 3 * SUP * C1; t += 256) swd[t] = w1d[t];

    int wid = threadIdx.x >> 6, lane = threadIdx.x & 63;
    int vtx = blockIdx.x * 4 + wid;
    int b = vtx >> 11, v = vtx & (NV - 1);
    const float* vb = verts + b * NV * 3;
    const int* nb = nbr + vtx * NN;
    const float* f0b = fm0 + (size_t)b * NV * K0;

    for (int t = lane; t < 21 * K0; t += 64) {
        int row = t >> 5, k = t & 31;
        int j = (row < NN) ? nb[row] : v;
        sm[wid][row][k] = f0b[j * K0 + k];
    }
    float vx = vb[v * 3], vy = vb[v * 3 + 1], vz = vb[v * 3 + 2];
    float dx[NN], dy[NN], dz[NN];
    #pragma unroll
    for (int n = 0; n < NN; n++) {
        int j = nb[n];
        dx[n] = vb[j * 3 + 0] - vx;
        dy[n] = vb[j * 3 + 1] - vy;
        dz[n] = vb[j * 3 + 2] - vz;
    }
    __syncthreads();

    float fcen = w1b[lane];
    {
        float wc[K0];
        #pragma unroll
        for (int k = 0; k < K0; k++) wc[k] = w1w[k * (8 * C1) + lane];
        #pragma unroll
        for (int k = 0; k < K0; k++) fcen += sm[wid][20][k] * wc[k];
    }
    float total = 0.f;
    #pragma unroll 1
    for (int s = 0; s < SUP; s++) {
        float wc[K0];
        #pragma unroll
        for (int k = 0; k < K0; k++) wc[k] = w1w[k * (8 * C1) + C1 + s * C1 + lane];
        float bs = w1b[C1 + s * C1 + lane];
        float w0 = swd[0 * (SUP * C1) + s * C1 + lane];
        float w1 = swd[1 * (SUP * C1) + s * C1 + lane];
        float w2 = swd[2 * (SUP * C1) + s * C1 + lane];
        float m = -3.4e38f;
        #pragma unroll
        for (int n = 0; n < NN; n++) {
            float fs = bs;
            #pragma unroll
            for (int k = 0; k < K0; k++) fs += sm[wid][n][k] * wc[k];
            float th = fmaxf(dx[n] * w0 + dy[n] * w1 + dz[n] * w2, 0.f);
            m = fmaxf(m, th * fs);
        }
        total += m;
    }
    fm1[vtx * C1 + lane] = fmaxf(fcen + total, 0.f);
}

// ---------------------------------------------------------------------------
// K8: FUSED operator_nd #2 (+relu) -> fm2 (8,256,256).
// ---------------------------------------------------------------------------
__global__ __launch_bounds__(256, 2) void opnd2_fused(const float* __restrict__ v1,
                                                      const int* __restrict__ nbr2,
                                                      const float* __restrict__ fm1p,
                                                      const float* __restrict__ w2w,
                                                      const float* __restrict__ w2b,
                                                      const float* __restrict__ w2d,
                                                      float* __restrict__ fm2) {
    __shared__ float swd[3 * SUP * C2];
    __shared__ float sm[4][21][C1];
    for (int t = threadIdx.x; t < 3 * SUP * C2; t += 256) swd[t] = w2d[t];

    int wid = threadIdx.x >> 6, lane = threadIdx.x & 63;
    int vtx = blockIdx.x * 4 + wid;
    int b = vtx >> 8, v = vtx & (NV2 - 1);
    const float* vb = v1 + b * NV2 * 3;
    const int* nb = nbr2 + vtx * NN;
    const float* f1b = fm1p + (size_t)b * NV2 * C1;

    for (int t = lane; t < 21 * C1; t += 64) {
        int row = t >> 6, k = t & 63;
        int j = (row < NN) ? nb[row] : v;
        sm[wid][row][k] = f1b[j * C1 + k];
    }
    float vx = vb[v * 3], vy = vb[v * 3 + 1], vz = vb[v * 3 + 2];
    float dx[NN], dy[NN], dz[NN];
    #pragma unroll
    for (int n = 0; n < NN; n++) {
        int j = nb[n];
        dx[n] = vb[j * 3 + 0] - vx;
        dy[n] = vb[j * 3 + 1] - vy;
        dz[n] = vb[j * 3 + 2] - vz;
    }
    __syncthreads();

    #pragma unroll 1
    for (int jj = 0; jj < 4; jj++) {
        int cj = jj * 64 + lane;
        float fcen = w2b[cj];
        #pragma unroll 1
        for (int kt = 0; kt < C1; kt += 32) {
            float wc[32];
            #pragma unroll
            for (int k = 0; k < 32; k++) wc[k] = w2w[(kt + k) * (8 * C2) + cj];
            #pragma unroll
            for (int k = 0; k < 32; k++) fcen += sm[wid][20][kt + k] * wc[k];
        }
        float total = 0.f;
        #pragma unroll 1
        for (int s = 0; s < SUP; s++) {
            float bs = w2b[C2 + s * C2 + cj];
            float fs[NN];
            #pragma unroll
            for (int n = 0; n < NN; n++) fs[n] = bs;
            #pragma unroll 1
            for (int kt = 0; kt < C1; kt += 32) {
                float wc[32];
                #pragma unroll
                for (int k = 0; k < 32; k++) wc[k] = w2w[(kt + k) * (8 * C2) + C2 + s * C2 + cj];
                #pragma unroll
                for (int n = 0; n < NN; n++) {
                    #pragma unroll
                    for (int k = 0; k < 32; k++) fs[n] += sm[wid][n][kt + k] * wc[k];
                }
            }
            float w0 = swd[0 * (SUP * C2) + s * C2 + cj];
            float w1 = swd[1 * (SUP * C2) + s * C2 + cj];
            float w2 = swd[2 * (SUP * C2) + s * C2 + cj];
            float m = -3.4e38f;
            #pragma unroll
            for (int n = 0; n < NN; n++) {
                float th = fmaxf(dx[n] * w0 + dy[n] * w1 + dz[n] * w2, 0.f);
                m = fmaxf(m, th * fs[n]);
            }
            total += m;
        }
        fm2[vtx * C2 + cj] = fmaxf(fcen + total, 0.f);
    }
}

// ---------------------------------------------------------------------------
// K5: pooling 1 -> v1, fm1p. One wave per sampled vertex.
// ---------------------------------------------------------------------------
__global__ __launch_bounds__(256) void pool1_kernel(const float* __restrict__ verts,
                                                    const int* __restrict__ nbr1,
                                                    const float* __restrict__ fm1,
                                                    float* __restrict__ v1,
                                                    float* __restrict__ fm1p,
                                                    PermArg1 pa) {
    int wid = threadIdx.x >> 6, lane = threadIdx.x & 63;
    int gid = blockIdx.x * 4 + wid;
    int b = gid >> 8, p = gid & 255;
    int sv = pa.v[p];
    const int* nb = nbr1 + (b * NV + sv) * NN;
    float m = -3.4e38f;
    #pragma unroll
    for (int n = 0; n < 8; n++) {
        m = fmaxf(m, fm1[(b * NV + nb[n]) * C1 + lane]);
    }
    fm1p[gid * C1 + lane] = m;
    if (lane < 3) v1[gid * 3 + lane] = verts[(b * NV + sv) * 3 + lane];
}

// ---------------------------------------------------------------------------
// K9: pooling 2 -> fm3 (outputs[1]) — FLOAT32 output.
// ---------------------------------------------------------------------------
__global__ __launch_bounds__(256) void pool2_kernel(const int* __restrict__ nbr2,
                                                    const float* __restrict__ fm2,
                                                    float* __restrict__ out,
                                                    PermArg2 pa) {
    int wid = threadIdx.x >> 6, lane = threadIdx.x & 63;
    int gid = blockIdx.x * 4 + wid;
    int b = gid >> 4, p = gid & 15;
    int sv = pa.v[p];
    const int* nb = nbr2 + (b * NV2 + sv) * NN;
    #pragma unroll 1
    for (int jj = 0; jj < 4; jj++) {
        int c = lane + jj * 64;
        float m = -3.4e38f;
        #pragma unroll
        for (int n = 0; n < 16; n++) {
            m = fmaxf(m, fm2[(b * NV2 + nb[n]) * C2 + c]);
        }
        out[NB * NP2 * 3 + gid * C2 + c] = m;
    }
}

// ---------------------------------------------------------------------------
// Launch
// ---------------------------------------------------------------------------
extern "C" void kernel_launch(void* const* d_in, const int* in_sizes, int n_in,
                              void* d_out, int out_size, void* d_ws, size_t ws_size,
                              hipStream_t stream) {
    (void)in_sizes; (void)n_in; (void)out_size; (void)ws_size;
    const float* verts = (const float*)d_in[0];
    const float* w0w = (const float*)d_in[1];
    const float* w0d = (const float*)d_in[2];
    const float* w1w = (const float*)d_in[3];
    const float* w1b = (const float*)d_in[4];
    const float* w1d = (const float*)d_in[5];
    const float* w2w = (const float*)d_in[6];
    const float* w2b = (const float*)d_in[7];
    const float* w2d = (const float*)d_in[8];
    float* out = (float*)d_out;   // OUTPUT IS FLOAT32 (the R0 bf16 axiom was wrong)

    static const PermOut perms = compute_perms();

    PermArg1 pa1;
    PermArg2 pa2, pac;
    memcpy(pa1.v, perms.p1, sizeof(pa1.v));
    memcpy(pa2.v, perms.p2, sizeof(pa2.v));
    for (int j = 0; j < 16; j++) pac.v[j] = perms.p1[perms.p2[j]];

    char* ws = (char*)d_ws;
    size_t off = 0;
    auto alloc = [&](size_t bytes) -> void* {
        void* p = ws + off;
        off += (bytes + 255) & ~(size_t)255;
        return p;
    };
    int*   nbr1 = (int*)  alloc((size_t)NB * NV * NN * 4);
    float* fm0  = (float*)alloc((size_t)NB * NV * K0 * 4);
    float* fm1  = (float*)alloc((size_t)NB * NV * C1 * 4);
    float* v1   = (float*)alloc((size_t)NB * NV2 * 3 * 4);
    float* fm1p = (float*)alloc((size_t)NB * NV2 * C1 * 4);
    int*   nbr2 = (int*)  alloc((size_t)NB * NV2 * NN * 4);
    float* fm2  = (float*)alloc((size_t)NB * NV2 * C2 * 4);

    v2_kernel<<<1, 384, 0, stream>>>(verts, out, pac);
    knn1_kernel<<<256, 256, 0, stream>>>(verts, nbr1);
    op3d_kernel<<<64, 256, 0, stream>>>(verts, nbr1, w0w, w0d, fm0);
    opnd1_fused<<<NB * NV / 4, 256, 0, stream>>>(verts, nbr1, fm0, w1w, w1b, w1d, fm1);
    pool1_kernel<<<NB * NV2 / 4, 256, 0, stream>>>(verts, nbr1, fm1, v1, fm1p, pa1);
    knn2_kernel<<<NB, 256, 0, stream>>>(v1, nbr2);
    opnd2_fused<<<NB * NV2 / 4, 256, 0, stream>>>(v1, nbr2, fm1p, w2w, w2b, w2d, fm2);
    pool2_kernel<<<32, 256, 0, stream>>>(nbr2, fm2, out, pa2);
}

// Round 22
// 1925.640 us; speedup vs baseline: 2.9261x; 2.9261x over previous
//
#include <hip/hip_runtime.h>
#include <hip/hip_bf16.h>
#include <stdint.h>
#include <string.h>

// ---------------------------------------------------------------------------
// Problem constants
// ---------------------------------------------------------------------------
#define NB   8
#define NV   2048
#define NN   20      // NEIGHBOR_NUM
#define SUP  7       // SUPPORT
#define K0   32
#define C1   64
#define C2   256
#define NV2  256     // vertices after pooling 1
#define NP2  16      // vertices after pooling 2

// ---------------------------------------------------------------------------
// Permutations: PCG64 + masked rejection + subtract-mix SeedSequence —
// bit-proven identical to the container's np.random.default_rng (R4≡R5),
// and now PROVEN correct end-to-end (R21 passed, absmax 0.0).
// ---------------------------------------------------------------------------
typedef unsigned __int128 u128;

struct CPcg { u128 state; u128 inc; bool has32; uint32_t cached; };

constexpr u128 PCG_MULT = (((u128)2549297995355413924ULL) << 64) | 4865540595714422341ULL;

constexpr uint64_t c_rotr64(uint64_t v, unsigned r) {
    return (v >> (r & 63u)) | (v << ((64u - r) & 63u));
}
constexpr uint64_t pcg_next64(CPcg& g) {
    g.state = g.state * PCG_MULT + g.inc;
    uint64_t hi = (uint64_t)(g.state >> 64);
    uint64_t lo = (uint64_t)g.state;
    return c_rotr64(hi ^ lo, (unsigned)(hi >> 58));
}
constexpr uint32_t pcg_next32(CPcg& g) {
    if (g.has32) { g.has32 = false; return g.cached; }
    uint64_t n = pcg_next64(g);
    g.has32 = true;
    g.cached = (uint32_t)(n >> 32);
    return (uint32_t)n;
}
constexpr uint64_t rand_interval(CPcg& g, uint64_t mx) {
    if (mx == 0) return 0;
    uint64_t mask = mx;
    mask |= mask >> 1; mask |= mask >> 2; mask |= mask >> 4;
    mask |= mask >> 8; mask |= mask >> 16; mask |= mask >> 32;
    uint64_t v = 0;
    while ((v = ((uint64_t)pcg_next32(g) & mask)) > mx) {
    }
    return v;
}
constexpr uint32_t hashmix(uint32_t value, uint32_t& hc) {
    value ^= hc; hc *= 0x931e8875u; value *= hc; value ^= value >> 16; return value;
}
constexpr uint32_t mixpool(uint32_t x, uint32_t y) {
    uint32_t r = (x * 0xca01f9ddu) - (y * 0x4973f715u);
    r ^= r >> 16; return r;
}
constexpr CPcg make_rng(uint32_t entropy) {
    uint32_t pool[4] = {0, 0, 0, 0};
    uint32_t hc = 0x43b0d7e5u;
    for (int i = 0; i < 4; i++) {
        uint32_t v = (i == 0) ? entropy : 0u;
        pool[i] = hashmix(v, hc);
    }
    for (int isrc = 0; isrc < 4; isrc++)
        for (int idst = 0; idst < 4; idst++)
            if (isrc != idst) pool[idst] = mixpool(pool[idst], hashmix(pool[isrc], hc));
    uint32_t w[8] = {};
    uint32_t hb = 0x8b51f9ddu;
    for (int i = 0; i < 8; i++) {
        uint32_t dv = pool[i & 3];
        dv ^= hb; hb *= 0x58f38dedu; dv *= hb; dv ^= dv >> 16; w[i] = dv;
    }
    uint64_t sd[4] = {};
    for (int k = 0; k < 4; k++) sd[k] = (uint64_t)w[2 * k] | ((uint64_t)w[2 * k + 1] << 32);
    u128 s = (((u128)sd[0]) << 64) | sd[1];
    u128 iq = (((u128)sd[2]) << 64) | sd[3];
    CPcg g{};
    g.state = 0;
    g.inc = (iq << 1) | 1;
    g.state = g.state * PCG_MULT + g.inc;
    g.state += s;
    g.state = g.state * PCG_MULT + g.inc;
    g.has32 = false; g.cached = 0;
    return g;
}

struct PermOut { int p1[256]; int p2[16]; };

constexpr PermOut compute_perms() {
    PermOut o{};
    {
        CPcg g = make_rng(1u);
        int arr[2048] = {};
        for (int i = 0; i < 2048; i++) arr[i] = i;
        for (int i = 2047; i >= 1; i--) {
            int j = (int)rand_interval(g, (uint64_t)i);
            int t = arr[i]; arr[i] = arr[j]; arr[j] = t;
        }
        for (int i = 0; i < 256; i++) o.p1[i] = arr[i];
    }
    {
        CPcg g = make_rng(2u);
        int arr[256] = {};
        for (int i = 0; i < 256; i++) arr[i] = i;
        for (int i = 255; i >= 1; i--) {
            int j = (int)rand_interval(g, (uint64_t)i);
            int t = arr[i]; arr[i] = arr[j]; arr[j] = t;
        }
        for (int i = 0; i < 16; i++) o.p2[i] = arr[i];
    }
    return o;
}

struct PermArg1 { int v[256]; };
struct PermArg2 { int v[16]; };

// ---------------------------------------------------------------------------
// K0: v2 (outputs[0]) = verts[:, p1[p2[j]], :] — f32
// ---------------------------------------------------------------------------
__global__ __launch_bounds__(384) void v2_kernel(const float* __restrict__ verts,
                                                 float* __restrict__ out,
                                                 PermArg2 cidx) {
    int t = threadIdx.x;  // 0..383
    if (t < NB * NP2 * 3) {
        int b = t / (NP2 * 3);
        int rem = t - b * (NP2 * 3);
        int j = rem / 3;
        int c = rem - j * 3;
        out[t] = verts[(b * NV + cidx.v[j]) * 3 + c];
    }
}

// ---------------------------------------------------------------------------
// K1: KNN over full vertex set (N=2048). 4 threads/row, top-20 + 4-way merge.
// ---------------------------------------------------------------------------
__global__ __launch_bounds__(256) void knn1_kernel(const float* __restrict__ verts,
                                                   int* __restrict__ nbr) {
    __shared__ float sv[NV * 3];
    __shared__ float sd[256 * NN];
    __shared__ int   si[256 * NN];

    int b = blockIdx.x >> 5;
    int rbase = (blockIdx.x & 31) * 64;
    const float* vb = verts + b * NV * 3;
    for (int t = threadIdx.x; t < NV * 3; t += 256) sv[t] = vb[t];

    int r = threadIdx.x >> 2;
    int q = threadIdx.x & 3;
    int i = rbase + r;

    float* ld = sd + threadIdx.x * NN;
    int*   li = si + threadIdx.x * NN;
    for (int t = 0; t < NN; t++) { ld[t] = 3.4e38f; li[t] = 0x7fffffff; }
    __syncthreads();

    float vx = sv[i * 3 + 0], vy = sv[i * 3 + 1], vz = sv[i * 3 + 2];
    float qi = vx * vx + vy * vy + vz * vz;

    float thr_d = 3.4e38f;
    int   thr_i = 0x7fffffff;

    for (int jj = 0; jj < 512; jj++) {
        int j = q * 512 + ((jj + q * 8) & 511);
        float xj = sv[j * 3 + 0], yj = sv[j * 3 + 1], zj = sv[j * 3 + 2];
        float inner = vx * xj + vy * yj + vz * zj;
        float qj = xj * xj + yj * yj + zj * zj;
        float dist = (-2.0f * inner + qi) + qj;
        bool acc = (dist < thr_d) || (dist == thr_d && j < thr_i);
        if (j != i && acc) {
            int p = NN - 1;
            while (p > 0 && (ld[p - 1] > dist || (ld[p - 1] == dist && li[p - 1] > j))) {
                ld[p] = ld[p - 1]; li[p] = li[p - 1]; p--;
            }
            ld[p] = dist; li[p] = j;
            thr_d = ld[NN - 1]; thr_i = li[NN - 1];
        }
    }
    __syncthreads();

    if (threadIdx.x < 64) {
        int r2 = threadIdx.x;
        int base = r2 * 4;
        int p[4] = {0, 0, 0, 0};
        int* dst = nbr + (b * NV + rbase + r2) * NN;
        for (int t = 0; t < NN; t++) {
            float bd = 3.5e38f; int bi = 0x7fffffff; int bq = 0;
            #pragma unroll
            for (int qq = 0; qq < 4; qq++) {
                float d = sd[(base + qq) * NN + p[qq]];
                int  ix = si[(base + qq) * NN + p[qq]];
                if (d < bd || (d == bd && ix < bi)) { bd = d; bi = ix; bq = qq; }
            }
            dst[t] = bi;
            p[bq]++;
        }
    }
}

// ---------------------------------------------------------------------------
// K6: KNN over pooled vertices (N=256), one thread per row
// ---------------------------------------------------------------------------
__global__ __launch_bounds__(256) void knn2_kernel(const float* __restrict__ v1,
                                                   int* __restrict__ nbr2) {
    __shared__ float sv[NV2 * 3];
    __shared__ float sd[256 * NN];
    __shared__ int   si[256 * NN];
    int b = blockIdx.x;
    for (int t = threadIdx.x; t < NV2 * 3; t += 256) sv[t] = v1[b * NV2 * 3 + t];
    int i = threadIdx.x;
    float* ld = sd + i * NN;
    int*   li = si + i * NN;
    for (int t = 0; t < NN; t++) { ld[t] = 3.4e38f; li[t] = 0x7fffffff; }
    __syncthreads();

    float vx = sv[i * 3 + 0], vy = sv[i * 3 + 1], vz = sv[i * 3 + 2];
    float qi = vx * vx + vy * vy + vz * vz;
    float thr_d = 3.4e38f;
    int   thr_i = 0x7fffffff;
    for (int j = 0; j < NV2; j++) {
        float xj = sv[j * 3 + 0], yj = sv[j * 3 + 1], zj = sv[j * 3 + 2];
        float inner = vx * xj + vy * yj + vz * zj;
        float qj = xj * xj + yj * yj + zj * zj;
        float dist = (-2.0f * inner + qi) + qj;
        bool acc = (dist < thr_d) || (dist == thr_d && j < thr_i);
        if (j != i && acc) {
            int p = NN - 1;
            while (p > 0 && (ld[p - 1] > dist || (ld[p - 1] == dist && li[p - 1] > j))) {
                ld[p] = ld[p - 1]; li[p] = li[p - 1]; p--;
            }
            ld[p] = dist; li[p] = j;
            thr_d = ld[NN - 1]; thr_i = li[NN - 1];
        }
    }
    int* dst = nbr2 + (b * NV2 + i) * NN;
    for (int t = 0; t < NN; t++) dst[t] = li[t];
}

// ---------------------------------------------------------------------------
// K2: operator3d + relu -> fm0 (8,2048,32). One thread per vertex.
// ---------------------------------------------------------------------------
__global__ __launch_bounds__(256) void op3d_kernel(const float* __restrict__ verts,
                                                   const int* __restrict__ nbr,
                                                   const float* __restrict__ w0w,
                                                   const float* __restrict__ w0d,
                                                   float* __restrict__ fm0) {
    __shared__ float swd[3 * SUP * K0];
    __shared__ float sww[SUP * K0];
    for (int t = threadIdx.x; t < 3 * SUP * K0; t += 256) swd[t] = w0d[t];
    for (int t = threadIdx.x; t < SUP * K0; t += 256) sww[t] = w0w[t];
    __syncthreads();

    int gid = blockIdx.x * 256 + threadIdx.x;
    int b = gid >> 11, v = gid & (NV - 1);
    const float* vb = verts + b * NV * 3;
    float vx = vb[v * 3], vy = vb[v * 3 + 1], vz = vb[v * 3 + 2];

    const int* nb = nbr + gid * NN;
    float dx[NN], dy[NN], dz[NN];
    #pragma unroll
    for (int n = 0; n < NN; n++) {
        int j = nb[n];
        dx[n] = vb[j * 3 + 0] - vx;
        dy[n] = vb[j * 3 + 1] - vy;
        dz[n] = vb[j * 3 + 2] - vz;
    }
    float* out = fm0 + gid * K0;
    #pragma unroll 1
    for (int k = 0; k < K0; k++) {
        float acc = 0.f;
        #pragma unroll
        for (int s = 0; s < SUP; s++) {
            float w0 = swd[0 * 224 + s * K0 + k];
            float w1 = swd[1 * 224 + s * K0 + k];
            float w2 = swd[2 * 224 + s * K0 + k];
            float m = 0.f;
            #pragma unroll
            for (int n = 0; n < NN; n++) {
                float t = dx[n] * w0 + dy[n] * w1 + dz[n] * w2;
                t = fmaxf(t, 0.f);
                m = fmaxf(m, t);
            }
            acc += m * sww[s * K0 + k];
        }
        out[k] = fmaxf(acc, 0.f);
    }
}

// ---------------------------------------------------------------------------
// K4: FUSED operator_nd #1 (+relu) -> fm1. Weights STAGED IN LDS per block
// (8 KB per s-block, shared by 4 waves) — kills the 34 GB global request
// stream that made R21's version 7.3 GB of HBM fetch.
// ---------------------------------------------------------------------------
__global__ __launch_bounds__(256, 2) void opnd1_fused(const float* __restrict__ verts,
                                                      const int* __restrict__ nbr,
                                                      const float* __restrict__ fm0,
                                                      const float* __restrict__ w1w,
                                                      const float* __restrict__ w1b,
                                                      const float* __restrict__ w1d,
                                                      float* __restrict__ fm1) {
    __shared__ float swd[3 * SUP * C1];   // 5.4 KB
    __shared__ float sm[4][21][K0];       // 10.5 KB
    __shared__ float sw[K0 * C1];         // 8 KB weight block
    for (int t = threadIdx.x; t < 3 * SUP * C1; t += 256) swd[t] = w1d[t];

    int wid = threadIdx.x >> 6, lane = threadIdx.x & 63;
    int vtx = blockIdx.x * 4 + wid;
    int b = vtx >> 11, v = vtx & (NV - 1);
    const float* vb = verts + b * NV * 3;
    const int* nb = nbr + vtx * NN;
    const float* f0b = fm0 + (size_t)b * NV * K0;

    for (int t = lane; t < 21 * K0; t += 64) {
        int row = t >> 5, k = t & 31;
        int j = (row < NN) ? nb[row] : v;
        sm[wid][row][k] = f0b[j * K0 + k];
    }
    float vx = vb[v * 3], vy = vb[v * 3 + 1], vz = vb[v * 3 + 2];
    float dx[NN], dy[NN], dz[NN];
    #pragma unroll
    for (int n = 0; n < NN; n++) {
        int j = nb[n];
        dx[n] = vb[j * 3 + 0] - vx;
        dy[n] = vb[j * 3 + 1] - vy;
        dz[n] = vb[j * 3 + 2] - vz;
    }

    float fcen = 0.f;
    float total = 0.f;
    #pragma unroll 1
    for (int blk = 0; blk < 8; blk++) {   // 0 = center, 1..7 = support
        __syncthreads();
        int colbase = blk * C1;  // center cols [0,64), support ss cols [64+ss*64, ...)
        for (int t = threadIdx.x; t < K0 * C1; t += 256) {
            sw[t] = w1w[(t >> 6) * (8 * C1) + colbase + (t & 63)];
        }
        __syncthreads();
        if (blk == 0) {
            float f = w1b[lane];
            #pragma unroll
            for (int k = 0; k < K0; k++) f += sm[wid][20][k] * sw[k * C1 + lane];
            fcen = f;
        } else {
            int ss = blk - 1;
            float bs = w1b[C1 + ss * C1 + lane];
            float w0 = swd[0 * (SUP * C1) + ss * C1 + lane];
            float w1 = swd[1 * (SUP * C1) + ss * C1 + lane];
            float w2 = swd[2 * (SUP * C1) + ss * C1 + lane];
            float m = -3.4e38f;
            #pragma unroll 1
            for (int n = 0; n < NN; n++) {
                float fs = bs;
                #pragma unroll
                for (int k = 0; k < K0; k++) fs += sm[wid][n][k] * sw[k * C1 + lane];
                float th = fmaxf(dx[n] * w0 + dy[n] * w1 + dz[n] * w2, 0.f);
                m = fmaxf(m, th * fs);
            }
            total += m;
        }
    }
    fm1[vtx * C1 + lane] = fmaxf(fcen + total, 0.f);
}

// ---------------------------------------------------------------------------
// K8: FUSED operator_nd #2 (+relu) -> fm2. Weights staged in LDS per
// (block, jj) chunk: 16 KB each, shared by 4 waves.
// ---------------------------------------------------------------------------
__global__ __launch_bounds__(256, 2) void opnd2_fused(const float* __restrict__ v1,
                                                      const int* __restrict__ nbr2,
                                                      const float* __restrict__ fm1p,
                                                      const float* __restrict__ w2w,
                                                      const float* __restrict__ w2b,
                                                      const float* __restrict__ w2d,
                                                      float* __restrict__ fm2) {
    __shared__ float swd[3 * SUP * C2];   // 21.5 KB
    __shared__ float sm[4][21][C1];       // 21.5 KB
    __shared__ float sw[C1 * 64];         // 16 KB weight chunk
    for (int t = threadIdx.x; t < 3 * SUP * C2; t += 256) swd[t] = w2d[t];

    int wid = threadIdx.x >> 6, lane = threadIdx.x & 63;
    int vtx = blockIdx.x * 4 + wid;
    int b = vtx >> 8, v = vtx & (NV2 - 1);
    const float* vb = v1 + b * NV2 * 3;
    const int* nb = nbr2 + vtx * NN;
    const float* f1b = fm1p + (size_t)b * NV2 * C1;

    for (int t = lane; t < 21 * C1; t += 64) {
        int row = t >> 6, k = t & 63;
        int j = (row < NN) ? nb[row] : v;
        sm[wid][row][k] = f1b[j * C1 + k];
    }
    float vx = vb[v * 3], vy = vb[v * 3 + 1], vz = vb[v * 3 + 2];
    float dx[NN], dy[NN], dz[NN];
    #pragma unroll
    for (int n = 0; n < NN; n++) {
        int j = nb[n];
        dx[n] = vb[j * 3 + 0] - vx;
        dy[n] = vb[j * 3 + 1] - vy;
        dz[n] = vb[j * 3 + 2] - vz;
    }

    #pragma unroll 1
    for (int jj = 0; jj < 4; jj++) {
        int cj = jj * 64 + lane;
        float fcen = 0.f;
        float total = 0.f;
        #pragma unroll 1
        for (int blk = 0; blk < 8; blk++) {   // 0 = center, 1..7 = support
            __syncthreads();
            int colbase = (blk == 0) ? (jj * 64) : (C2 + (blk - 1) * C2 + jj * 64);
            for (int t = threadIdx.x; t < C1 * 64; t += 256) {
                sw[t] = w2w[(t >> 6) * (8 * C2) + colbase + (t & 63)];
            }
            __syncthreads();
            if (blk == 0) {
                float f = w2b[cj];
                #pragma unroll 4
                for (int k = 0; k < C1; k++) f += sm[wid][20][k] * sw[k * 64 + lane];
                fcen = f;
            } else {
                int ss = blk - 1;
                float bs = w2b[C2 + ss * C2 + cj];
                float w0 = swd[0 * (SUP * C2) + ss * C2 + cj];
                float w1 = swd[1 * (SUP * C2) + ss * C2 + cj];
                float w2 = swd[2 * (SUP * C2) + ss * C2 + cj];
                float m = -3.4e38f;
                #pragma unroll 1
                for (int n = 0; n < NN; n++) {
                    float fs = bs;
                    #pragma unroll 8
                    for (int k = 0; k < C1; k++) fs += sm[wid][n][k] * sw[k * 64 + lane];
                    float th = fmaxf(dx[n] * w0 + dy[n] * w1 + dz[n] * w2, 0.f);
                    m = fmaxf(m, th * fs);
                }
                total += m;
            }
        }
        fm2[vtx * C2 + cj] = fmaxf(fcen + total, 0.f);
    }
}

// ---------------------------------------------------------------------------
// K5: pooling 1 -> v1, fm1p. One wave per sampled vertex.
// ---------------------------------------------------------------------------
__global__ __launch_bounds__(256) void pool1_kernel(const float* __restrict__ verts,
                                                    const int* __restrict__ nbr1,
                                                    const float* __restrict__ fm1,
                                                    float* __restrict__ v1,
                                                    float* __restrict__ fm1p,
                                                    PermArg1 pa) {
    int wid = threadIdx.x >> 6, lane = threadIdx.x & 63;
    int gid = blockIdx.x * 4 + wid;
    int b = gid >> 8, p = gid & 255;
    int sv = pa.v[p];
    const int* nb = nbr1 + (b * NV + sv) * NN;
    float m = -3.4e38f;
    #pragma unroll
    for (int n = 0; n < 8; n++) {
        m = fmaxf(m, fm1[(b * NV + nb[n]) * C1 + lane]);
    }
    fm1p[gid * C1 + lane] = m;
    if (lane < 3) v1[gid * 3 + lane] = verts[(b * NV + sv) * 3 + lane];
}

// ---------------------------------------------------------------------------
// K9: pooling 2 -> fm3 (outputs[1]) — f32
// ---------------------------------------------------------------------------
__global__ __launch_bounds__(256) void pool2_kernel(const int* __restrict__ nbr2,
                                                    const float* __restrict__ fm2,
                                                    float* __restrict__ out,
                                                    PermArg2 pa) {
    int wid = threadIdx.x >> 6, lane = threadIdx.x & 63;
    int gid = blockIdx.x * 4 + wid;
    int b = gid >> 4, p = gid & 15;
    int sv = pa.v[p];
    const int* nb = nbr2 + (b * NV2 + sv) * NN;
    #pragma unroll 1
    for (int jj = 0; jj < 4; jj++) {
        int c = lane + jj * 64;
        float m = -3.4e38f;
        #pragma unroll
        for (int n = 0; n < 16; n++) {
            m = fmaxf(m, fm2[(b * NV2 + nb[n]) * C2 + c]);
        }
        out[NB * NP2 * 3 + gid * C2 + c] = m;
    }
}

// ---------------------------------------------------------------------------
// Launch
// ---------------------------------------------------------------------------
extern "C" void kernel_launch(void* const* d_in, const int* in_sizes, int n_in,
                              void* d_out, int out_size, void* d_ws, size_t ws_size,
                              hipStream_t stream) {
    (void)in_sizes; (void)n_in; (void)out_size; (void)ws_size;
    const float* verts = (const float*)d_in[0];
    const float* w0w = (const float*)d_in[1];
    const float* w0d = (const float*)d_in[2];
    const float* w1w = (const float*)d_in[3];
    const float* w1b = (const float*)d_in[4];
    const float* w1d = (const float*)d_in[5];
    const float* w2w = (const float*)d_in[6];
    const float* w2b = (const float*)d_in[7];
    const float* w2d = (const float*)d_in[8];
    float* out = (float*)d_out;

    static const PermOut perms = compute_perms();

    PermArg1 pa1;
    PermArg2 pa2, pac;
    memcpy(pa1.v, perms.p1, sizeof(pa1.v));
    memcpy(pa2.v, perms.p2, sizeof(pa2.v));
    for (int j = 0; j < 16; j++) pac.v[j] = perms.p1[perms.p2[j]];

    char* ws = (char*)d_ws;
    size_t off = 0;
    auto alloc = [&](size_t bytes) -> void* {
        void* p = ws + off;
        off += (bytes + 255) & ~(size_t)255;
        return p;
    };
    int*   nbr1 = (int*)  alloc((size_t)NB * NV * NN * 4);
    float* fm0  = (float*)alloc((size_t)NB * NV * K0 * 4);
    float* fm1  = (float*)alloc((size_t)NB * NV * C1 * 4);
    float* v1   = (float*)alloc((size_t)NB * NV2 * 3 * 4);
    float* fm1p = (float*)alloc((size_t)NB * NV2 * C1 * 4);
    int*   nbr2 = (int*)  alloc((size_t)NB * NV2 * NN * 4);
    float* fm2  = (float*)alloc((size_t)NB * NV2 * C2 * 4);

    v2_kernel<<<1, 384, 0, stream>>>(verts, out, pac);
    knn1_kernel<<<256, 256, 0, stream>>>(verts, nbr1);
    op3d_kernel<<<64, 256, 0, stream>>>(verts, nbr1, w0w, w0d, fm0);
    opnd1_fused<<<NB * NV / 4, 256, 0, stream>>>(verts, nbr1, fm0, w1w, w1b, w1d, fm1);
    pool1_kernel<<<NB * NV2 / 4, 256, 0, stream>>>(verts, nbr1, fm1, v1, fm1p, pa1);
    knn2_kernel<<<NB, 256, 0, stream>>>(v1, nbr2);
    opnd2_fused<<<NB * NV2 / 4, 256, 0, stream>>>(v1, nbr2, fm1p, w2w, w2b, w2d, fm2);
    pool2_kernel<<<32, 256, 0, stream>>>(nbr2, fm2, out, pa2);
}

// Round 24
// 1372.636 us; speedup vs baseline: 4.1050x; 1.4029x over previous
//
#include <hip/hip_runtime.h>
#include <hip/hip_bf16.h>
#include <stdint.h>
#include <string.h>

// ---------------------------------------------------------------------------
// Problem constants
// ---------------------------------------------------------------------------
#define NB   8
#define NV   2048
#define NN   20      // NEIGHBOR_NUM
#define SUP  7       // SUPPORT
#define K0   32
#define C1   64
#define C2   256
#define NV2  256     // vertices after pooling 1
#define NP2  16      // vertices after pooling 2
#define COLL_CAP 256

// ---------------------------------------------------------------------------
// Permutations: PCG64 + masked rejection + subtract-mix SeedSequence —
// proven correct end-to-end (R21/R22 passed, absmax ~0).
// ---------------------------------------------------------------------------
typedef unsigned __int128 u128;

struct CPcg { u128 state; u128 inc; bool has32; uint32_t cached; };

constexpr u128 PCG_MULT = (((u128)2549297995355413924ULL) << 64) | 4865540595714422341ULL;

constexpr uint64_t c_rotr64(uint64_t v, unsigned r) {
    return (v >> (r & 63u)) | (v << ((64u - r) & 63u));
}
constexpr uint64_t pcg_next64(CPcg& g) {
    g.state = g.state * PCG_MULT + g.inc;
    uint64_t hi = (uint64_t)(g.state >> 64);
    uint64_t lo = (uint64_t)g.state;
    return c_rotr64(hi ^ lo, (unsigned)(hi >> 58));
}
constexpr uint32_t pcg_next32(CPcg& g) {
    if (g.has32) { g.has32 = false; return g.cached; }
    uint64_t n = pcg_next64(g);
    g.has32 = true;
    g.cached = (uint32_t)(n >> 32);
    return (uint32_t)n;
}
constexpr uint64_t rand_interval(CPcg& g, uint64_t mx) {
    if (mx == 0) return 0;
    uint64_t mask = mx;
    mask |= mask >> 1; mask |= mask >> 2; mask |= mask >> 4;
    mask |= mask >> 8; mask |= mask >> 16; mask |= mask >> 32;
    uint64_t v = 0;
    while ((v = ((uint64_t)pcg_next32(g) & mask)) > mx) {
    }
    return v;
}
constexpr uint32_t hashmix(uint32_t value, uint32_t& hc) {
    value ^= hc; hc *= 0x931e8875u; value *= hc; value ^= value >> 16; return value;
}
constexpr uint32_t mixpool(uint32_t x, uint32_t y) {
    uint32_t r = (x * 0xca01f9ddu) - (y * 0x4973f715u);
    r ^= r >> 16; return r;
}
constexpr CPcg make_rng(uint32_t entropy) {
    uint32_t pool[4] = {0, 0, 0, 0};
    uint32_t hc = 0x43b0d7e5u;
    for (int i = 0; i < 4; i++) {
        uint32_t v = (i == 0) ? entropy : 0u;
        pool[i] = hashmix(v, hc);
    }
    for (int isrc = 0; isrc < 4; isrc++)
        for (int idst = 0; idst < 4; idst++)
            if (isrc != idst) pool[idst] = mixpool(pool[idst], hashmix(pool[isrc], hc));
    uint32_t w[8] = {};
    uint32_t hb = 0x8b51f9ddu;
    for (int i = 0; i < 8; i++) {
        uint32_t dv = pool[i & 3];
        dv ^= hb; hb *= 0x58f38dedu; dv *= hb; dv ^= dv >> 16; w[i] = dv;
    }
    uint64_t sd[4] = {};
    for (int k = 0; k < 4; k++) sd[k] = (uint64_t)w[2 * k] | ((uint64_t)w[2 * k + 1] << 32);
    u128 s = (((u128)sd[0]) << 64) | sd[1];
    u128 iq = (((u128)sd[2]) << 64) | sd[3];
    CPcg g{};
    g.state = 0;
    g.inc = (iq << 1) | 1;
    g.state = g.state * PCG_MULT + g.inc;
    g.state += s;
    g.state = g.state * PCG_MULT + g.inc;
    g.has32 = false; g.cached = 0;
    return g;
}

struct PermOut { int p1[256]; int p2[16]; };

constexpr PermOut compute_perms() {
    PermOut o{};
    {
        CPcg g = make_rng(1u);
        int arr[2048] = {};
        for (int i = 0; i < 2048; i++) arr[i] = i;
        for (int i = 2047; i >= 1; i--) {
            int j = (int)rand_interval(g, (uint64_t)i);
            int t = arr[i]; arr[i] = arr[j]; arr[j] = t;
        }
        for (int i = 0; i < 256; i++) o.p1[i] = arr[i];
    }
    {
        CPcg g = make_rng(2u);
        int arr[256] = {};
        for (int i = 0; i < 256; i++) arr[i] = i;
        for (int i = 255; i >= 1; i--) {
            int j = (int)rand_interval(g, (uint64_t)i);
            int t = arr[i]; arr[i] = arr[j]; arr[j] = t;
        }
        for (int i = 0; i < 16; i++) o.p2[i] = arr[i];
    }
    return o;
}

struct PermArg1 { int v[256]; };
struct PermArg2 { int v[16]; };

// ---------------------------------------------------------------------------
// K0: v2 (outputs[0]) = verts[:, p1[p2[j]], :] — f32
// ---------------------------------------------------------------------------
__global__ __launch_bounds__(384) void v2_kernel(const float* __restrict__ verts,
                                                 float* __restrict__ out,
                                                 PermArg2 cidx) {
    int t = threadIdx.x;  // 0..383
    if (t < NB * NP2 * 3) {
        int b = t / (NP2 * 3);
        int rem = t - b * (NP2 * 3);
        int j = rem / 3;
        int c = rem - j * 3;
        out[t] = verts[(b * NV + cidx.v[j]) * 3 + c];
    }
}

// ---------------------------------------------------------------------------
// KNN via exact wave-per-row radix select. One wave = one row; candidates in
// registers as monotonically-mapped dist bits; two 8-bit LDS histogram passes
// find the top-20 boundary; collect + rank gives exact (dist, idx) ascending
// top-20 excluding self (identical semantics to the R22 insertion version).
// ---------------------------------------------------------------------------
template<int N, int CPL>
__global__ __launch_bounds__(256) void knn_radix_kernel(const float* __restrict__ verts,
                                                        int* __restrict__ nbr) {
    __shared__ float sv[N * 3];
    __shared__ int hist[4][256];
    __shared__ unsigned long long coll[4][COLL_CAP];
    __shared__ int cnt[4];

    constexpr int RPB = 16;              // rows per block
    int bpb = N / RPB;                   // blocks per batch
    int b = blockIdx.x / bpb;
    int rbase = (blockIdx.x % bpb) * RPB;

    const float* vb = verts + (size_t)b * N * 3;
    for (int t = threadIdx.x; t < N * 3; t += 256) sv[t] = vb[t];
    __syncthreads();

    int wid = threadIdx.x >> 6, lane = threadIdx.x & 63;
    int* myhist = hist[wid];
    unsigned long long* mycoll = coll[wid];

    for (int rr = 0; rr < 4; rr++) {
        int i = rbase + wid * 4 + rr;
        float vx = sv[i * 3 + 0], vy = sv[i * 3 + 1], vz = sv[i * 3 + 2];
        float qi = vx * vx + vy * vy + vz * vz;

        unsigned key[CPL];
        #pragma unroll
        for (int t = 0; t < CPL; t++) {
            int j = lane + 64 * t;
            float xj = sv[j * 3 + 0], yj = sv[j * 3 + 1], zj = sv[j * 3 + 2];
            float inner = vx * xj + vy * yj + vz * zj;
            float qj = xj * xj + yj * yj + zj * zj;
            float dist = (-2.0f * inner + qi) + qj;   // same expr as before
            unsigned u = __float_as_uint(dist);
            u = (u & 0x80000000u) ? ~u : (u | 0x80000000u);  // monotonic map
            key[t] = (j == i) ? 0xFFFFFFFFu : u;
        }

        // pass 1: histogram of key>>24
        #pragma unroll
        for (int q = 0; q < 4; q++) myhist[lane * 4 + q] = 0;
        __asm__ volatile("s_waitcnt lgkmcnt(0)" ::: "memory");
        #pragma unroll
        for (int t = 0; t < CPL; t++) atomicAdd(&myhist[key[t] >> 24], 1);
        __asm__ volatile("s_waitcnt lgkmcnt(0)" ::: "memory");

        int B1 = 255, below1 = 0;
        {
            int P = 0;
            for (int bb = 0; bb < 256; bb++) {        // uniform across lanes
                int c = myhist[bb];
                if (P + c >= NN) { B1 = bb; below1 = P; break; }
                P += c;
            }
        }

        // pass 2: histogram of (key>>16)&0xFF within bin B1
        #pragma unroll
        for (int q = 0; q < 4; q++) myhist[lane * 4 + q] = 0;
        __asm__ volatile("s_waitcnt lgkmcnt(0)" ::: "memory");
        #pragma unroll
        for (int t = 0; t < CPL; t++)
            if ((int)(key[t] >> 24) == B1) atomicAdd(&myhist[(key[t] >> 16) & 0xFF], 1);
        __asm__ volatile("s_waitcnt lgkmcnt(0)" ::: "memory");

        int B2 = 255;
        {
            int P = 0, r1 = NN - below1;
            for (int bb = 0; bb < 256; bb++) {
                int c = myhist[bb];
                if (P + c >= r1) { B2 = bb; break; }
                P += c;
            }
        }

        // collect definite + boundary elements
        if (lane == 0) cnt[wid] = 0;
        __asm__ volatile("s_waitcnt lgkmcnt(0)" ::: "memory");
        #pragma unroll
        for (int t = 0; t < CPL; t++) {
            unsigned mk = key[t];
            int hb = (int)(mk >> 24), sb = (int)((mk >> 16) & 0xFF);
            bool take = (hb < B1) || (hb == B1 && sb <= B2);
            if (take) {
                int pos = atomicAdd(&cnt[wid], 1);
                if (pos < COLL_CAP)
                    mycoll[pos] = ((unsigned long long)mk << 32) | (unsigned)(lane + 64 * t);
            }
        }
        __asm__ volatile("s_waitcnt lgkmcnt(0)" ::: "memory");
        int count = cnt[wid];
        if (count > COLL_CAP) count = COLL_CAP;

        // rank pass: exact (mapped_dist, idx) ascending; write ranks < 20
        int* dst = nbr + ((size_t)b * N + i) * NN;
        for (int e = lane; e < count; e += 64) {
            unsigned long long me = mycoll[e];
            int rank = 0;
            for (int m = 0; m < count; m++) rank += (mycoll[m] < me);
            if (rank < NN) dst[rank] = (int)(me & 0xFFFFFFFFull);
        }
    }
}

// ---------------------------------------------------------------------------
// K2: operator3d + relu -> fm0 (8,2048,32). One thread per vertex.
// ---------------------------------------------------------------------------
__global__ __launch_bounds__(256) void op3d_kernel(const float* __restrict__ verts,
                                                   const int* __restrict__ nbr,
                                                   const float* __restrict__ w0w,
                                                   const float* __restrict__ w0d,
                                                   float* __restrict__ fm0) {
    __shared__ float swd[3 * SUP * K0];
    __shared__ float sww[SUP * K0];
    for (int t = threadIdx.x; t < 3 * SUP * K0; t += 256) swd[t] = w0d[t];
    for (int t = threadIdx.x; t < SUP * K0; t += 256) sww[t] = w0w[t];
    __syncthreads();

    int gid = blockIdx.x * 256 + threadIdx.x;
    int b = gid >> 11, v = gid & (NV - 1);
    const float* vb = verts + b * NV * 3;
    float vx = vb[v * 3], vy = vb[v * 3 + 1], vz = vb[v * 3 + 2];

    const int* nb = nbr + gid * NN;
    float dx[NN], dy[NN], dz[NN];
    #pragma unroll
    for (int n = 0; n < NN; n++) {
        int j = nb[n];
        dx[n] = vb[j * 3 + 0] - vx;
        dy[n] = vb[j * 3 + 1] - vy;
        dz[n] = vb[j * 3 + 2] - vz;
    }
    float* out = fm0 + gid * K0;
    #pragma unroll 1
    for (int k = 0; k < K0; k++) {
        float acc = 0.f;
        #pragma unroll
        for (int s = 0; s < SUP; s++) {
            float w0 = swd[0 * 224 + s * K0 + k];
            float w1 = swd[1 * 224 + s * K0 + k];
            float w2 = swd[2 * 224 + s * K0 + k];
            float m = 0.f;
            #pragma unroll
            for (int n = 0; n < NN; n++) {
                float t = dx[n] * w0 + dy[n] * w1 + dz[n] * w2;
                t = fmaxf(t, 0.f);
                m = fmaxf(m, t);
            }
            acc += m * sww[s * K0 + k];
        }
        out[k] = fmaxf(acc, 0.f);
    }
}

// ---------------------------------------------------------------------------
// K4: FUSED operator_nd #1 (+relu) -> fm1. Weights staged in LDS per block.
// ---------------------------------------------------------------------------
__global__ __launch_bounds__(256, 2) void opnd1_fused(const float* __restrict__ verts,
                                                      const int* __restrict__ nbr,
                                                      const float* __restrict__ fm0,
                                                      const float* __restrict__ w1w,
                                                      const float* __restrict__ w1b,
                                                      const float* __restrict__ w1d,
                                                      float* __restrict__ fm1) {
    __shared__ float swd[3 * SUP * C1];
    __shared__ float sm[4][21][K0];
    __shared__ float sw[K0 * C1];
    for (int t = threadIdx.x; t < 3 * SUP * C1; t += 256) swd[t] = w1d[t];

    int wid = threadIdx.x >> 6, lane = threadIdx.x & 63;
    int vtx = blockIdx.x * 4 + wid;
    int b = vtx >> 11, v = vtx & (NV - 1);
    const float* vb = verts + b * NV * 3;
    const int* nb = nbr + vtx * NN;
    const float* f0b = fm0 + (size_t)b * NV * K0;

    for (int t = lane; t < 21 * K0; t += 64) {
        int row = t >> 5, k = t & 31;
        int j = (row < NN) ? nb[row] : v;
        sm[wid][row][k] = f0b[j * K0 + k];
    }
    float vx = vb[v * 3], vy = vb[v * 3 + 1], vz = vb[v * 3 + 2];
    float dx[NN], dy[NN], dz[NN];
    #pragma unroll
    for (int n = 0; n < NN; n++) {
        int j = nb[n];
        dx[n] = vb[j * 3 + 0] - vx;
        dy[n] = vb[j * 3 + 1] - vy;
        dz[n] = vb[j * 3 + 2] - vz;
    }

    float fcen = 0.f;
    float total = 0.f;
    #pragma unroll 1
    for (int blk = 0; blk < 8; blk++) {
        __syncthreads();
        int colbase = blk * C1;
        for (int t = threadIdx.x; t < K0 * C1; t += 256) {
            sw[t] = w1w[(t >> 6) * (8 * C1) + colbase + (t & 63)];
        }
        __syncthreads();
        if (blk == 0) {
            float f = w1b[lane];
            #pragma unroll
            for (int k = 0; k < K0; k++) f += sm[wid][20][k] * sw[k * C1 + lane];
            fcen = f;
        } else {
            int ss = blk - 1;
            float bs = w1b[C1 + ss * C1 + lane];
            float w0 = swd[0 * (SUP * C1) + ss * C1 + lane];
            float w1 = swd[1 * (SUP * C1) + ss * C1 + lane];
            float w2 = swd[2 * (SUP * C1) + ss * C1 + lane];
            float m = -3.4e38f;
            #pragma unroll 1
            for (int n = 0; n < NN; n++) {
                float fs = bs;
                #pragma unroll
                for (int k = 0; k < K0; k++) fs += sm[wid][n][k] * sw[k * C1 + lane];
                float th = fmaxf(dx[n] * w0 + dy[n] * w1 + dz[n] * w2, 0.f);
                m = fmaxf(m, th * fs);
            }
            total += m;
        }
    }
    fm1[vtx * C1 + lane] = fmaxf(fcen + total, 0.f);
}

// ---------------------------------------------------------------------------
// K8: FUSED operator_nd #2 (+relu) -> fm2. Weights staged per (blk, jj) chunk.
// ---------------------------------------------------------------------------
__global__ __launch_bounds__(256, 2) void opnd2_fused(const float* __restrict__ v1,
                                                      const int* __restrict__ nbr2,
                                                      const float* __restrict__ fm1p,
                                                      const float* __restrict__ w2w,
                                                      const float* __restrict__ w2b,
                                                      const float* __restrict__ w2d,
                                                      float* __restrict__ fm2) {
    __shared__ float swd[3 * SUP * C2];
    __shared__ float sm[4][21][C1];
    __shared__ float sw[C1 * 64];
    for (int t = threadIdx.x; t < 3 * SUP * C2; t += 256) swd[t] = w2d[t];

    int wid = threadIdx.x >> 6, lane = threadIdx.x & 63;
    int vtx = blockIdx.x * 4 + wid;
    int b = vtx >> 8, v = vtx & (NV2 - 1);
    const float* vb = v1 + b * NV2 * 3;
    const int* nb = nbr2 + vtx * NN;
    const float* f1b = fm1p + (size_t)b * NV2 * C1;

    for (int t = lane; t < 21 * C1; t += 64) {
        int row = t >> 6, k = t & 63;
        int j = (row < NN) ? nb[row] : v;
        sm[wid][row][k] = f1b[j * C1 + k];
    }
    float vx = vb[v * 3], vy = vb[v * 3 + 1], vz = vb[v * 3 + 2];
    float dx[NN], dy[NN], dz[NN];
    #pragma unroll
    for (int n = 0; n < NN; n++) {
        int j = nb[n];
        dx[n] = vb[j * 3 + 0] - vx;
        dy[n] = vb[j * 3 + 1] - vy;
        dz[n] = vb[j * 3 + 2] - vz;
    }

    #pragma unroll 1
    for (int jj = 0; jj < 4; jj++) {
        int cj = jj * 64 + lane;
        float fcen = 0.f;
        float total = 0.f;
        #pragma unroll 1
        for (int blk = 0; blk < 8; blk++) {
            __syncthreads();
            int colbase = (blk == 0) ? (jj * 64) : (C2 + (blk - 1) * C2 + jj * 64);
            for (int t = threadIdx.x; t < C1 * 64; t += 256) {
                sw[t] = w2w[(t >> 6) * (8 * C2) + colbase + (t & 63)];
            }
            __syncthreads();
            if (blk == 0) {
                float f = w2b[cj];
                #pragma unroll 4
                for (int k = 0; k < C1; k++) f += sm[wid][20][k] * sw[k * 64 + lane];
                fcen = f;
            } else {
                int ss = blk - 1;
                float bs = w2b[C2 + ss * C2 + cj];
                float w0 = swd[0 * (SUP * C2) + ss * C2 + cj];
                float w1 = swd[1 * (SUP * C2) + ss * C2 + cj];
                float w2 = swd[2 * (SUP * C2) + ss * C2 + cj];
                float m = -3.4e38f;
                #pragma unroll 1
                for (int n = 0; n < NN; n++) {
                    float fs = bs;
                    #pragma unroll 8
                    for (int k = 0; k < C1; k++) fs += sm[wid][n][k] * sw[k * 64 + lane];
                    float th = fmaxf(dx[n] * w0 + dy[n] * w1 + dz[n] * w2, 0.f);
                    m = fmaxf(m, th * fs);
                }
                total += m;
            }
        }
        fm2[vtx * C2 + cj] = fmaxf(fcen + total, 0.f);
    }
}

// ---------------------------------------------------------------------------
// K5: pooling 1 -> v1, fm1p. One wave per sampled vertex.
// ---------------------------------------------------------------------------
__global__ __launch_bounds__(256) void pool1_kernel(const float* __restrict__ verts,
                                                    const int* __restrict__ nbr1,
                                                    const float* __restrict__ fm1,
                                                    float* __restrict__ v1,
                                                    float* __restrict__ fm1p,
                                                    PermArg1 pa) {
    int wid = threadIdx.x >> 6, lane = threadIdx.x & 63;
    int gid = blockIdx.x * 4 + wid;
    int b = gid >> 8, p = gid & 255;
    int sv = pa.v[p];
    const int* nb = nbr1 + (b * NV + sv) * NN;
    float m = -3.4e38f;
    #pragma unroll
    for (int n = 0; n < 8; n++) {
        m = fmaxf(m, fm1[(b * NV + nb[n]) * C1 + lane]);
    }
    fm1p[gid * C1 + lane] = m;
    if (lane < 3) v1[gid * 3 + lane] = verts[(b * NV + sv) * 3 + lane];
}

// ---------------------------------------------------------------------------
// K9: pooling 2 -> fm3 (outputs[1]) — f32
// ---------------------------------------------------------------------------
__global__ __launch_bounds__(256) void pool2_kernel(const int* __restrict__ nbr2,
                                                    const float* __restrict__ fm2,
                                                    float* __restrict__ out,
                                                    PermArg2 pa) {
    int wid = threadIdx.x >> 6, lane = threadIdx.x & 63;
    int gid = blockIdx.x * 4 + wid;
    int b = gid >> 4, p = gid & 15;
    int sv = pa.v[p];
    const int* nb = nbr2 + (b * NV2 + sv) * NN;
    #pragma unroll 1
    for (int jj = 0; jj < 4; jj++) {
        int c = lane + jj * 64;
        float m = -3.4e38f;
        #pragma unroll
        for (int n = 0; n < 16; n++) {
            m = fmaxf(m, fm2[(b * NV2 + nb[n]) * C2 + c]);
        }
        out[NB * NP2 * 3 + gid * C2 + c] = m;
    }
}

// ---------------------------------------------------------------------------
// Launch
// ---------------------------------------------------------------------------
extern "C" void kernel_launch(void* const* d_in, const int* in_sizes, int n_in,
                              void* d_out, int out_size, void* d_ws, size_t ws_size,
                              hipStream_t stream) {
    (void)in_sizes; (void)n_in; (void)out_size; (void)ws_size;
    const float* verts = (const float*)d_in[0];
    const float* w0w = (const float*)d_in[1];
    const float* w0d = (const float*)d_in[2];
    const float* w1w = (const float*)d_in[3];
    const float* w1b = (const float*)d_in[4];
    const float* w1d = (const float*)d_in[5];
    const float* w2w = (const float*)d_in[6];
    const float* w2b = (const float*)d_in[7];
    const float* w2d = (const float*)d_in[8];
    float* out = (float*)d_out;

    static const PermOut perms = compute_perms();

    PermArg1 pa1;
    PermArg2 pa2, pac;
    memcpy(pa1.v, perms.p1, sizeof(pa1.v));
    memcpy(pa2.v, perms.p2, sizeof(pa2.v));
    for (int j = 0; j < 16; j++) pac.v[j] = perms.p1[perms.p2[j]];

    char* ws = (char*)d_ws;
    size_t off = 0;
    auto alloc = [&](size_t bytes) -> void* {
        void* p = ws + off;
        off += (bytes + 255) & ~(size_t)255;
        return p;
    };
    int*   nbr1 = (int*)  alloc((size_t)NB * NV * NN * 4);
    float* fm0  = (float*)alloc((size_t)NB * NV * K0 * 4);
    float* fm1  = (float*)alloc((size_t)NB * NV * C1 * 4);
    float* v1   = (float*)alloc((size_t)NB * NV2 * 3 * 4);
    float* fm1p = (float*)alloc((size_t)NB * NV2 * C1 * 4);
    int*   nbr2 = (int*)  alloc((size_t)NB * NV2 * NN * 4);
    float* fm2  = (float*)alloc((size_t)NB * NV2 * C2 * 4);

    v2_kernel<<<1, 384, 0, stream>>>(verts, out, pac);
    knn_radix_kernel<NV, NV / 64><<<NB * (NV / 16), 256, 0, stream>>>(verts, nbr1);
    op3d_kernel<<<64, 256, 0, stream>>>(verts, nbr1, w0w, w0d, fm0);
    opnd1_fused<<<NB * NV / 4, 256, 0, stream>>>(verts, nbr1, fm0, w1w, w1b, w1d, fm1);
    pool1_kernel<<<NB * NV2 / 4, 256, 0, stream>>>(verts, nbr1, fm1, v1, fm1p, pa1);
    knn_radix_kernel<NV2, NV2 / 64><<<NB * (NV2 / 16), 256, 0, stream>>>(v1, nbr2);
    opnd2_fused<<<NB * NV2 / 4, 256, 0, stream>>>(v1, nbr2, fm1p, w2w, w2b, w2d, fm2);
    pool2_kernel<<<32, 256, 0, stream>>>(nbr2, fm2, out, pa2);
}

// Round 25
// 1272.464 us; speedup vs baseline: 4.4281x; 1.0787x over previous
//
#include <hip/hip_runtime.h>
#include <hip/hip_bf16.h>
#include <stdint.h>
#include <string.h>

// ---------------------------------------------------------------------------
// Problem constants
// ---------------------------------------------------------------------------
#define NB   8
#define NV   2048
#define NN   20      // NEIGHBOR_NUM
#define SUP  7       // SUPPORT
#define K0   32
#define C1   64
#define C2   256
#define NV2  256     // vertices after pooling 1
#define NP2  16      // vertices after pooling 2
#define COLL_CAP 256

// ---------------------------------------------------------------------------
// Permutations: PCG64 + masked rejection + subtract-mix SeedSequence —
// proven correct end-to-end (R21/R22/R24 passed).
// ---------------------------------------------------------------------------
typedef unsigned __int128 u128;

struct CPcg { u128 state; u128 inc; bool has32; uint32_t cached; };

constexpr u128 PCG_MULT = (((u128)2549297995355413924ULL) << 64) | 4865540595714422341ULL;

constexpr uint64_t c_rotr64(uint64_t v, unsigned r) {
    return (v >> (r & 63u)) | (v << ((64u - r) & 63u));
}
constexpr uint64_t pcg_next64(CPcg& g) {
    g.state = g.state * PCG_MULT + g.inc;
    uint64_t hi = (uint64_t)(g.state >> 64);
    uint64_t lo = (uint64_t)g.state;
    return c_rotr64(hi ^ lo, (unsigned)(hi >> 58));
}
constexpr uint32_t pcg_next32(CPcg& g) {
    if (g.has32) { g.has32 = false; return g.cached; }
    uint64_t n = pcg_next64(g);
    g.has32 = true;
    g.cached = (uint32_t)(n >> 32);
    return (uint32_t)n;
}
constexpr uint64_t rand_interval(CPcg& g, uint64_t mx) {
    if (mx == 0) return 0;
    uint64_t mask = mx;
    mask |= mask >> 1; mask |= mask >> 2; mask |= mask >> 4;
    mask |= mask >> 8; mask |= mask >> 16; mask |= mask >> 32;
    uint64_t v = 0;
    while ((v = ((uint64_t)pcg_next32(g) & mask)) > mx) {
    }
    return v;
}
constexpr uint32_t hashmix(uint32_t value, uint32_t& hc) {
    value ^= hc; hc *= 0x931e8875u; value *= hc; value ^= value >> 16; return value;
}
constexpr uint32_t mixpool(uint32_t x, uint32_t y) {
    uint32_t r = (x * 0xca01f9ddu) - (y * 0x4973f715u);
    r ^= r >> 16; return r;
}
constexpr CPcg make_rng(uint32_t entropy) {
    uint32_t pool[4] = {0, 0, 0, 0};
    uint32_t hc = 0x43b0d7e5u;
    for (int i = 0; i < 4; i++) {
        uint32_t v = (i == 0) ? entropy : 0u;
        pool[i] = hashmix(v, hc);
    }
    for (int isrc = 0; isrc < 4; isrc++)
        for (int idst = 0; idst < 4; idst++)
            if (isrc != idst) pool[idst] = mixpool(pool[idst], hashmix(pool[isrc], hc));
    uint32_t w[8] = {};
    uint32_t hb = 0x8b51f9ddu;
    for (int i = 0; i < 8; i++) {
        uint32_t dv = pool[i & 3];
        dv ^= hb; hb *= 0x58f38dedu; dv *= hb; dv ^= dv >> 16; w[i] = dv;
    }
    uint64_t sd[4] = {};
    for (int k = 0; k < 4; k++) sd[k] = (uint64_t)w[2 * k] | ((uint64_t)w[2 * k + 1] << 32);
    u128 s = (((u128)sd[0]) << 64) | sd[1];
    u128 iq = (((u128)sd[2]) << 64) | sd[3];
    CPcg g{};
    g.state = 0;
    g.inc = (iq << 1) | 1;
    g.state = g.state * PCG_MULT + g.inc;
    g.state += s;
    g.state = g.state * PCG_MULT + g.inc;
    g.has32 = false; g.cached = 0;
    return g;
}

struct PermOut { int p1[256]; int p2[16]; };

constexpr PermOut compute_perms() {
    PermOut o{};
    {
        CPcg g = make_rng(1u);
        int arr[2048] = {};
        for (int i = 0; i < 2048; i++) arr[i] = i;
        for (int i = 2047; i >= 1; i--) {
            int j = (int)rand_interval(g, (uint64_t)i);
            int t = arr[i]; arr[i] = arr[j]; arr[j] = t;
        }
        for (int i = 0; i < 256; i++) o.p1[i] = arr[i];
    }
    {
        CPcg g = make_rng(2u);
        int arr[256] = {};
        for (int i = 0; i < 256; i++) arr[i] = i;
        for (int i = 255; i >= 1; i--) {
            int j = (int)rand_interval(g, (uint64_t)i);
            int t = arr[i]; arr[i] = arr[j]; arr[j] = t;
        }
        for (int i = 0; i < 16; i++) o.p2[i] = arr[i];
    }
    return o;
}

struct PermArg1 { int v[256]; };
struct PermArg2 { int v[16]; };

// ---------------------------------------------------------------------------
// K0: v2 (outputs[0]) = verts[:, p1[p2[j]], :] — f32
// ---------------------------------------------------------------------------
__global__ __launch_bounds__(384) void v2_kernel(const float* __restrict__ verts,
                                                 float* __restrict__ out,
                                                 PermArg2 cidx) {
    int t = threadIdx.x;  // 0..383
    if (t < NB * NP2 * 3) {
        int b = t / (NP2 * 3);
        int rem = t - b * (NP2 * 3);
        int j = rem / 3;
        int c = rem - j * 3;
        out[t] = verts[(b * NV + cidx.v[j]) * 3 + c];
    }
}

// ---------------------------------------------------------------------------
// KNN via exact wave-per-row radix select (R24, proven).
// ---------------------------------------------------------------------------
template<int N, int CPL>
__global__ __launch_bounds__(256) void knn_radix_kernel(const float* __restrict__ verts,
                                                        int* __restrict__ nbr) {
    __shared__ float sv[N * 3];
    __shared__ int hist[4][256];
    __shared__ unsigned long long coll[4][COLL_CAP];
    __shared__ int cnt[4];

    constexpr int RPB = 16;
    int bpb = N / RPB;
    int b = blockIdx.x / bpb;
    int rbase = (blockIdx.x % bpb) * RPB;

    const float* vb = verts + (size_t)b * N * 3;
    for (int t = threadIdx.x; t < N * 3; t += 256) sv[t] = vb[t];
    __syncthreads();

    int wid = threadIdx.x >> 6, lane = threadIdx.x & 63;
    int* myhist = hist[wid];
    unsigned long long* mycoll = coll[wid];

    for (int rr = 0; rr < 4; rr++) {
        int i = rbase + wid * 4 + rr;
        float vx = sv[i * 3 + 0], vy = sv[i * 3 + 1], vz = sv[i * 3 + 2];
        float qi = vx * vx + vy * vy + vz * vz;

        unsigned key[CPL];
        #pragma unroll
        for (int t = 0; t < CPL; t++) {
            int j = lane + 64 * t;
            float xj = sv[j * 3 + 0], yj = sv[j * 3 + 1], zj = sv[j * 3 + 2];
            float inner = vx * xj + vy * yj + vz * zj;
            float qj = xj * xj + yj * yj + zj * zj;
            float dist = (-2.0f * inner + qi) + qj;
            unsigned u = __float_as_uint(dist);
            u = (u & 0x80000000u) ? ~u : (u | 0x80000000u);
            key[t] = (j == i) ? 0xFFFFFFFFu : u;
        }

        #pragma unroll
        for (int q = 0; q < 4; q++) myhist[lane * 4 + q] = 0;
        __asm__ volatile("s_waitcnt lgkmcnt(0)" ::: "memory");
        #pragma unroll
        for (int t = 0; t < CPL; t++) atomicAdd(&myhist[key[t] >> 24], 1);
        __asm__ volatile("s_waitcnt lgkmcnt(0)" ::: "memory");

        int B1 = 255, below1 = 0;
        {
            int P = 0;
            for (int bb = 0; bb < 256; bb++) {
                int c = myhist[bb];
                if (P + c >= NN) { B1 = bb; below1 = P; break; }
                P += c;
            }
        }

        #pragma unroll
        for (int q = 0; q < 4; q++) myhist[lane * 4 + q] = 0;
        __asm__ volatile("s_waitcnt lgkmcnt(0)" ::: "memory");
        #pragma unroll
        for (int t = 0; t < CPL; t++)
            if ((int)(key[t] >> 24) == B1) atomicAdd(&myhist[(key[t] >> 16) & 0xFF], 1);
        __asm__ volatile("s_waitcnt lgkmcnt(0)" ::: "memory");

        int B2 = 255;
        {
            int P = 0, r1 = NN - below1;
            for (int bb = 0; bb < 256; bb++) {
                int c = myhist[bb];
                if (P + c >= r1) { B2 = bb; break; }
                P += c;
            }
        }

        if (lane == 0) cnt[wid] = 0;
        __asm__ volatile("s_waitcnt lgkmcnt(0)" ::: "memory");
        #pragma unroll
        for (int t = 0; t < CPL; t++) {
            unsigned mk = key[t];
            int hb = (int)(mk >> 24), sb = (int)((mk >> 16) & 0xFF);
            bool take = (hb < B1) || (hb == B1 && sb <= B2);
            if (take) {
                int pos = atomicAdd(&cnt[wid], 1);
                if (pos < COLL_CAP)
                    mycoll[pos] = ((unsigned long long)mk << 32) | (unsigned)(lane + 64 * t);
            }
        }
        __asm__ volatile("s_waitcnt lgkmcnt(0)" ::: "memory");
        int count = cnt[wid];
        if (count > COLL_CAP) count = COLL_CAP;

        int* dst = nbr + ((size_t)b * N + i) * NN;
        for (int e = lane; e < count; e += 64) {
            unsigned long long me = mycoll[e];
            int rank = 0;
            for (int m = 0; m < count; m++) rank += (mycoll[m] < me);
            if (rank < NN) dst[rank] = (int)(me & 0xFFFFFFFFull);
        }
    }
}

// ---------------------------------------------------------------------------
// K2: operator3d + relu -> fm0 (8,2048,32). One thread per vertex.
// ---------------------------------------------------------------------------
__global__ __launch_bounds__(256) void op3d_kernel(const float* __restrict__ verts,
                                                   const int* __restrict__ nbr,
                                                   const float* __restrict__ w0w,
                                                   const float* __restrict__ w0d,
                                                   float* __restrict__ fm0) {
    __shared__ float swd[3 * SUP * K0];
    __shared__ float sww[SUP * K0];
    for (int t = threadIdx.x; t < 3 * SUP * K0; t += 256) swd[t] = w0d[t];
    for (int t = threadIdx.x; t < SUP * K0; t += 256) sww[t] = w0w[t];
    __syncthreads();

    int gid = blockIdx.x * 256 + threadIdx.x;
    int b = gid >> 11, v = gid & (NV - 1);
    const float* vb = verts + b * NV * 3;
    float vx = vb[v * 3], vy = vb[v * 3 + 1], vz = vb[v * 3 + 2];

    const int* nb = nbr + gid * NN;
    float dx[NN], dy[NN], dz[NN];
    #pragma unroll
    for (int n = 0; n < NN; n++) {
        int j = nb[n];
        dx[n] = vb[j * 3 + 0] - vx;
        dy[n] = vb[j * 3 + 1] - vy;
        dz[n] = vb[j * 3 + 2] - vz;
    }
    float* out = fm0 + gid * K0;
    #pragma unroll 1
    for (int k = 0; k < K0; k++) {
        float acc = 0.f;
        #pragma unroll
        for (int s = 0; s < SUP; s++) {
            float w0 = swd[0 * 224 + s * K0 + k];
            float w1 = swd[1 * 224 + s * K0 + k];
            float w2 = swd[2 * 224 + s * K0 + k];
            float m = 0.f;
            #pragma unroll
            for (int n = 0; n < NN; n++) {
                float t = dx[n] * w0 + dy[n] * w1 + dz[n] * w2;
                t = fmaxf(t, 0.f);
                m = fmaxf(m, t);
            }
            acc += m * sww[s * K0 + k];
        }
        out[k] = fmaxf(acc, 0.f);
    }
}

// ---------------------------------------------------------------------------
// K4: FUSED operator_nd #1 (+relu) -> fm1. Weights in LDS; k-outer loop so
// each per-lane sw read is amortized over NN=20 neighbors (fs[] in regs).
// Per-accumulator FP order unchanged (k ascending) => bit-identical.
// ---------------------------------------------------------------------------
__global__ __launch_bounds__(256, 2) void opnd1_fused(const float* __restrict__ verts,
                                                      const int* __restrict__ nbr,
                                                      const float* __restrict__ fm0,
                                                      const float* __restrict__ w1w,
                                                      const float* __restrict__ w1b,
                                                      const float* __restrict__ w1d,
                                                      float* __restrict__ fm1) {
    __shared__ float swd[3 * SUP * C1];
    __shared__ float sm[4][21][K0];
    __shared__ float sw[K0 * C1];
    for (int t = threadIdx.x; t < 3 * SUP * C1; t += 256) swd[t] = w1d[t];

    int wid = threadIdx.x >> 6, lane = threadIdx.x & 63;
    int vtx = blockIdx.x * 4 + wid;
    int b = vtx >> 11, v = vtx & (NV - 1);
    const float* vb = verts + b * NV * 3;
    const int* nb = nbr + vtx * NN;
    const float* f0b = fm0 + (size_t)b * NV * K0;

    for (int t = lane; t < 21 * K0; t += 64) {
        int row = t >> 5, k = t & 31;
        int j = (row < NN) ? nb[row] : v;
        sm[wid][row][k] = f0b[j * K0 + k];
    }
    float vx = vb[v * 3], vy = vb[v * 3 + 1], vz = vb[v * 3 + 2];
    float dx[NN], dy[NN], dz[NN];
    #pragma unroll
    for (int n = 0; n < NN; n++) {
        int j = nb[n];
        dx[n] = vb[j * 3 + 0] - vx;
        dy[n] = vb[j * 3 + 1] - vy;
        dz[n] = vb[j * 3 + 2] - vz;
    }

    float fcen = 0.f;
    float total = 0.f;
    #pragma unroll 1
    for (int blk = 0; blk < 8; blk++) {
        __syncthreads();
        int colbase = blk * C1;
        for (int t = threadIdx.x; t < K0 * C1; t += 256) {
            sw[t] = w1w[(t >> 6) * (8 * C1) + colbase + (t & 63)];
        }
        __syncthreads();
        if (blk == 0) {
            float f = w1b[lane];
            #pragma unroll
            for (int k = 0; k < K0; k++) f += sm[wid][20][k] * sw[k * C1 + lane];
            fcen = f;
        } else {
            int ss = blk - 1;
            float bs = w1b[C1 + ss * C1 + lane];
            float fs[NN];
            #pragma unroll
            for (int n = 0; n < NN; n++) fs[n] = bs;
            #pragma unroll 1
            for (int k = 0; k < K0; k++) {
                float wk = sw[k * C1 + lane];
                #pragma unroll
                for (int n = 0; n < NN; n++) fs[n] += sm[wid][n][k] * wk;
            }
            float w0 = swd[0 * (SUP * C1) + ss * C1 + lane];
            float w1 = swd[1 * (SUP * C1) + ss * C1 + lane];
            float w2 = swd[2 * (SUP * C1) + ss * C1 + lane];
            float m = -3.4e38f;
            #pragma unroll
            for (int n = 0; n < NN; n++) {
                float th = fmaxf(dx[n] * w0 + dy[n] * w1 + dz[n] * w2, 0.f);
                m = fmaxf(m, th * fs[n]);
            }
            total += m;
        }
    }
    fm1[vtx * C1 + lane] = fmaxf(fcen + total, 0.f);
}

// ---------------------------------------------------------------------------
// K8: FUSED operator_nd #2 (+relu) -> fm2. Same k-outer amortization.
// ---------------------------------------------------------------------------
__global__ __launch_bounds__(256, 2) void opnd2_fused(const float* __restrict__ v1,
                                                      const int* __restrict__ nbr2,
                                                      const float* __restrict__ fm1p,
                                                      const float* __restrict__ w2w,
                                                      const float* __restrict__ w2b,
                                                      const float* __restrict__ w2d,
                                                      float* __restrict__ fm2) {
    __shared__ float swd[3 * SUP * C2];
    __shared__ float sm[4][21][C1];
    __shared__ float sw[C1 * 64];
    for (int t = threadIdx.x; t < 3 * SUP * C2; t += 256) swd[t] = w2d[t];

    int wid = threadIdx.x >> 6, lane = threadIdx.x & 63;
    int vtx = blockIdx.x * 4 + wid;
    int b = vtx >> 8, v = vtx & (NV2 - 1);
    const float* vb = v1 + b * NV2 * 3;
    const int* nb = nbr2 + vtx * NN;
    const float* f1b = fm1p + (size_t)b * NV2 * C1;

    for (int t = lane; t < 21 * C1; t += 64) {
        int row = t >> 6, k = t & 63;
        int j = (row < NN) ? nb[row] : v;
        sm[wid][row][k] = f1b[j * C1 + k];
    }
    float vx = vb[v * 3], vy = vb[v * 3 + 1], vz = vb[v * 3 + 2];
    float dx[NN], dy[NN], dz[NN];
    #pragma unroll
    for (int n = 0; n < NN; n++) {
        int j = nb[n];
        dx[n] = vb[j * 3 + 0] - vx;
        dy[n] = vb[j * 3 + 1] - vy;
        dz[n] = vb[j * 3 + 2] - vz;
    }

    #pragma unroll 1
    for (int jj = 0; jj < 4; jj++) {
        int cj = jj * 64 + lane;
        float fcen = 0.f;
        float total = 0.f;
        #pragma unroll 1
        for (int blk = 0; blk < 8; blk++) {
            __syncthreads();
            int colbase = (blk == 0) ? (jj * 64) : (C2 + (blk - 1) * C2 + jj * 64);
            for (int t = threadIdx.x; t < C1 * 64; t += 256) {
                sw[t] = w2w[(t >> 6) * (8 * C2) + colbase + (t & 63)];
            }
            __syncthreads();
            if (blk == 0) {
                float f = w2b[cj];
                #pragma unroll 4
                for (int k = 0; k < C1; k++) f += sm[wid][20][k] * sw[k * 64 + lane];
                fcen = f;
            } else {
                int ss = blk - 1;
                float bs = w2b[C2 + ss * C2 + cj];
                float fs[NN];
                #pragma unroll
                for (int n = 0; n < NN; n++) fs[n] = bs;
                #pragma unroll 1
                for (int k = 0; k < C1; k++) {
                    float wk = sw[k * 64 + lane];
                    #pragma unroll
                    for (int n = 0; n < NN; n++) fs[n] += sm[wid][n][k] * wk;
                }
                float w0 = swd[0 * (SUP * C2) + ss * C2 + cj];
                float w1 = swd[1 * (SUP * C2) + ss * C2 + cj];
                float w2 = swd[2 * (SUP * C2) + ss * C2 + cj];
                float m = -3.4e38f;
                #pragma unroll
                for (int n = 0; n < NN; n++) {
                    float th = fmaxf(dx[n] * w0 + dy[n] * w1 + dz[n] * w2, 0.f);
                    m = fmaxf(m, th * fs[n]);
                }
                total += m;
            }
        }
        fm2[vtx * C2 + cj] = fmaxf(fcen + total, 0.f);
    }
}

// ---------------------------------------------------------------------------
// K5: pooling 1 -> v1, fm1p. One wave per sampled vertex.
// ---------------------------------------------------------------------------
__global__ __launch_bounds__(256) void pool1_kernel(const float* __restrict__ verts,
                                                    const int* __restrict__ nbr1,
                                                    const float* __restrict__ fm1,
                                                    float* __restrict__ v1,
                                                    float* __restrict__ fm1p,
                                                    PermArg1 pa) {
    int wid = threadIdx.x >> 6, lane = threadIdx.x & 63;
    int gid = blockIdx.x * 4 + wid;
    int b = gid >> 8, p = gid & 255;
    int sv = pa.v[p];
    const int* nb = nbr1 + (b * NV + sv) * NN;
    float m = -3.4e38f;
    #pragma unroll
    for (int n = 0; n < 8; n++) {
        m = fmaxf(m, fm1[(b * NV + nb[n]) * C1 + lane]);
    }
    fm1p[gid * C1 + lane] = m;
    if (lane < 3) v1[gid * 3 + lane] = verts[(b * NV + sv) * 3 + lane];
}

// ---------------------------------------------------------------------------
// K9: pooling 2 -> fm3 (outputs[1]) — f32
// ---------------------------------------------------------------------------
__global__ __launch_bounds__(256) void pool2_kernel(const int* __restrict__ nbr2,
                                                    const float* __restrict__ fm2,
                                                    float* __restrict__ out,
                                                    PermArg2 pa) {
    int wid = threadIdx.x >> 6, lane = threadIdx.x & 63;
    int gid = blockIdx.x * 4 + wid;
    int b = gid >> 4, p = gid & 15;
    int sv = pa.v[p];
    const int* nb = nbr2 + (b * NV2 + sv) * NN;
    #pragma unroll 1
    for (int jj = 0; jj < 4; jj++) {
        int c = lane + jj * 64;
        float m = -3.4e38f;
        #pragma unroll
        for (int n = 0; n < 16; n++) {
            m = fmaxf(m, fm2[(b * NV2 + nb[n]) * C2 + c]);
        }
        out[NB * NP2 * 3 + gid * C2 + c] = m;
    }
}

// ---------------------------------------------------------------------------
// Launch
// ---------------------------------------------------------------------------
extern "C" void kernel_launch(void* const* d_in, const int* in_sizes, int n_in,
                              void* d_out, int out_size, void* d_ws, size_t ws_size,
                              hipStream_t stream) {
    (void)in_sizes; (void)n_in; (void)out_size; (void)ws_size;
    const float* verts = (const float*)d_in[0];
    const float* w0w = (const float*)d_in[1];
    const float* w0d = (const float*)d_in[2];
    const float* w1w = (const float*)d_in[3];
    const float* w1b = (const float*)d_in[4];
    const float* w1d = (const float*)d_in[5];
    const float* w2w = (const float*)d_in[6];
    const float* w2b = (const float*)d_in[7];
    const float* w2d = (const float*)d_in[8];
    float* out = (float*)d_out;

    static const PermOut perms = compute_perms();

    PermArg1 pa1;
    PermArg2 pa2, pac;
    memcpy(pa1.v, perms.p1, sizeof(pa1.v));
    memcpy(pa2.v, perms.p2, sizeof(pa2.v));
    for (int j = 0; j < 16; j++) pac.v[j] = perms.p1[perms.p2[j]];

    char* ws = (char*)d_ws;
    size_t off = 0;
    auto alloc = [&](size_t bytes) -> void* {
        void* p = ws + off;
        off += (bytes + 255) & ~(size_t)255;
        return p;
    };
    int*   nbr1 = (int*)  alloc((size_t)NB * NV * NN * 4);
    float* fm0  = (float*)alloc((size_t)NB * NV * K0 * 4);
    float* fm1  = (float*)alloc((size_t)NB * NV * C1 * 4);
    float* v1   = (float*)alloc((size_t)NB * NV2 * 3 * 4);
    float* fm1p = (float*)alloc((size_t)NB * NV2 * C1 * 4);
    int*   nbr2 = (int*)  alloc((size_t)NB * NV2 * NN * 4);
    float* fm2  = (float*)alloc((size_t)NB * NV2 * C2 * 4);

    v2_kernel<<<1, 384, 0, stream>>>(verts, out, pac);
    knn_radix_kernel<NV, NV / 64><<<NB * (NV / 16), 256, 0, stream>>>(verts, nbr1);
    op3d_kernel<<<64, 256, 0, stream>>>(verts, nbr1, w0w, w0d, fm0);
    opnd1_fused<<<NB * NV / 4, 256, 0, stream>>>(verts, nbr1, fm0, w1w, w1b, w1d, fm1);
    pool1_kernel<<<NB * NV2 / 4, 256, 0, stream>>>(verts, nbr1, fm1, v1, fm1p, pa1);
    knn_radix_kernel<NV2, NV2 / 64><<<NB * (NV2 / 16), 256, 0, stream>>>(v1, nbr2);
    opnd2_fused<<<NB * NV2 / 4, 256, 0, stream>>>(v1, nbr2, fm1p, w2w, w2b, w2d, fm2);
    pool2_kernel<<<32, 256, 0, stream>>>(nbr2, fm2, out, pa2);
}

// Round 26
// 780.522 us; speedup vs baseline: 7.2190x; 1.6303x over previous
//
#include <hip/hip_runtime.h>
#include <hip/hip_bf16.h>
#include <stdint.h>
#include <string.h>

// ---------------------------------------------------------------------------
// Problem constants
// ---------------------------------------------------------------------------
#define NB   8
#define NV   2048
#define NN   20      // NEIGHBOR_NUM
#define SUP  7       // SUPPORT
#define K0   32
#define C1   64
#define C2   256
#define NV2  256     // vertices after pooling 1
#define NP2  16      // vertices after pooling 2
#define COLL_CAP 512

// ---------------------------------------------------------------------------
// Permutations: PCG64 + masked rejection + subtract-mix SeedSequence —
// proven correct end-to-end (R21..R25 passed).
// ---------------------------------------------------------------------------
typedef unsigned __int128 u128;

struct CPcg { u128 state; u128 inc; bool has32; uint32_t cached; };

constexpr u128 PCG_MULT = (((u128)2549297995355413924ULL) << 64) | 4865540595714422341ULL;

constexpr uint64_t c_rotr64(uint64_t v, unsigned r) {
    return (v >> (r & 63u)) | (v << ((64u - r) & 63u));
}
constexpr uint64_t pcg_next64(CPcg& g) {
    g.state = g.state * PCG_MULT + g.inc;
    uint64_t hi = (uint64_t)(g.state >> 64);
    uint64_t lo = (uint64_t)g.state;
    return c_rotr64(hi ^ lo, (unsigned)(hi >> 58));
}
constexpr uint32_t pcg_next32(CPcg& g) {
    if (g.has32) { g.has32 = false; return g.cached; }
    uint64_t n = pcg_next64(g);
    g.has32 = true;
    g.cached = (uint32_t)(n >> 32);
    return (uint32_t)n;
}
constexpr uint64_t rand_interval(CPcg& g, uint64_t mx) {
    if (mx == 0) return 0;
    uint64_t mask = mx;
    mask |= mask >> 1; mask |= mask >> 2; mask |= mask >> 4;
    mask |= mask >> 8; mask |= mask >> 16; mask |= mask >> 32;
    uint64_t v = 0;
    while ((v = ((uint64_t)pcg_next32(g) & mask)) > mx) {
    }
    return v;
}
constexpr uint32_t hashmix(uint32_t value, uint32_t& hc) {
    value ^= hc; hc *= 0x931e8875u; value *= hc; value ^= value >> 16; return value;
}
constexpr uint32_t mixpool(uint32_t x, uint32_t y) {
    uint32_t r = (x * 0xca01f9ddu) - (y * 0x4973f715u);
    r ^= r >> 16; return r;
}
constexpr CPcg make_rng(uint32_t entropy) {
    uint32_t pool[4] = {0, 0, 0, 0};
    uint32_t hc = 0x43b0d7e5u;
    for (int i = 0; i < 4; i++) {
        uint32_t v = (i == 0) ? entropy : 0u;
        pool[i] = hashmix(v, hc);
    }
    for (int isrc = 0; isrc < 4; isrc++)
        for (int idst = 0; idst < 4; idst++)
            if (isrc != idst) pool[idst] = mixpool(pool[idst], hashmix(pool[isrc], hc));
    uint32_t w[8] = {};
    uint32_t hb = 0x8b51f9ddu;
    for (int i = 0; i < 8; i++) {
        uint32_t dv = pool[i & 3];
        dv ^= hb; hb *= 0x58f38dedu; dv *= hb; dv ^= dv >> 16; w[i] = dv;
    }
    uint64_t sd[4] = {};
    for (int k = 0; k < 4; k++) sd[k] = (uint64_t)w[2 * k] | ((uint64_t)w[2 * k + 1] << 32);
    u128 s = (((u128)sd[0]) << 64) | sd[1];
    u128 iq = (((u128)sd[2]) << 64) | sd[3];
    CPcg g{};
    g.state = 0;
    g.inc = (iq << 1) | 1;
    g.state = g.state * PCG_MULT + g.inc;
    g.state += s;
    g.state = g.state * PCG_MULT + g.inc;
    g.has32 = false; g.cached = 0;
    return g;
}

struct PermOut { int p1[256]; int p2[16]; };

constexpr PermOut compute_perms() {
    PermOut o{};
    {
        CPcg g = make_rng(1u);
        int arr[2048] = {};
        for (int i = 0; i < 2048; i++) arr[i] = i;
        for (int i = 2047; i >= 1; i--) {
            int j = (int)rand_interval(g, (uint64_t)i);
            int t = arr[i]; arr[i] = arr[j]; arr[j] = t;
        }
        for (int i = 0; i < 256; i++) o.p1[i] = arr[i];
    }
    {
        CPcg g = make_rng(2u);
        int arr[256] = {};
        for (int i = 0; i < 256; i++) arr[i] = i;
        for (int i = 255; i >= 1; i--) {
            int j = (int)rand_interval(g, (uint64_t)i);
            int t = arr[i]; arr[i] = arr[j]; arr[j] = t;
        }
        for (int i = 0; i < 16; i++) o.p2[i] = arr[i];
    }
    return o;
}

struct PermArg1 { int v[256]; };
struct PermArg2 { int v[16]; };

// ---------------------------------------------------------------------------
// K0: v2 (outputs[0]) = verts[:, p1[p2[j]], :] — f32
// ---------------------------------------------------------------------------
__global__ __launch_bounds__(384) void v2_kernel(const float* __restrict__ verts,
                                                 float* __restrict__ out,
                                                 PermArg2 cidx) {
    int t = threadIdx.x;  // 0..383
    if (t < NB * NP2 * 3) {
        int b = t / (NP2 * 3);
        int rem = t - b * (NP2 * 3);
        int j = rem / 3;
        int c = rem - j * 3;
        out[t] = verts[(b * NV + cidx.v[j]) * 3 + c];
    }
}

// ---------------------------------------------------------------------------
// KNN via exact wave-per-row LINEAR-BUCKET select: wave min/max of mapped
// keys, 256 linear buckets (monotone map => bucket order == key order), one
// histogram pass, 6-step shuffle scan for the rank-20 boundary, collect
// bins <= boundary (superset), exact (dist, idx) rank pass. Output identical
// to R22/R24 semantics.
// ---------------------------------------------------------------------------
template<int N, int CPL>
__global__ __launch_bounds__(256) void knn_bucket_kernel(const float* __restrict__ verts,
                                                         int* __restrict__ nbr) {
    __shared__ float sv[N * 3];
    __shared__ int hist[4][256];
    __shared__ unsigned long long coll[4][COLL_CAP];
    __shared__ int cnt[4];

    constexpr int RPB = 16;
    int bpb = N / RPB;
    int b = blockIdx.x / bpb;
    int rbase = (blockIdx.x % bpb) * RPB;

    const float* vb = verts + (size_t)b * N * 3;
    for (int t = threadIdx.x; t < N * 3; t += 256) sv[t] = vb[t];
    __syncthreads();

    int wid = threadIdx.x >> 6, lane = threadIdx.x & 63;
    int* myhist = hist[wid];
    unsigned long long* mycoll = coll[wid];

    for (int rr = 0; rr < 4; rr++) {
        int i = rbase + wid * 4 + rr;
        float vx = sv[i * 3 + 0], vy = sv[i * 3 + 1], vz = sv[i * 3 + 2];
        float qi = vx * vx + vy * vy + vz * vz;

        unsigned key[CPL];
        unsigned lmin = 0xFFFFFFFFu, lmax = 0u;
        #pragma unroll
        for (int t = 0; t < CPL; t++) {
            int j = lane + 64 * t;
            float xj = sv[j * 3 + 0], yj = sv[j * 3 + 1], zj = sv[j * 3 + 2];
            float inner = vx * xj + vy * yj + vz * zj;
            float qj = xj * xj + yj * yj + zj * zj;
            float dist = (-2.0f * inner + qi) + qj;   // same expr as reference
            unsigned u = __float_as_uint(dist);
            u = (u & 0x80000000u) ? ~u : (u | 0x80000000u);  // monotone map
            if (j == i) u = 0xFFFFFFFFu;                      // self sentinel
            key[t] = u;
            if (u != 0xFFFFFFFFu) {
                lmin = (u < lmin) ? u : lmin;
                lmax = (u > lmax) ? u : lmax;
            }
        }
        // wave min/max (6 shuffle steps each)
        #pragma unroll
        for (int off = 32; off >= 1; off >>= 1) {
            unsigned o1 = (unsigned)__shfl_xor((int)lmin, off);
            unsigned o2 = (unsigned)__shfl_xor((int)lmax, off);
            lmin = (o1 < lmin) ? o1 : lmin;
            lmax = (o2 > lmax) ? o2 : lmax;
        }
        float scale = (lmax > lmin) ? 255.0f / (float)(lmax - lmin) : 0.0f;

        // zero + histogram (one pass, linear bins)
        #pragma unroll
        for (int q = 0; q < 4; q++) myhist[lane * 4 + q] = 0;
        __asm__ volatile("s_waitcnt lgkmcnt(0)" ::: "memory");
        int bins[CPL];
        #pragma unroll
        for (int t = 0; t < CPL; t++) {
            int bi = (key[t] == 0xFFFFFFFFu) ? 255
                     : (int)((float)(key[t] - lmin) * scale);
            bi = (bi > 255) ? 255 : bi;
            bins[t] = bi;
            atomicAdd(&myhist[bi], 1);
        }
        __asm__ volatile("s_waitcnt lgkmcnt(0)" ::: "memory");

        // wave-parallel boundary search: lane owns bins 4l..4l+3
        int h0 = myhist[lane * 4 + 0];
        int h1 = myhist[lane * 4 + 1];
        int h2 = myhist[lane * 4 + 2];
        int h3 = myhist[lane * 4 + 3];
        int s = h0 + h1 + h2 + h3;
        int cum = s;
        #pragma unroll
        for (int off = 1; off < 64; off <<= 1) {
            int v = __shfl_up(cum, off);
            if (lane >= off) cum += v;
        }
        unsigned long long bal = __ballot(cum >= NN);
        int L = __ffsll((long long)bal) - 1;   // first lane reaching rank NN
        int baseL = __shfl(cum, L) - __shfl(s, L);
        int g0 = __shfl(h0, L), g1 = __shfl(h1, L), g2 = __shfl(h2, L);
        int B;
        if (baseL + g0 >= NN)            B = 4 * L + 0;
        else if (baseL + g0 + g1 >= NN)  B = 4 * L + 1;
        else if (baseL + g0 + g1 + g2 >= NN) B = 4 * L + 2;
        else                              B = 4 * L + 3;

        // collect bins <= B
        if (lane == 0) cnt[wid] = 0;
        __asm__ volatile("s_waitcnt lgkmcnt(0)" ::: "memory");
        #pragma unroll
        for (int t = 0; t < CPL; t++) {
            if (bins[t] <= B) {
                int pos = atomicAdd(&cnt[wid], 1);
                if (pos < COLL_CAP)
                    mycoll[pos] = ((unsigned long long)key[t] << 32) | (unsigned)(lane + 64 * t);
            }
        }
        __asm__ volatile("s_waitcnt lgkmcnt(0)" ::: "memory");
        int count = cnt[wid];
        if (count > COLL_CAP) count = COLL_CAP;

        // exact rank pass
        int* dst = nbr + ((size_t)b * N + i) * NN;
        for (int e = lane; e < count; e += 64) {
            unsigned long long me = mycoll[e];
            int rank = 0;
            for (int m = 0; m < count; m++) rank += (mycoll[m] < me);
            if (rank < NN) dst[rank] = (int)(me & 0xFFFFFFFFull);
        }
    }
}

// ---------------------------------------------------------------------------
// K2: operator3d + relu -> fm0 (8,2048,32). One thread per vertex.
// ---------------------------------------------------------------------------
__global__ __launch_bounds__(256) void op3d_kernel(const float* __restrict__ verts,
                                                   const int* __restrict__ nbr,
                                                   const float* __restrict__ w0w,
                                                   const float* __restrict__ w0d,
                                                   float* __restrict__ fm0) {
    __shared__ float swd[3 * SUP * K0];
    __shared__ float sww[SUP * K0];
    for (int t = threadIdx.x; t < 3 * SUP * K0; t += 256) swd[t] = w0d[t];
    for (int t = threadIdx.x; t < SUP * K0; t += 256) sww[t] = w0w[t];
    __syncthreads();

    int gid = blockIdx.x * 256 + threadIdx.x;
    int b = gid >> 11, v = gid & (NV - 1);
    const float* vb = verts + b * NV * 3;
    float vx = vb[v * 3], vy = vb[v * 3 + 1], vz = vb[v * 3 + 2];

    const int* nb = nbr + gid * NN;
    float dx[NN], dy[NN], dz[NN];
    #pragma unroll
    for (int n = 0; n < NN; n++) {
        int j = nb[n];
        dx[n] = vb[j * 3 + 0] - vx;
        dy[n] = vb[j * 3 + 1] - vy;
        dz[n] = vb[j * 3 + 2] - vz;
    }
    float* out = fm0 + gid * K0;
    #pragma unroll 1
    for (int k = 0; k < K0; k++) {
        float acc = 0.f;
        #pragma unroll
        for (int s = 0; s < SUP; s++) {
            float w0 = swd[0 * 224 + s * K0 + k];
            float w1 = swd[1 * 224 + s * K0 + k];
            float w2 = swd[2 * 224 + s * K0 + k];
            float m = 0.f;
            #pragma unroll
            for (int n = 0; n < NN; n++) {
                float t = dx[n] * w0 + dy[n] * w1 + dz[n] * w2;
                t = fmaxf(t, 0.f);
                m = fmaxf(m, t);
            }
            acc += m * sww[s * K0 + k];
        }
        out[k] = fmaxf(acc, 0.f);
    }
}

// ---------------------------------------------------------------------------
// K4: FUSED operator_nd #1 (+relu) -> fm1 (k-outer LDS-amortized, R25 proven)
// ---------------------------------------------------------------------------
__global__ __launch_bounds__(256, 2) void opnd1_fused(const float* __restrict__ verts,
                                                      const int* __restrict__ nbr,
                                                      const float* __restrict__ fm0,
                                                      const float* __restrict__ w1w,
                                                      const float* __restrict__ w1b,
                                                      const float* __restrict__ w1d,
                                                      float* __restrict__ fm1) {
    __shared__ float swd[3 * SUP * C1];
    __shared__ float sm[4][21][K0];
    __shared__ float sw[K0 * C1];
    for (int t = threadIdx.x; t < 3 * SUP * C1; t += 256) swd[t] = w1d[t];

    int wid = threadIdx.x >> 6, lane = threadIdx.x & 63;
    int vtx = blockIdx.x * 4 + wid;
    int b = vtx >> 11, v = vtx & (NV - 1);
    const float* vb = verts + b * NV * 3;
    const int* nb = nbr + vtx * NN;
    const float* f0b = fm0 + (size_t)b * NV * K0;

    for (int t = lane; t < 21 * K0; t += 64) {
        int row = t >> 5, k = t & 31;
        int j = (row < NN) ? nb[row] : v;
        sm[wid][row][k] = f0b[j * K0 + k];
    }
    float vx = vb[v * 3], vy = vb[v * 3 + 1], vz = vb[v * 3 + 2];
    float dx[NN], dy[NN], dz[NN];
    #pragma unroll
    for (int n = 0; n < NN; n++) {
        int j = nb[n];
        dx[n] = vb[j * 3 + 0] - vx;
        dy[n] = vb[j * 3 + 1] - vy;
        dz[n] = vb[j * 3 + 2] - vz;
    }

    float fcen = 0.f;
    float total = 0.f;
    #pragma unroll 1
    for (int blk = 0; blk < 8; blk++) {
        __syncthreads();
        int colbase = blk * C1;
        for (int t = threadIdx.x; t < K0 * C1; t += 256) {
            sw[t] = w1w[(t >> 6) * (8 * C1) + colbase + (t & 63)];
        }
        __syncthreads();
        if (blk == 0) {
            float f = w1b[lane];
            #pragma unroll
            for (int k = 0; k < K0; k++) f += sm[wid][20][k] * sw[k * C1 + lane];
            fcen = f;
        } else {
            int ss = blk - 1;
            float bs = w1b[C1 + ss * C1 + lane];
            float fs[NN];
            #pragma unroll
            for (int n = 0; n < NN; n++) fs[n] = bs;
            #pragma unroll 1
            for (int k = 0; k < K0; k++) {
                float wk = sw[k * C1 + lane];
                #pragma unroll
                for (int n = 0; n < NN; n++) fs[n] += sm[wid][n][k] * wk;
            }
            float w0 = swd[0 * (SUP * C1) + ss * C1 + lane];
            float w1 = swd[1 * (SUP * C1) + ss * C1 + lane];
            float w2 = swd[2 * (SUP * C1) + ss * C1 + lane];
            float m = -3.4e38f;
            #pragma unroll
            for (int n = 0; n < NN; n++) {
                float th = fmaxf(dx[n] * w0 + dy[n] * w1 + dz[n] * w2, 0.f);
                m = fmaxf(m, th * fs[n]);
            }
            total += m;
        }
    }
    fm1[vtx * C1 + lane] = fmaxf(fcen + total, 0.f);
}

// ---------------------------------------------------------------------------
// K8: FUSED operator_nd #2 (+relu) -> fm2 (k-outer LDS-amortized, R25 proven)
// ---------------------------------------------------------------------------
__global__ __launch_bounds__(256, 2) void opnd2_fused(const float* __restrict__ v1,
                                                      const int* __restrict__ nbr2,
                                                      const float* __restrict__ fm1p,
                                                      const float* __restrict__ w2w,
                                                      const float* __restrict__ w2b,
                                                      const float* __restrict__ w2d,
                                                      float* __restrict__ fm2) {
    __shared__ float swd[3 * SUP * C2];
    __shared__ float sm[4][21][C1];
    __shared__ float sw[C1 * 64];
    for (int t = threadIdx.x; t < 3 * SUP * C2; t += 256) swd[t] = w2d[t];

    int wid = threadIdx.x >> 6, lane = threadIdx.x & 63;
    int vtx = blockIdx.x * 4 + wid;
    int b = vtx >> 8, v = vtx & (NV2 - 1);
    const float* vb = v1 + b * NV2 * 3;
    const int* nb = nbr2 + vtx * NN;
    const float* f1b = fm1p + (size_t)b * NV2 * C1;

    for (int t = lane; t < 21 * C1; t += 64) {
        int row = t >> 6, k = t & 63;
        int j = (row < NN) ? nb[row] : v;
        sm[wid][row][k] = f1b[j * C1 + k];
    }
    float vx = vb[v * 3], vy = vb[v * 3 + 1], vz = vb[v * 3 + 2];
    float dx[NN], dy[NN], dz[NN];
    #pragma unroll
    for (int n = 0; n < NN; n++) {
        int j = nb[n];
        dx[n] = vb[j * 3 + 0] - vx;
        dy[n] = vb[j * 3 + 1] - vy;
        dz[n] = vb[j * 3 + 2] - vz;
    }

    #pragma unroll 1
    for (int jj = 0; jj < 4; jj++) {
        int cj = jj * 64 + lane;
        float fcen = 0.f;
        float total = 0.f;
        #pragma unroll 1
        for (int blk = 0; blk < 8; blk++) {
            __syncthreads();
            int colbase = (blk == 0) ? (jj * 64) : (C2 + (blk - 1) * C2 + jj * 64);
            for (int t = threadIdx.x; t < C1 * 64; t += 256) {
                sw[t] = w2w[(t >> 6) * (8 * C2) + colbase + (t & 63)];
            }
            __syncthreads();
            if (blk == 0) {
                float f = w2b[cj];
                #pragma unroll 4
                for (int k = 0; k < C1; k++) f += sm[wid][20][k] * sw[k * 64 + lane];
                fcen = f;
            } else {
                int ss = blk - 1;
                float bs = w2b[C2 + ss * C2 + cj];
                float fs[NN];
                #pragma unroll
                for (int n = 0; n < NN; n++) fs[n] = bs;
                #pragma unroll 1
                for (int k = 0; k < C1; k++) {
                    float wk = sw[k * 64 + lane];
                    #pragma unroll
                    for (int n = 0; n < NN; n++) fs[n] += sm[wid][n][k] * wk;
                }
                float w0 = swd[0 * (SUP * C2) + ss * C2 + cj];
                float w1 = swd[1 * (SUP * C2) + ss * C2 + cj];
                float w2 = swd[2 * (SUP * C2) + ss * C2 + cj];
                float m = -3.4e38f;
                #pragma unroll
                for (int n = 0; n < NN; n++) {
                    float th = fmaxf(dx[n] * w0 + dy[n] * w1 + dz[n] * w2, 0.f);
                    m = fmaxf(m, th * fs[n]);
                }
                total += m;
            }
        }
        fm2[vtx * C2 + cj] = fmaxf(fcen + total, 0.f);
    }
}

// ---------------------------------------------------------------------------
// K5: pooling 1 -> v1, fm1p. One wave per sampled vertex.
// ---------------------------------------------------------------------------
__global__ __launch_bounds__(256) void pool1_kernel(const float* __restrict__ verts,
                                                    const int* __restrict__ nbr1,
                                                    const float* __restrict__ fm1,
                                                    float* __restrict__ v1,
                                                    float* __restrict__ fm1p,
                                                    PermArg1 pa) {
    int wid = threadIdx.x >> 6, lane = threadIdx.x & 63;
    int gid = blockIdx.x * 4 + wid;
    int b = gid >> 8, p = gid & 255;
    int sv = pa.v[p];
    const int* nb = nbr1 + (b * NV + sv) * NN;
    float m = -3.4e38f;
    #pragma unroll
    for (int n = 0; n < 8; n++) {
        m = fmaxf(m, fm1[(b * NV + nb[n]) * C1 + lane]);
    }
    fm1p[gid * C1 + lane] = m;
    if (lane < 3) v1[gid * 3 + lane] = verts[(b * NV + sv) * 3 + lane];
}

// ---------------------------------------------------------------------------
// K9: pooling 2 -> fm3 (outputs[1]) — f32
// ---------------------------------------------------------------------------
__global__ __launch_bounds__(256) void pool2_kernel(const int* __restrict__ nbr2,
                                                    const float* __restrict__ fm2,
                                                    float* __restrict__ out,
                                                    PermArg2 pa) {
    int wid = threadIdx.x >> 6, lane = threadIdx.x & 63;
    int gid = blockIdx.x * 4 + wid;
    int b = gid >> 4, p = gid & 15;
    int sv = pa.v[p];
    const int* nb = nbr2 + (b * NV2 + sv) * NN;
    #pragma unroll 1
    for (int jj = 0; jj < 4; jj++) {
        int c = lane + jj * 64;
        float m = -3.4e38f;
        #pragma unroll
        for (int n = 0; n < 16; n++) {
            m = fmaxf(m, fm2[(b * NV2 + nb[n]) * C2 + c]);
        }
        out[NB * NP2 * 3 + gid * C2 + c] = m;
    }
}

// ---------------------------------------------------------------------------
// Launch
// ---------------------------------------------------------------------------
extern "C" void kernel_launch(void* const* d_in, const int* in_sizes, int n_in,
                              void* d_out, int out_size, void* d_ws, size_t ws_size,
                              hipStream_t stream) {
    (void)in_sizes; (void)n_in; (void)out_size; (void)ws_size;
    const float* verts = (const float*)d_in[0];
    const float* w0w = (const float*)d_in[1];
    const float* w0d = (const float*)d_in[2];
    const float* w1w = (const float*)d_in[3];
    const float* w1b = (const float*)d_in[4];
    const float* w1d = (const float*)d_in[5];
    const float* w2w = (const float*)d_in[6];
    const float* w2b = (const float*)d_in[7];
    const float* w2d = (const float*)d_in[8];
    float* out = (float*)d_out;

    static const PermOut perms = compute_perms();

    PermArg1 pa1;
    PermArg2 pa2, pac;
    memcpy(pa1.v, perms.p1, sizeof(pa1.v));
    memcpy(pa2.v, perms.p2, sizeof(pa2.v));
    for (int j = 0; j < 16; j++) pac.v[j] = perms.p1[perms.p2[j]];

    char* ws = (char*)d_ws;
    size_t off = 0;
    auto alloc = [&](size_t bytes) -> void* {
        void* p = ws + off;
        off += (bytes + 255) & ~(size_t)255;
        return p;
    };
    int*   nbr1 = (int*)  alloc((size_t)NB * NV * NN * 4);
    float* fm0  = (float*)alloc((size_t)NB * NV * K0 * 4);
    float* fm1  = (float*)alloc((size_t)NB * NV * C1 * 4);
    float* v1   = (float*)alloc((size_t)NB * NV2 * 3 * 4);
    float* fm1p = (float*)alloc((size_t)NB * NV2 * C1 * 4);
    int*   nbr2 = (int*)  alloc((size_t)NB * NV2 * NN * 4);
    float* fm2  = (float*)alloc((size_t)NB * NV2 * C2 * 4);

    v2_kernel<<<1, 384, 0, stream>>>(verts, out, pac);
    knn_bucket_kernel<NV, NV / 64><<<NB * (NV / 16), 256, 0, stream>>>(verts, nbr1);
    op3d_kernel<<<64, 256, 0, stream>>>(verts, nbr1, w0w, w0d, fm0);
    opnd1_fused<<<NB * NV / 4, 256, 0, stream>>>(verts, nbr1, fm0, w1w, w1b, w1d, fm1);
    pool1_kernel<<<NB * NV2 / 4, 256, 0, stream>>>(verts, nbr1, fm1, v1, fm1p, pa1);
    knn_bucket_kernel<NV2, NV2 / 64><<<NB * (NV2 / 16), 256, 0, stream>>>(v1, nbr2);
    opnd2_fused<<<NB * NV2 / 4, 256, 0, stream>>>(v1, nbr2, fm1p, w2w, w2b, w2d, fm2);
    pool2_kernel<<<32, 256, 0, stream>>>(nbr2, fm2, out, pa2);
}

// Round 27
// 571.252 us; speedup vs baseline: 9.8636x; 1.3663x over previous
//
#include <hip/hip_runtime.h>
#include <hip/hip_bf16.h>
#include <stdint.h>
#include <string.h>

// ---------------------------------------------------------------------------
// Problem constants
// ---------------------------------------------------------------------------
#define NB   8
#define NV   2048
#define NN   20      // NEIGHBOR_NUM
#define SUP  7       // SUPPORT
#define K0   32
#define C1   64
#define C2   256
#define NV2  256     // vertices after pooling 1
#define NP2  16      // vertices after pooling 2
#define COLL_CAP 512

// ---------------------------------------------------------------------------
// Permutations (proven R21..R26)
// ---------------------------------------------------------------------------
typedef unsigned __int128 u128;

struct CPcg { u128 state; u128 inc; bool has32; uint32_t cached; };

constexpr u128 PCG_MULT = (((u128)2549297995355413924ULL) << 64) | 4865540595714422341ULL;

constexpr uint64_t c_rotr64(uint64_t v, unsigned r) {
    return (v >> (r & 63u)) | (v << ((64u - r) & 63u));
}
constexpr uint64_t pcg_next64(CPcg& g) {
    g.state = g.state * PCG_MULT + g.inc;
    uint64_t hi = (uint64_t)(g.state >> 64);
    uint64_t lo = (uint64_t)g.state;
    return c_rotr64(hi ^ lo, (unsigned)(hi >> 58));
}
constexpr uint32_t pcg_next32(CPcg& g) {
    if (g.has32) { g.has32 = false; return g.cached; }
    uint64_t n = pcg_next64(g);
    g.has32 = true;
    g.cached = (uint32_t)(n >> 32);
    return (uint32_t)n;
}
constexpr uint64_t rand_interval(CPcg& g, uint64_t mx) {
    if (mx == 0) return 0;
    uint64_t mask = mx;
    mask |= mask >> 1; mask |= mask >> 2; mask |= mask >> 4;
    mask |= mask >> 8; mask |= mask >> 16; mask |= mask >> 32;
    uint64_t v = 0;
    while ((v = ((uint64_t)pcg_next32(g) & mask)) > mx) {
    }
    return v;
}
constexpr uint32_t hashmix(uint32_t value, uint32_t& hc) {
    value ^= hc; hc *= 0x931e8875u; value *= hc; value ^= value >> 16; return value;
}
constexpr uint32_t mixpool(uint32_t x, uint32_t y) {
    uint32_t r = (x * 0xca01f9ddu) - (y * 0x4973f715u);
    r ^= r >> 16; return r;
}
constexpr CPcg make_rng(uint32_t entropy) {
    uint32_t pool[4] = {0, 0, 0, 0};
    uint32_t hc = 0x43b0d7e5u;
    for (int i = 0; i < 4; i++) {
        uint32_t v = (i == 0) ? entropy : 0u;
        pool[i] = hashmix(v, hc);
    }
    for (int isrc = 0; isrc < 4; isrc++)
        for (int idst = 0; idst < 4; idst++)
            if (isrc != idst) pool[idst] = mixpool(pool[idst], hashmix(pool[isrc], hc));
    uint32_t w[8] = {};
    uint32_t hb = 0x8b51f9ddu;
    for (int i = 0; i < 8; i++) {
        uint32_t dv = pool[i & 3];
        dv ^= hb; hb *= 0x58f38dedu; dv *= hb; dv ^= dv >> 16; w[i] = dv;
    }
    uint64_t sd[4] = {};
    for (int k = 0; k < 4; k++) sd[k] = (uint64_t)w[2 * k] | ((uint64_t)w[2 * k + 1] << 32);
    u128 s = (((u128)sd[0]) << 64) | sd[1];
    u128 iq = (((u128)sd[2]) << 64) | sd[3];
    CPcg g{};
    g.state = 0;
    g.inc = (iq << 1) | 1;
    g.state = g.state * PCG_MULT + g.inc;
    g.state += s;
    g.state = g.state * PCG_MULT + g.inc;
    g.has32 = false; g.cached = 0;
    return g;
}

struct PermOut { int p1[256]; int p2[16]; };

constexpr PermOut compute_perms() {
    PermOut o{};
    {
        CPcg g = make_rng(1u);
        int arr[2048] = {};
        for (int i = 0; i < 2048; i++) arr[i] = i;
        for (int i = 2047; i >= 1; i--) {
            int j = (int)rand_interval(g, (uint64_t)i);
            int t = arr[i]; arr[i] = arr[j]; arr[j] = t;
        }
        for (int i = 0; i < 256; i++) o.p1[i] = arr[i];
    }
    {
        CPcg g = make_rng(2u);
        int arr[256] = {};
        for (int i = 0; i < 256; i++) arr[i] = i;
        for (int i = 255; i >= 1; i--) {
            int j = (int)rand_interval(g, (uint64_t)i);
            int t = arr[i]; arr[i] = arr[j]; arr[j] = t;
        }
        for (int i = 0; i < 16; i++) o.p2[i] = arr[i];
    }
    return o;
}

struct PermArg1 { int v[256]; };
struct PermArg2 { int v[16]; };

// ---------------------------------------------------------------------------
// K0: v2 (outputs[0]) = verts[:, p1[p2[j]], :] — f32
// ---------------------------------------------------------------------------
__global__ __launch_bounds__(384) void v2_kernel(const float* __restrict__ verts,
                                                 float* __restrict__ out,
                                                 PermArg2 cidx) {
    int t = threadIdx.x;
    if (t < NB * NP2 * 3) {
        int b = t / (NP2 * 3);
        int rem = t - b * (NP2 * 3);
        int j = rem / 3;
        int c = rem - j * 3;
        out[t] = verts[(b * NV + cidx.v[j]) * 3 + c];
    }
}

// ---------------------------------------------------------------------------
// KNN via linear-bucket select (R26, proven)
// ---------------------------------------------------------------------------
template<int N, int CPL>
__global__ __launch_bounds__(256) void knn_bucket_kernel(const float* __restrict__ verts,
                                                         int* __restrict__ nbr) {
    __shared__ float sv[N * 3];
    __shared__ int hist[4][256];
    __shared__ unsigned long long coll[4][COLL_CAP];
    __shared__ int cnt[4];

    constexpr int RPB = 16;
    int bpb = N / RPB;
    int b = blockIdx.x / bpb;
    int rbase = (blockIdx.x % bpb) * RPB;

    const float* vb = verts + (size_t)b * N * 3;
    for (int t = threadIdx.x; t < N * 3; t += 256) sv[t] = vb[t];
    __syncthreads();

    int wid = threadIdx.x >> 6, lane = threadIdx.x & 63;
    int* myhist = hist[wid];
    unsigned long long* mycoll = coll[wid];

    for (int rr = 0; rr < 4; rr++) {
        int i = rbase + wid * 4 + rr;
        float vx = sv[i * 3 + 0], vy = sv[i * 3 + 1], vz = sv[i * 3 + 2];
        float qi = vx * vx + vy * vy + vz * vz;

        unsigned key[CPL];
        unsigned lmin = 0xFFFFFFFFu, lmax = 0u;
        #pragma unroll
        for (int t = 0; t < CPL; t++) {
            int j = lane + 64 * t;
            float xj = sv[j * 3 + 0], yj = sv[j * 3 + 1], zj = sv[j * 3 + 2];
            float inner = vx * xj + vy * yj + vz * zj;
            float qj = xj * xj + yj * yj + zj * zj;
            float dist = (-2.0f * inner + qi) + qj;
            unsigned u = __float_as_uint(dist);
            u = (u & 0x80000000u) ? ~u : (u | 0x80000000u);
            if (j == i) u = 0xFFFFFFFFu;
            key[t] = u;
            if (u != 0xFFFFFFFFu) {
                lmin = (u < lmin) ? u : lmin;
                lmax = (u > lmax) ? u : lmax;
            }
        }
        #pragma unroll
        for (int off = 32; off >= 1; off >>= 1) {
            unsigned o1 = (unsigned)__shfl_xor((int)lmin, off);
            unsigned o2 = (unsigned)__shfl_xor((int)lmax, off);
            lmin = (o1 < lmin) ? o1 : lmin;
            lmax = (o2 > lmax) ? o2 : lmax;
        }
        float scale = (lmax > lmin) ? 255.0f / (float)(lmax - lmin) : 0.0f;

        #pragma unroll
        for (int q = 0; q < 4; q++) myhist[lane * 4 + q] = 0;
        __asm__ volatile("s_waitcnt lgkmcnt(0)" ::: "memory");
        int bins[CPL];
        #pragma unroll
        for (int t = 0; t < CPL; t++) {
            int bi = (key[t] == 0xFFFFFFFFu) ? 255
                     : (int)((float)(key[t] - lmin) * scale);
            bi = (bi > 255) ? 255 : bi;
            bins[t] = bi;
            atomicAdd(&myhist[bi], 1);
        }
        __asm__ volatile("s_waitcnt lgkmcnt(0)" ::: "memory");

        int h0 = myhist[lane * 4 + 0];
        int h1 = myhist[lane * 4 + 1];
        int h2 = myhist[lane * 4 + 2];
        int h3 = myhist[lane * 4 + 3];
        int s = h0 + h1 + h2 + h3;
        int cum = s;
        #pragma unroll
        for (int off = 1; off < 64; off <<= 1) {
            int v = __shfl_up(cum, off);
            if (lane >= off) cum += v;
        }
        unsigned long long bal = __ballot(cum >= NN);
        int L = __ffsll((long long)bal) - 1;
        int baseL = __shfl(cum, L) - __shfl(s, L);
        int g0 = __shfl(h0, L), g1 = __shfl(h1, L), g2 = __shfl(h2, L);
        int B;
        if (baseL + g0 >= NN)            B = 4 * L + 0;
        else if (baseL + g0 + g1 >= NN)  B = 4 * L + 1;
        else if (baseL + g0 + g1 + g2 >= NN) B = 4 * L + 2;
        else                              B = 4 * L + 3;

        if (lane == 0) cnt[wid] = 0;
        __asm__ volatile("s_waitcnt lgkmcnt(0)" ::: "memory");
        #pragma unroll
        for (int t = 0; t < CPL; t++) {
            if (bins[t] <= B) {
                int pos = atomicAdd(&cnt[wid], 1);
                if (pos < COLL_CAP)
                    mycoll[pos] = ((unsigned long long)key[t] << 32) | (unsigned)(lane + 64 * t);
            }
        }
        __asm__ volatile("s_waitcnt lgkmcnt(0)" ::: "memory");
        int count = cnt[wid];
        if (count > COLL_CAP) count = COLL_CAP;

        int* dst = nbr + ((size_t)b * N + i) * NN;
        for (int e = lane; e < count; e += 64) {
            unsigned long long me = mycoll[e];
            int rank = 0;
            for (int m = 0; m < count; m++) rank += (mycoll[m] < me);
            if (rank < NN) dst[rank] = (int)(me & 0xFFFFFFFFull);
        }
    }
}

// ---------------------------------------------------------------------------
// K2: operator3d + relu -> fm0 (8,2048,32). One thread per vertex.
// ---------------------------------------------------------------------------
__global__ __launch_bounds__(256) void op3d_kernel(const float* __restrict__ verts,
                                                   const int* __restrict__ nbr,
                                                   const float* __restrict__ w0w,
                                                   const float* __restrict__ w0d,
                                                   float* __restrict__ fm0) {
    __shared__ float swd[3 * SUP * K0];
    __shared__ float sww[SUP * K0];
    for (int t = threadIdx.x; t < 3 * SUP * K0; t += 256) swd[t] = w0d[t];
    for (int t = threadIdx.x; t < SUP * K0; t += 256) sww[t] = w0w[t];
    __syncthreads();

    int gid = blockIdx.x * 256 + threadIdx.x;
    int b = gid >> 11, v = gid & (NV - 1);
    const float* vb = verts + b * NV * 3;
    float vx = vb[v * 3], vy = vb[v * 3 + 1], vz = vb[v * 3 + 2];

    const int* nb = nbr + gid * NN;
    float dx[NN], dy[NN], dz[NN];
    #pragma unroll
    for (int n = 0; n < NN; n++) {
        int j = nb[n];
        dx[n] = vb[j * 3 + 0] - vx;
        dy[n] = vb[j * 3 + 1] - vy;
        dz[n] = vb[j * 3 + 2] - vz;
    }
    float* out = fm0 + gid * K0;
    #pragma unroll 1
    for (int k = 0; k < K0; k++) {
        float acc = 0.f;
        #pragma unroll
        for (int s = 0; s < SUP; s++) {
            float w0 = swd[0 * 224 + s * K0 + k];
            float w1 = swd[1 * 224 + s * K0 + k];
            float w2 = swd[2 * 224 + s * K0 + k];
            float m = 0.f;
            #pragma unroll
            for (int n = 0; n < NN; n++) {
                float t = dx[n] * w0 + dy[n] * w1 + dz[n] * w2;
                t = fmaxf(t, 0.f);
                m = fmaxf(m, t);
            }
            acc += m * sww[s * K0 + k];
        }
        out[k] = fmaxf(acc, 0.f);
    }
}

// ---------------------------------------------------------------------------
// feat GEMM: feat[rows x N] = fm[rows x K] @ w[K x N] + bias. 64x64 tiles,
// bias-init + k-ascending accumulation (identical FP order to fused version).
// ---------------------------------------------------------------------------
template<int K, int N>
__global__ __launch_bounds__(256) void feat_gemm(const float* __restrict__ fm,
                                                 const float* __restrict__ w,
                                                 const float* __restrict__ bias,
                                                 float* __restrict__ feat) {
    __shared__ float sf[64][K];
    __shared__ float swt[K][64];
    int cb = blockIdx.x % (N / 64), rb = blockIdx.x / (N / 64);
    int r0 = rb * 64, c0 = cb * 64;

    for (int t = threadIdx.x; t < 64 * K; t += 256)
        sf[t / K][t % K] = fm[(size_t)(r0 + t / K) * K + (t % K)];
    for (int t = threadIdx.x; t < K * 64; t += 256)
        swt[t >> 6][t & 63] = w[(size_t)(t >> 6) * N + c0 + (t & 63)];
    __syncthreads();

    int col = threadIdx.x & 63, rg = threadIdx.x >> 6;
    float bv = bias[c0 + col];
    float acc[16];
    #pragma unroll
    for (int r = 0; r < 16; r++) acc[r] = bv;
    #pragma unroll 1
    for (int k = 0; k < K; k++) {
        float wk = swt[k][col];
        #pragma unroll
        for (int r = 0; r < 16; r++) acc[r] += sf[rg * 16 + r][k] * wk;
    }
    #pragma unroll
    for (int r = 0; r < 16; r++)
        feat[(size_t)(r0 + rg * 16 + r) * N + c0 + col] = acc[r];
}

// ---------------------------------------------------------------------------
// opnd1 gather-max: wave per vertex, lane = channel. Coalesced 256B reads of
// neighbor feat rows (L2-resident). -> fm1 (+relu)
// ---------------------------------------------------------------------------
__global__ __launch_bounds__(256) void opnd1_gather(const float* __restrict__ verts,
                                                    const int* __restrict__ nbr,
                                                    const float* __restrict__ feat1,
                                                    const float* __restrict__ w1d,
                                                    float* __restrict__ fm1) {
    __shared__ float swd[3 * SUP * C1];
    for (int t = threadIdx.x; t < 3 * SUP * C1; t += 256) swd[t] = w1d[t];
    __syncthreads();

    int wid = threadIdx.x >> 6, lane = threadIdx.x & 63;
    int vtx = blockIdx.x * 4 + wid;
    int b = vtx >> 11, v = vtx & (NV - 1);
    const float* vb = verts + b * NV * 3;
    const int* nb = nbr + vtx * NN;
    float vx = vb[v * 3], vy = vb[v * 3 + 1], vz = vb[v * 3 + 2];
    float dx[NN], dy[NN], dz[NN];
    const float* rp[NN];
    #pragma unroll
    for (int n = 0; n < NN; n++) {
        int j = nb[n];
        dx[n] = vb[j * 3 + 0] - vx;
        dy[n] = vb[j * 3 + 1] - vy;
        dz[n] = vb[j * 3 + 2] - vz;
        rp[n] = feat1 + ((size_t)b * NV + j) * (8 * C1) + C1 + lane;
    }

    float fcen = feat1[((size_t)b * NV + v) * (8 * C1) + lane];
    float total = 0.f;
    #pragma unroll 1
    for (int ss = 0; ss < SUP; ss++) {
        float w0 = swd[0 * (SUP * C1) + ss * C1 + lane];
        float w1 = swd[1 * (SUP * C1) + ss * C1 + lane];
        float w2 = swd[2 * (SUP * C1) + ss * C1 + lane];
        float m = -3.4e38f;
        #pragma unroll
        for (int n = 0; n < NN; n++) {
            float th = fmaxf(dx[n] * w0 + dy[n] * w1 + dz[n] * w2, 0.f);
            m = fmaxf(m, th * rp[n][ss * C1]);
        }
        total += m;
    }
    fm1[vtx * C1 + lane] = fmaxf(fcen + total, 0.f);
}

// ---------------------------------------------------------------------------
// opnd2 gather-max: wave per vertex, 4 channel-chunks. -> fm2 (+relu)
// ---------------------------------------------------------------------------
__global__ __launch_bounds__(256) void opnd2_gather(const float* __restrict__ v1,
                                                    const int* __restrict__ nbr2,
                                                    const float* __restrict__ feat2,
                                                    const float* __restrict__ w2d,
                                                    float* __restrict__ fm2) {
    __shared__ float swd[3 * SUP * C2];
    for (int t = threadIdx.x; t < 3 * SUP * C2; t += 256) swd[t] = w2d[t];
    __syncthreads();

    int wid = threadIdx.x >> 6, lane = threadIdx.x & 63;
    int vtx = blockIdx.x * 4 + wid;
    int b = vtx >> 8, v = vtx & (NV2 - 1);
    const float* vb = v1 + b * NV2 * 3;
    const int* nb = nbr2 + vtx * NN;
    float vx = vb[v * 3], vy = vb[v * 3 + 1], vz = vb[v * 3 + 2];
    float dx[NN], dy[NN], dz[NN];
    const float* rp[NN];
    #pragma unroll
    for (int n = 0; n < NN; n++) {
        int j = nb[n];
        dx[n] = vb[j * 3 + 0] - vx;
        dy[n] = vb[j * 3 + 1] - vy;
        dz[n] = vb[j * 3 + 2] - vz;
        rp[n] = feat2 + ((size_t)b * NV2 + j) * (8 * C2) + C2 + lane;
    }
    const float* crow = feat2 + ((size_t)b * NV2 + v) * (8 * C2);

    #pragma unroll 1
    for (int jj = 0; jj < 4; jj++) {
        int cj = jj * 64 + lane;
        float fcen = crow[cj];
        float total = 0.f;
        #pragma unroll 1
        for (int ss = 0; ss < SUP; ss++) {
            float w0 = swd[0 * (SUP * C2) + ss * C2 + cj];
            float w1 = swd[1 * (SUP * C2) + ss * C2 + cj];
            float w2 = swd[2 * (SUP * C2) + ss * C2 + cj];
            float m = -3.4e38f;
            #pragma unroll
            for (int n = 0; n < NN; n++) {
                float th = fmaxf(dx[n] * w0 + dy[n] * w1 + dz[n] * w2, 0.f);
                m = fmaxf(m, th * rp[n][ss * C2 + jj * 64]);
            }
            total += m;
        }
        fm2[vtx * C2 + cj] = fmaxf(fcen + total, 0.f);
    }
}

// ---------------------------------------------------------------------------
// K5: pooling 1 -> v1, fm1p. One wave per sampled vertex.
// ---------------------------------------------------------------------------
__global__ __launch_bounds__(256) void pool1_kernel(const float* __restrict__ verts,
                                                    const int* __restrict__ nbr1,
                                                    const float* __restrict__ fm1,
                                                    float* __restrict__ v1,
                                                    float* __restrict__ fm1p,
                                                    PermArg1 pa) {
    int wid = threadIdx.x >> 6, lane = threadIdx.x & 63;
    int gid = blockIdx.x * 4 + wid;
    int b = gid >> 8, p = gid & 255;
    int sv = pa.v[p];
    const int* nb = nbr1 + (b * NV + sv) * NN;
    float m = -3.4e38f;
    #pragma unroll
    for (int n = 0; n < 8; n++) {
        m = fmaxf(m, fm1[(b * NV + nb[n]) * C1 + lane]);
    }
    fm1p[gid * C1 + lane] = m;
    if (lane < 3) v1[gid * 3 + lane] = verts[(b * NV + sv) * 3 + lane];
}

// ---------------------------------------------------------------------------
// K9: pooling 2 -> fm3 (outputs[1]) — f32
// ---------------------------------------------------------------------------
__global__ __launch_bounds__(256) void pool2_kernel(const int* __restrict__ nbr2,
                                                    const float* __restrict__ fm2,
                                                    float* __restrict__ out,
                                                    PermArg2 pa) {
    int wid = threadIdx.x >> 6, lane = threadIdx.x & 63;
    int gid = blockIdx.x * 4 + wid;
    int b = gid >> 4, p = gid & 15;
    int sv = pa.v[p];
    const int* nb = nbr2 + (b * NV2 + sv) * NN;
    #pragma unroll 1
    for (int jj = 0; jj < 4; jj++) {
        int c = lane + jj * 64;
        float m = -3.4e38f;
        #pragma unroll
        for (int n = 0; n < 16; n++) {
            m = fmaxf(m, fm2[(b * NV2 + nb[n]) * C2 + c]);
        }
        out[NB * NP2 * 3 + gid * C2 + c] = m;
    }
}

// ---------------------------------------------------------------------------
// Launch
// ---------------------------------------------------------------------------
extern "C" void kernel_launch(void* const* d_in, const int* in_sizes, int n_in,
                              void* d_out, int out_size, void* d_ws, size_t ws_size,
                              hipStream_t stream) {
    (void)in_sizes; (void)n_in; (void)out_size; (void)ws_size;
    const float* verts = (const float*)d_in[0];
    const float* w0w = (const float*)d_in[1];
    const float* w0d = (const float*)d_in[2];
    const float* w1w = (const float*)d_in[3];
    const float* w1b = (const float*)d_in[4];
    const float* w1d = (const float*)d_in[5];
    const float* w2w = (const float*)d_in[6];
    const float* w2b = (const float*)d_in[7];
    const float* w2d = (const float*)d_in[8];
    float* out = (float*)d_out;

    static const PermOut perms = compute_perms();

    PermArg1 pa1;
    PermArg2 pa2, pac;
    memcpy(pa1.v, perms.p1, sizeof(pa1.v));
    memcpy(pa2.v, perms.p2, sizeof(pa2.v));
    for (int j = 0; j < 16; j++) pac.v[j] = perms.p1[perms.p2[j]];

    char* ws = (char*)d_ws;
    size_t off = 0;
    auto alloc = [&](size_t bytes) -> void* {
        void* p = ws + off;
        off += (bytes + 255) & ~(size_t)255;
        return p;
    };
    int*   nbr1  = (int*)  alloc((size_t)NB * NV * NN * 4);        // 1.3 MB
    float* fm0   = (float*)alloc((size_t)NB * NV * K0 * 4);        // 2 MB
    float* feat1 = (float*)alloc((size_t)NB * NV * 8 * C1 * 4);    // 33.5 MB
    float* fm1   = (float*)alloc((size_t)NB * NV * C1 * 4);        // 4.2 MB
    float* v1    = (float*)alloc((size_t)NB * NV2 * 3 * 4);
    float* fm1p  = (float*)alloc((size_t)NB * NV2 * C1 * 4);
    int*   nbr2  = (int*)  alloc((size_t)NB * NV2 * NN * 4);
    float* feat2 = (float*)alloc((size_t)NB * NV2 * 8 * C2 * 4);   // 16.8 MB
    float* fm2   = (float*)alloc((size_t)NB * NV2 * C2 * 4);       // 2 MB

    v2_kernel<<<1, 384, 0, stream>>>(verts, out, pac);
    knn_bucket_kernel<NV, NV / 64><<<NB * (NV / 16), 256, 0, stream>>>(verts, nbr1);
    op3d_kernel<<<64, 256, 0, stream>>>(verts, nbr1, w0w, w0d, fm0);
    // feat1 = fm0 @ w1w + w1b : rows 16384, K=32, N=512 -> 256*8 blocks
    feat_gemm<K0, 8 * C1><<<(NB * NV / 64) * (8 * C1 / 64), 256, 0, stream>>>(fm0, w1w, w1b, feat1);
    opnd1_gather<<<NB * NV / 4, 256, 0, stream>>>(verts, nbr1, feat1, w1d, fm1);
    pool1_kernel<<<NB * NV2 / 4, 256, 0, stream>>>(verts, nbr1, fm1, v1, fm1p, pa1);
    knn_bucket_kernel<NV2, NV2 / 64><<<NB * (NV2 / 16), 256, 0, stream>>>(v1, nbr2);
    // feat2 = fm1p @ w2w + w2b : rows 2048, K=64, N=2048 -> 32*32 blocks
    feat_gemm<C1, 8 * C2><<<(NB * NV2 / 64) * (8 * C2 / 64), 256, 0, stream>>>(fm1p, w2w, w2b, feat2);
    opnd2_gather<<<NB * NV2 / 4, 256, 0, stream>>>(v1, nbr2, feat2, w2d, fm2);
    pool2_kernel<<<32, 256, 0, stream>>>(nbr2, fm2, out, pa2);
}

// Round 28
// 385.809 us; speedup vs baseline: 14.6047x; 1.4807x over previous
//
#include <hip/hip_runtime.h>
#include <hip/hip_bf16.h>
#include <stdint.h>
#include <string.h>

// ---------------------------------------------------------------------------
// Problem constants
// ---------------------------------------------------------------------------
#define NB   8
#define NV   2048
#define NN   20      // NEIGHBOR_NUM
#define SUP  7       // SUPPORT
#define K0   32
#define C1   64
#define C2   256
#define NV2  256     // vertices after pooling 1
#define NP2  16      // vertices after pooling 2
#define COLL_CAP 512

// ---------------------------------------------------------------------------
// Permutations (proven R21..R27)
// ---------------------------------------------------------------------------
typedef unsigned __int128 u128;

struct CPcg { u128 state; u128 inc; bool has32; uint32_t cached; };

constexpr u128 PCG_MULT = (((u128)2549297995355413924ULL) << 64) | 4865540595714422341ULL;

constexpr uint64_t c_rotr64(uint64_t v, unsigned r) {
    return (v >> (r & 63u)) | (v << ((64u - r) & 63u));
}
constexpr uint64_t pcg_next64(CPcg& g) {
    g.state = g.state * PCG_MULT + g.inc;
    uint64_t hi = (uint64_t)(g.state >> 64);
    uint64_t lo = (uint64_t)g.state;
    return c_rotr64(hi ^ lo, (unsigned)(hi >> 58));
}
constexpr uint32_t pcg_next32(CPcg& g) {
    if (g.has32) { g.has32 = false; return g.cached; }
    uint64_t n = pcg_next64(g);
    g.has32 = true;
    g.cached = (uint32_t)(n >> 32);
    return (uint32_t)n;
}
constexpr uint64_t rand_interval(CPcg& g, uint64_t mx) {
    if (mx == 0) return 0;
    uint64_t mask = mx;
    mask |= mask >> 1; mask |= mask >> 2; mask |= mask >> 4;
    mask |= mask >> 8; mask |= mask >> 16; mask |= mask >> 32;
    uint64_t v = 0;
    while ((v = ((uint64_t)pcg_next32(g) & mask)) > mx) {
    }
    return v;
}
constexpr uint32_t hashmix(uint32_t value, uint32_t& hc) {
    value ^= hc; hc *= 0x931e8875u; value *= hc; value ^= value >> 16; return value;
}
constexpr uint32_t mixpool(uint32_t x, uint32_t y) {
    uint32_t r = (x * 0xca01f9ddu) - (y * 0x4973f715u);
    r ^= r >> 16; return r;
}
constexpr CPcg make_rng(uint32_t entropy) {
    uint32_t pool[4] = {0, 0, 0, 0};
    uint32_t hc = 0x43b0d7e5u;
    for (int i = 0; i < 4; i++) {
        uint32_t v = (i == 0) ? entropy : 0u;
        pool[i] = hashmix(v, hc);
    }
    for (int isrc = 0; isrc < 4; isrc++)
        for (int idst = 0; idst < 4; idst++)
            if (isrc != idst) pool[idst] = mixpool(pool[idst], hashmix(pool[isrc], hc));
    uint32_t w[8] = {};
    uint32_t hb = 0x8b51f9ddu;
    for (int i = 0; i < 8; i++) {
        uint32_t dv = pool[i & 3];
        dv ^= hb; hb *= 0x58f38dedu; dv *= hb; dv ^= dv >> 16; w[i] = dv;
    }
    uint64_t sd[4] = {};
    for (int k = 0; k < 4; k++) sd[k] = (uint64_t)w[2 * k] | ((uint64_t)w[2 * k + 1] << 32);
    u128 s = (((u128)sd[0]) << 64) | sd[1];
    u128 iq = (((u128)sd[2]) << 64) | sd[3];
    CPcg g{};
    g.state = 0;
    g.inc = (iq << 1) | 1;
    g.state = g.state * PCG_MULT + g.inc;
    g.state += s;
    g.state = g.state * PCG_MULT + g.inc;
    g.has32 = false; g.cached = 0;
    return g;
}

struct PermOut { int p1[256]; int p2[16]; };

constexpr PermOut compute_perms() {
    PermOut o{};
    {
        CPcg g = make_rng(1u);
        int arr[2048] = {};
        for (int i = 0; i < 2048; i++) arr[i] = i;
        for (int i = 2047; i >= 1; i--) {
            int j = (int)rand_interval(g, (uint64_t)i);
            int t = arr[i]; arr[i] = arr[j]; arr[j] = t;
        }
        for (int i = 0; i < 256; i++) o.p1[i] = arr[i];
    }
    {
        CPcg g = make_rng(2u);
        int arr[256] = {};
        for (int i = 0; i < 256; i++) arr[i] = i;
        for (int i = 255; i >= 1; i--) {
            int j = (int)rand_interval(g, (uint64_t)i);
            int t = arr[i]; arr[i] = arr[j]; arr[j] = t;
        }
        for (int i = 0; i < 16; i++) o.p2[i] = arr[i];
    }
    return o;
}

struct PermArg1 { int v[256]; };
struct PermArg2 { int v[16]; };

// ---------------------------------------------------------------------------
// K0: v2 (outputs[0]) = verts[:, p1[p2[j]], :] — f32
// ---------------------------------------------------------------------------
__global__ __launch_bounds__(384) void v2_kernel(const float* __restrict__ verts,
                                                 float* __restrict__ out,
                                                 PermArg2 cidx) {
    int t = threadIdx.x;
    if (t < NB * NP2 * 3) {
        int b = t / (NP2 * 3);
        int rem = t - b * (NP2 * 3);
        int j = rem / 3;
        int c = rem - j * 3;
        out[t] = verts[(b * NV + cidx.v[j]) * 3 + c];
    }
}

// ---------------------------------------------------------------------------
// KNN via linear-bucket select (R26, proven)
// ---------------------------------------------------------------------------
template<int N, int CPL>
__global__ __launch_bounds__(256) void knn_bucket_kernel(const float* __restrict__ verts,
                                                         int* __restrict__ nbr) {
    __shared__ float sv[N * 3];
    __shared__ int hist[4][256];
    __shared__ unsigned long long coll[4][COLL_CAP];
    __shared__ int cnt[4];

    constexpr int RPB = 16;
    int bpb = N / RPB;
    int b = blockIdx.x / bpb;
    int rbase = (blockIdx.x % bpb) * RPB;

    const float* vb = verts + (size_t)b * N * 3;
    for (int t = threadIdx.x; t < N * 3; t += 256) sv[t] = vb[t];
    __syncthreads();

    int wid = threadIdx.x >> 6, lane = threadIdx.x & 63;
    int* myhist = hist[wid];
    unsigned long long* mycoll = coll[wid];

    for (int rr = 0; rr < 4; rr++) {
        int i = rbase + wid * 4 + rr;
        float vx = sv[i * 3 + 0], vy = sv[i * 3 + 1], vz = sv[i * 3 + 2];
        float qi = vx * vx + vy * vy + vz * vz;

        unsigned key[CPL];
        unsigned lmin = 0xFFFFFFFFu, lmax = 0u;
        #pragma unroll
        for (int t = 0; t < CPL; t++) {
            int j = lane + 64 * t;
            float xj = sv[j * 3 + 0], yj = sv[j * 3 + 1], zj = sv[j * 3 + 2];
            float inner = vx * xj + vy * yj + vz * zj;
            float qj = xj * xj + yj * yj + zj * zj;
            float dist = (-2.0f * inner + qi) + qj;
            unsigned u = __float_as_uint(dist);
            u = (u & 0x80000000u) ? ~u : (u | 0x80000000u);
            if (j == i) u = 0xFFFFFFFFu;
            key[t] = u;
            if (u != 0xFFFFFFFFu) {
                lmin = (u < lmin) ? u : lmin;
                lmax = (u > lmax) ? u : lmax;
            }
        }
        #pragma unroll
        for (int off = 32; off >= 1; off >>= 1) {
            unsigned o1 = (unsigned)__shfl_xor((int)lmin, off);
            unsigned o2 = (unsigned)__shfl_xor((int)lmax, off);
            lmin = (o1 < lmin) ? o1 : lmin;
            lmax = (o2 > lmax) ? o2 : lmax;
        }
        float scale = (lmax > lmin) ? 255.0f / (float)(lmax - lmin) : 0.0f;

        #pragma unroll
        for (int q = 0; q < 4; q++) myhist[lane * 4 + q] = 0;
        __asm__ volatile("s_waitcnt lgkmcnt(0)" ::: "memory");
        int bins[CPL];
        #pragma unroll
        for (int t = 0; t < CPL; t++) {
            int bi = (key[t] == 0xFFFFFFFFu) ? 255
                     : (int)((float)(key[t] - lmin) * scale);
            bi = (bi > 255) ? 255 : bi;
            bins[t] = bi;
            atomicAdd(&myhist[bi], 1);
        }
        __asm__ volatile("s_waitcnt lgkmcnt(0)" ::: "memory");

        int h0 = myhist[lane * 4 + 0];
        int h1 = myhist[lane * 4 + 1];
        int h2 = myhist[lane * 4 + 2];
        int h3 = myhist[lane * 4 + 3];
        int s = h0 + h1 + h2 + h3;
        int cum = s;
        #pragma unroll
        for (int off = 1; off < 64; off <<= 1) {
            int v = __shfl_up(cum, off);
            if (lane >= off) cum += v;
        }
        unsigned long long bal = __ballot(cum >= NN);
        int L = __ffsll((long long)bal) - 1;
        int baseL = __shfl(cum, L) - __shfl(s, L);
        int g0 = __shfl(h0, L), g1 = __shfl(h1, L), g2 = __shfl(h2, L);
        int B;
        if (baseL + g0 >= NN)            B = 4 * L + 0;
        else if (baseL + g0 + g1 >= NN)  B = 4 * L + 1;
        else if (baseL + g0 + g1 + g2 >= NN) B = 4 * L + 2;
        else                              B = 4 * L + 3;

        if (lane == 0) cnt[wid] = 0;
        __asm__ volatile("s_waitcnt lgkmcnt(0)" ::: "memory");
        #pragma unroll
        for (int t = 0; t < CPL; t++) {
            if (bins[t] <= B) {
                int pos = atomicAdd(&cnt[wid], 1);
                if (pos < COLL_CAP)
                    mycoll[pos] = ((unsigned long long)key[t] << 32) | (unsigned)(lane + 64 * t);
            }
        }
        __asm__ volatile("s_waitcnt lgkmcnt(0)" ::: "memory");
        int count = cnt[wid];
        if (count > COLL_CAP) count = COLL_CAP;

        int* dst = nbr + ((size_t)b * N + i) * NN;
        for (int e = lane; e < count; e += 64) {
            unsigned long long me = mycoll[e];
            int rank = 0;
            for (int m = 0; m < count; m++) rank += (mycoll[m] < me);
            if (rank < NN) dst[rank] = (int)(me & 0xFFFFFFFFull);
        }
    }
}

// ---------------------------------------------------------------------------
// K2: operator3d + relu -> fm0 (8,2048,32). One thread per vertex.
// ---------------------------------------------------------------------------
__global__ __launch_bounds__(256) void op3d_kernel(const float* __restrict__ verts,
                                                   const int* __restrict__ nbr,
                                                   const float* __restrict__ w0w,
                                                   const float* __restrict__ w0d,
                                                   float* __restrict__ fm0) {
    __shared__ float swd[3 * SUP * K0];
    __shared__ float sww[SUP * K0];
    for (int t = threadIdx.x; t < 3 * SUP * K0; t += 256) swd[t] = w0d[t];
    for (int t = threadIdx.x; t < SUP * K0; t += 256) sww[t] = w0w[t];
    __syncthreads();

    int gid = blockIdx.x * 256 + threadIdx.x;
    int b = gid >> 11, v = gid & (NV - 1);
    const float* vb = verts + b * NV * 3;
    float vx = vb[v * 3], vy = vb[v * 3 + 1], vz = vb[v * 3 + 2];

    const int* nb = nbr + gid * NN;
    float dx[NN], dy[NN], dz[NN];
    #pragma unroll
    for (int n = 0; n < NN; n++) {
        int j = nb[n];
        dx[n] = vb[j * 3 + 0] - vx;
        dy[n] = vb[j * 3 + 1] - vy;
        dz[n] = vb[j * 3 + 2] - vz;
    }
    float* out = fm0 + gid * K0;
    #pragma unroll 1
    for (int k = 0; k < K0; k++) {
        float acc = 0.f;
        #pragma unroll
        for (int s = 0; s < SUP; s++) {
            float w0 = swd[0 * 224 + s * K0 + k];
            float w1 = swd[1 * 224 + s * K0 + k];
            float w2 = swd[2 * 224 + s * K0 + k];
            float m = 0.f;
            #pragma unroll
            for (int n = 0; n < NN; n++) {
                float t = dx[n] * w0 + dy[n] * w1 + dz[n] * w2;
                t = fmaxf(t, 0.f);
                m = fmaxf(m, t);
            }
            acc += m * sww[s * K0 + k];
        }
        out[k] = fmaxf(acc, 0.f);
    }
}

// ---------------------------------------------------------------------------
// feat GEMM: feat[rows x N] = fm[rows x K] @ w[K x N] + bias (R27, proven)
// ---------------------------------------------------------------------------
template<int K, int N>
__global__ __launch_bounds__(256) void feat_gemm(const float* __restrict__ fm,
                                                 const float* __restrict__ w,
                                                 const float* __restrict__ bias,
                                                 float* __restrict__ feat) {
    __shared__ float sf[64][K];
    __shared__ float swt[K][64];
    int cb = blockIdx.x % (N / 64), rb = blockIdx.x / (N / 64);
    int r0 = rb * 64, c0 = cb * 64;

    for (int t = threadIdx.x; t < 64 * K; t += 256)
        sf[t / K][t % K] = fm[(size_t)(r0 + t / K) * K + (t % K)];
    for (int t = threadIdx.x; t < K * 64; t += 256)
        swt[t >> 6][t & 63] = w[(size_t)(t >> 6) * N + c0 + (t & 63)];
    __syncthreads();

    int col = threadIdx.x & 63, rg = threadIdx.x >> 6;
    float bv = bias[c0 + col];
    float acc[16];
    #pragma unroll
    for (int r = 0; r < 16; r++) acc[r] = bv;
    #pragma unroll 1
    for (int k = 0; k < K; k++) {
        float wk = swt[k][col];
        #pragma unroll
        for (int r = 0; r < 16; r++) acc[r] += sf[rg * 16 + r][k] * wk;
    }
    #pragma unroll
    for (int r = 0; r < 16; r++)
        feat[(size_t)(r0 + rg * 16 + r) * N + c0 + col] = acc[r];
}

// ---------------------------------------------------------------------------
// opnd1 gather-max (n-outer): stream each neighbor row's 7x256B chunks
// back-to-back; m[SUP] running maxes in regs; total = sum ss ascending.
// Bit-identical to ss-outer (fmax exact, final sum order unchanged).
// ---------------------------------------------------------------------------
__global__ __launch_bounds__(256) void opnd1_gather(const float* __restrict__ verts,
                                                    const int* __restrict__ nbr,
                                                    const float* __restrict__ feat1,
                                                    const float* __restrict__ w1d,
                                                    float* __restrict__ fm1) {
    __shared__ float swd[3 * SUP * C1];
    for (int t = threadIdx.x; t < 3 * SUP * C1; t += 256) swd[t] = w1d[t];
    __syncthreads();

    int wid = threadIdx.x >> 6, lane = threadIdx.x & 63;
    int vtx = blockIdx.x * 4 + wid;
    int b = vtx >> 11, v = vtx & (NV - 1);
    const float* vb = verts + b * NV * 3;
    const int* nb = nbr + vtx * NN;
    float vx = vb[v * 3], vy = vb[v * 3 + 1], vz = vb[v * 3 + 2];

    // per-lane support weights in registers
    float w0r[SUP], w1r[SUP], w2r[SUP];
    #pragma unroll
    for (int ss = 0; ss < SUP; ss++) {
        w0r[ss] = swd[0 * (SUP * C1) + ss * C1 + lane];
        w1r[ss] = swd[1 * (SUP * C1) + ss * C1 + lane];
        w2r[ss] = swd[2 * (SUP * C1) + ss * C1 + lane];
    }

    const float* fb = feat1 + (size_t)b * NV * (8 * C1);
    float m[SUP];
    #pragma unroll
    for (int ss = 0; ss < SUP; ss++) m[ss] = -3.4e38f;

    #pragma unroll 1
    for (int n = 0; n < NN; n++) {
        int j = nb[n];
        float dx = vb[j * 3 + 0] - vx;
        float dy = vb[j * 3 + 1] - vy;
        float dz = vb[j * 3 + 2] - vz;
        const float* row = fb + (size_t)j * (8 * C1) + C1 + lane;
        #pragma unroll
        for (int ss = 0; ss < SUP; ss++) {
            float th = fmaxf(dx * w0r[ss] + dy * w1r[ss] + dz * w2r[ss], 0.f);
            m[ss] = fmaxf(m[ss], th * row[ss * C1]);
        }
    }
    float fcen = fb[(size_t)v * (8 * C1) + lane];
    float total = 0.f;
    #pragma unroll
    for (int ss = 0; ss < SUP; ss++) total += m[ss];
    fm1[vtx * C1 + lane] = fmaxf(fcen + total, 0.f);
}

// ---------------------------------------------------------------------------
// opnd2 gather-max (n-outer), 4 channel-chunks. -> fm2 (+relu)
// ---------------------------------------------------------------------------
__global__ __launch_bounds__(256) void opnd2_gather(const float* __restrict__ v1,
                                                    const int* __restrict__ nbr2,
                                                    const float* __restrict__ feat2,
                                                    const float* __restrict__ w2d,
                                                    float* __restrict__ fm2) {
    __shared__ float swd[3 * SUP * C2];
    for (int t = threadIdx.x; t < 3 * SUP * C2; t += 256) swd[t] = w2d[t];
    __syncthreads();

    int wid = threadIdx.x >> 6, lane = threadIdx.x & 63;
    int vtx = blockIdx.x * 4 + wid;
    int b = vtx >> 8, v = vtx & (NV2 - 1);
    const float* vb = v1 + b * NV2 * 3;
    const int* nb = nbr2 + vtx * NN;
    float vx = vb[v * 3], vy = vb[v * 3 + 1], vz = vb[v * 3 + 2];

    int idx[NN];
    float dx[NN], dy[NN], dz[NN];
    #pragma unroll
    for (int n = 0; n < NN; n++) {
        int j = nb[n];
        idx[n] = j;
        dx[n] = vb[j * 3 + 0] - vx;
        dy[n] = vb[j * 3 + 1] - vy;
        dz[n] = vb[j * 3 + 2] - vz;
    }
    const float* fb = feat2 + (size_t)b * NV2 * (8 * C2);
    const float* crow = fb + (size_t)v * (8 * C2);

    #pragma unroll 1
    for (int jj = 0; jj < 4; jj++) {
        int cj = jj * 64 + lane;
        float w0r[SUP], w1r[SUP], w2r[SUP];
        #pragma unroll
        for (int ss = 0; ss < SUP; ss++) {
            w0r[ss] = swd[0 * (SUP * C2) + ss * C2 + cj];
            w1r[ss] = swd[1 * (SUP * C2) + ss * C2 + cj];
            w2r[ss] = swd[2 * (SUP * C2) + ss * C2 + cj];
        }
        float m[SUP];
        #pragma unroll
        for (int ss = 0; ss < SUP; ss++) m[ss] = -3.4e38f;
        #pragma unroll 1
        for (int n = 0; n < NN; n++) {
            const float* row = fb + (size_t)idx[n] * (8 * C2) + C2 + cj;
            #pragma unroll
            for (int ss = 0; ss < SUP; ss++) {
                float th = fmaxf(dx[n] * w0r[ss] + dy[n] * w1r[ss] + dz[n] * w2r[ss], 0.f);
                m[ss] = fmaxf(m[ss], th * row[ss * C2]);
            }
        }
        float total = 0.f;
        #pragma unroll
        for (int ss = 0; ss < SUP; ss++) total += m[ss];
        fm2[vtx * C2 + cj] = fmaxf(crow[cj] + total, 0.f);
    }
}

// ---------------------------------------------------------------------------
// K5: pooling 1 -> v1, fm1p. One wave per sampled vertex.
// ---------------------------------------------------------------------------
__global__ __launch_bounds__(256) void pool1_kernel(const float* __restrict__ verts,
                                                    const int* __restrict__ nbr1,
                                                    const float* __restrict__ fm1,
                                                    float* __restrict__ v1,
                                                    float* __restrict__ fm1p,
                                                    PermArg1 pa) {
    int wid = threadIdx.x >> 6, lane = threadIdx.x & 63;
    int gid = blockIdx.x * 4 + wid;
    int b = gid >> 8, p = gid & 255;
    int sv = pa.v[p];
    const int* nb = nbr1 + (b * NV + sv) * NN;
    float m = -3.4e38f;
    #pragma unroll
    for (int n = 0; n < 8; n++) {
        m = fmaxf(m, fm1[(b * NV + nb[n]) * C1 + lane]);
    }
    fm1p[gid * C1 + lane] = m;
    if (lane < 3) v1[gid * 3 + lane] = verts[(b * NV + sv) * 3 + lane];
}

// ---------------------------------------------------------------------------
// K9: pooling 2 -> fm3 (outputs[1]) — f32
// ---------------------------------------------------------------------------
__global__ __launch_bounds__(256) void pool2_kernel(const int* __restrict__ nbr2,
                                                    const float* __restrict__ fm2,
                                                    float* __restrict__ out,
                                                    PermArg2 pa) {
    int wid = threadIdx.x >> 6, lane = threadIdx.x & 63;
    int gid = blockIdx.x * 4 + wid;
    int b = gid >> 4, p = gid & 15;
    int sv = pa.v[p];
    const int* nb = nbr2 + (b * NV2 + sv) * NN;
    #pragma unroll 1
    for (int jj = 0; jj < 4; jj++) {
        int c = lane + jj * 64;
        float m = -3.4e38f;
        #pragma unroll
        for (int n = 0; n < 16; n++) {
            m = fmaxf(m, fm2[(b * NV2 + nb[n]) * C2 + c]);
        }
        out[NB * NP2 * 3 + gid * C2 + c] = m;
    }
}

// ---------------------------------------------------------------------------
// Launch
// ---------------------------------------------------------------------------
extern "C" void kernel_launch(void* const* d_in, const int* in_sizes, int n_in,
                              void* d_out, int out_size, void* d_ws, size_t ws_size,
                              hipStream_t stream) {
    (void)in_sizes; (void)n_in; (void)out_size; (void)ws_size;
    const float* verts = (const float*)d_in[0];
    const float* w0w = (const float*)d_in[1];
    const float* w0d = (const float*)d_in[2];
    const float* w1w = (const float*)d_in[3];
    const float* w1b = (const float*)d_in[4];
    const float* w1d = (const float*)d_in[5];
    const float* w2w = (const float*)d_in[6];
    const float* w2b = (const float*)d_in[7];
    const float* w2d = (const float*)d_in[8];
    float* out = (float*)d_out;

    static const PermOut perms = compute_perms();

    PermArg1 pa1;
    PermArg2 pa2, pac;
    memcpy(pa1.v, perms.p1, sizeof(pa1.v));
    memcpy(pa2.v, perms.p2, sizeof(pa2.v));
    for (int j = 0; j < 16; j++) pac.v[j] = perms.p1[perms.p2[j]];

    char* ws = (char*)d_ws;
    size_t off = 0;
    auto alloc = [&](size_t bytes) -> void* {
        void* p = ws + off;
        off += (bytes + 255) & ~(size_t)255;
        return p;
    };
    int*   nbr1  = (int*)  alloc((size_t)NB * NV * NN * 4);
    float* fm0   = (float*)alloc((size_t)NB * NV * K0 * 4);
    float* feat1 = (float*)alloc((size_t)NB * NV * 8 * C1 * 4);
    float* fm1   = (float*)alloc((size_t)NB * NV * C1 * 4);
    float* v1    = (float*)alloc((size_t)NB * NV2 * 3 * 4);
    float* fm1p  = (float*)alloc((size_t)NB * NV2 * C1 * 4);
    int*   nbr2  = (int*)  alloc((size_t)NB * NV2 * NN * 4);
    float* feat2 = (float*)alloc((size_t)NB * NV2 * 8 * C2 * 4);
    float* fm2   = (float*)alloc((size_t)NB * NV2 * C2 * 4);

    v2_kernel<<<1, 384, 0, stream>>>(verts, out, pac);
    knn_bucket_kernel<NV, NV / 64><<<NB * (NV / 16), 256, 0, stream>>>(verts, nbr1);
    op3d_kernel<<<64, 256, 0, stream>>>(verts, nbr1, w0w, w0d, fm0);
    feat_gemm<K0, 8 * C1><<<(NB * NV / 64) * (8 * C1 / 64), 256, 0, stream>>>(fm0, w1w, w1b, feat1);
    opnd1_gather<<<NB * NV / 4, 256, 0, stream>>>(verts, nbr1, feat1, w1d, fm1);
    pool1_kernel<<<NB * NV2 / 4, 256, 0, stream>>>(verts, nbr1, fm1, v1, fm1p, pa1);
    knn_bucket_kernel<NV2, NV2 / 64><<<NB * (NV2 / 16), 256, 0, stream>>>(v1, nbr2);
    feat_gemm<C1, 8 * C2><<<(NB * NV2 / 64) * (8 * C2 / 64), 256, 0, stream>>>(fm1p, w2w, w2b, feat2);
    opnd2_gather<<<NB * NV2 / 4, 256, 0, stream>>>(v1, nbr2, feat2, w2d, fm2);
    pool2_kernel<<<32, 256, 0, stream>>>(nbr2, fm2, out, pa2);
}

// Round 29
// 281.376 us; speedup vs baseline: 20.0252x; 1.3712x over previous
//
#include <hip/hip_runtime.h>
#include <hip/hip_bf16.h>
#include <stdint.h>
#include <string.h>

// ---------------------------------------------------------------------------
// Problem constants
// ---------------------------------------------------------------------------
#define NB   8
#define NV   2048
#define NN   20      // NEIGHBOR_NUM
#define SUP  7       // SUPPORT
#define K0   32
#define C1   64
#define C2   256
#define NV2  256     // vertices after pooling 1
#define NP2  16      // vertices after pooling 2
#define COLL_CAP 512

// ---------------------------------------------------------------------------
// Permutations (proven R21..R28)
// ---------------------------------------------------------------------------
typedef unsigned __int128 u128;

struct CPcg { u128 state; u128 inc; bool has32; uint32_t cached; };

constexpr u128 PCG_MULT = (((u128)2549297995355413924ULL) << 64) | 4865540595714422341ULL;

constexpr uint64_t c_rotr64(uint64_t v, unsigned r) {
    return (v >> (r & 63u)) | (v << ((64u - r) & 63u));
}
constexpr uint64_t pcg_next64(CPcg& g) {
    g.state = g.state * PCG_MULT + g.inc;
    uint64_t hi = (uint64_t)(g.state >> 64);
    uint64_t lo = (uint64_t)g.state;
    return c_rotr64(hi ^ lo, (unsigned)(hi >> 58));
}
constexpr uint32_t pcg_next32(CPcg& g) {
    if (g.has32) { g.has32 = false; return g.cached; }
    uint64_t n = pcg_next64(g);
    g.has32 = true;
    g.cached = (uint32_t)(n >> 32);
    return (uint32_t)n;
}
constexpr uint64_t rand_interval(CPcg& g, uint64_t mx) {
    if (mx == 0) return 0;
    uint64_t mask = mx;
    mask |= mask >> 1; mask |= mask >> 2; mask |= mask >> 4;
    mask |= mask >> 8; mask |= mask >> 16; mask |= mask >> 32;
    uint64_t v = 0;
    while ((v = ((uint64_t)pcg_next32(g) & mask)) > mx) {
    }
    return v;
}
constexpr uint32_t hashmix(uint32_t value, uint32_t& hc) {
    value ^= hc; hc *= 0x931e8875u; value *= hc; value ^= value >> 16; return value;
}
constexpr uint32_t mixpool(uint32_t x, uint32_t y) {
    uint32_t r = (x * 0xca01f9ddu) - (y * 0x4973f715u);
    r ^= r >> 16; return r;
}
constexpr CPcg make_rng(uint32_t entropy) {
    uint32_t pool[4] = {0, 0, 0, 0};
    uint32_t hc = 0x43b0d7e5u;
    for (int i = 0; i < 4; i++) {
        uint32_t v = (i == 0) ? entropy : 0u;
        pool[i] = hashmix(v, hc);
    }
    for (int isrc = 0; isrc < 4; isrc++)
        for (int idst = 0; idst < 4; idst++)
            if (isrc != idst) pool[idst] = mixpool(pool[idst], hashmix(pool[isrc], hc));
    uint32_t w[8] = {};
    uint32_t hb = 0x8b51f9ddu;
    for (int i = 0; i < 8; i++) {
        uint32_t dv = pool[i & 3];
        dv ^= hb; hb *= 0x58f38dedu; dv *= hb; dv ^= dv >> 16; w[i] = dv;
    }
    uint64_t sd[4] = {};
    for (int k = 0; k < 4; k++) sd[k] = (uint64_t)w[2 * k] | ((uint64_t)w[2 * k + 1] << 32);
    u128 s = (((u128)sd[0]) << 64) | sd[1];
    u128 iq = (((u128)sd[2]) << 64) | sd[3];
    CPcg g{};
    g.state = 0;
    g.inc = (iq << 1) | 1;
    g.state = g.state * PCG_MULT + g.inc;
    g.state += s;
    g.state = g.state * PCG_MULT + g.inc;
    g.has32 = false; g.cached = 0;
    return g;
}

struct PermOut { int p1[256]; int p2[16]; };

constexpr PermOut compute_perms() {
    PermOut o{};
    {
        CPcg g = make_rng(1u);
        int arr[2048] = {};
        for (int i = 0; i < 2048; i++) arr[i] = i;
        for (int i = 2047; i >= 1; i--) {
            int j = (int)rand_interval(g, (uint64_t)i);
            int t = arr[i]; arr[i] = arr[j]; arr[j] = t;
        }
        for (int i = 0; i < 256; i++) o.p1[i] = arr[i];
    }
    {
        CPcg g = make_rng(2u);
        int arr[256] = {};
        for (int i = 0; i < 256; i++) arr[i] = i;
        for (int i = 255; i >= 1; i--) {
            int j = (int)rand_interval(g, (uint64_t)i);
            int t = arr[i]; arr[i] = arr[j]; arr[j] = t;
        }
        for (int i = 0; i < 16; i++) o.p2[i] = arr[i];
    }
    return o;
}

struct PermArg1 { int v[256]; };
struct PermArg2 { int v[16]; };

// ---------------------------------------------------------------------------
// K0: v2 (outputs[0]) = verts[:, p1[p2[j]], :] — f32
// ---------------------------------------------------------------------------
__global__ __launch_bounds__(384) void v2_kernel(const float* __restrict__ verts,
                                                 float* __restrict__ out,
                                                 PermArg2 cidx) {
    int t = threadIdx.x;
    if (t < NB * NP2 * 3) {
        int b = t / (NP2 * 3);
        int rem = t - b * (NP2 * 3);
        int j = rem / 3;
        int c = rem - j * 3;
        out[t] = verts[(b * NV + cidx.v[j]) * 3 + c];
    }
}

// ---------------------------------------------------------------------------
// KNN via linear-bucket select (R26, proven)
// ---------------------------------------------------------------------------
template<int N, int CPL>
__global__ __launch_bounds__(256) void knn_bucket_kernel(const float* __restrict__ verts,
                                                         int* __restrict__ nbr) {
    __shared__ float sv[N * 3];
    __shared__ int hist[4][256];
    __shared__ unsigned long long coll[4][COLL_CAP];
    __shared__ int cnt[4];

    constexpr int RPB = 16;
    int bpb = N / RPB;
    int b = blockIdx.x / bpb;
    int rbase = (blockIdx.x % bpb) * RPB;

    const float* vb = verts + (size_t)b * N * 3;
    for (int t = threadIdx.x; t < N * 3; t += 256) sv[t] = vb[t];
    __syncthreads();

    int wid = threadIdx.x >> 6, lane = threadIdx.x & 63;
    int* myhist = hist[wid];
    unsigned long long* mycoll = coll[wid];

    for (int rr = 0; rr < 4; rr++) {
        int i = rbase + wid * 4 + rr;
        float vx = sv[i * 3 + 0], vy = sv[i * 3 + 1], vz = sv[i * 3 + 2];
        float qi = vx * vx + vy * vy + vz * vz;

        unsigned key[CPL];
        unsigned lmin = 0xFFFFFFFFu, lmax = 0u;
        #pragma unroll
        for (int t = 0; t < CPL; t++) {
            int j = lane + 64 * t;
            float xj = sv[j * 3 + 0], yj = sv[j * 3 + 1], zj = sv[j * 3 + 2];
            float inner = vx * xj + vy * yj + vz * zj;
            float qj = xj * xj + yj * yj + zj * zj;
            float dist = (-2.0f * inner + qi) + qj;
            unsigned u = __float_as_uint(dist);
            u = (u & 0x80000000u) ? ~u : (u | 0x80000000u);
            if (j == i) u = 0xFFFFFFFFu;
            key[t] = u;
            if (u != 0xFFFFFFFFu) {
                lmin = (u < lmin) ? u : lmin;
                lmax = (u > lmax) ? u : lmax;
            }
        }
        #pragma unroll
        for (int off = 32; off >= 1; off >>= 1) {
            unsigned o1 = (unsigned)__shfl_xor((int)lmin, off);
            unsigned o2 = (unsigned)__shfl_xor((int)lmax, off);
            lmin = (o1 < lmin) ? o1 : lmin;
            lmax = (o2 > lmax) ? o2 : lmax;
        }
        float scale = (lmax > lmin) ? 255.0f / (float)(lmax - lmin) : 0.0f;

        #pragma unroll
        for (int q = 0; q < 4; q++) myhist[lane * 4 + q] = 0;
        __asm__ volatile("s_waitcnt lgkmcnt(0)" ::: "memory");
        int bins[CPL];
        #pragma unroll
        for (int t = 0; t < CPL; t++) {
            int bi = (key[t] == 0xFFFFFFFFu) ? 255
                     : (int)((float)(key[t] - lmin) * scale);
            bi = (bi > 255) ? 255 : bi;
            bins[t] = bi;
            atomicAdd(&myhist[bi], 1);
        }
        __asm__ volatile("s_waitcnt lgkmcnt(0)" ::: "memory");

        int h0 = myhist[lane * 4 + 0];
        int h1 = myhist[lane * 4 + 1];
        int h2 = myhist[lane * 4 + 2];
        int h3 = myhist[lane * 4 + 3];
        int s = h0 + h1 + h2 + h3;
        int cum = s;
        #pragma unroll
        for (int off = 1; off < 64; off <<= 1) {
            int v = __shfl_up(cum, off);
            if (lane >= off) cum += v;
        }
        unsigned long long bal = __ballot(cum >= NN);
        int L = __ffsll((long long)bal) - 1;
        int baseL = __shfl(cum, L) - __shfl(s, L);
        int g0 = __shfl(h0, L), g1 = __shfl(h1, L), g2 = __shfl(h2, L);
        int B;
        if (baseL + g0 >= NN)            B = 4 * L + 0;
        else if (baseL + g0 + g1 >= NN)  B = 4 * L + 1;
        else if (baseL + g0 + g1 + g2 >= NN) B = 4 * L + 2;
        else                              B = 4 * L + 3;

        if (lane == 0) cnt[wid] = 0;
        __asm__ volatile("s_waitcnt lgkmcnt(0)" ::: "memory");
        #pragma unroll
        for (int t = 0; t < CPL; t++) {
            if (bins[t] <= B) {
                int pos = atomicAdd(&cnt[wid], 1);
                if (pos < COLL_CAP)
                    mycoll[pos] = ((unsigned long long)key[t] << 32) | (unsigned)(lane + 64 * t);
            }
        }
        __asm__ volatile("s_waitcnt lgkmcnt(0)" ::: "memory");
        int count = cnt[wid];
        if (count > COLL_CAP) count = COLL_CAP;

        int* dst = nbr + ((size_t)b * N + i) * NN;
        for (int e = lane; e < count; e += 64) {
            unsigned long long me = mycoll[e];
            int rank = 0;
            for (int m = 0; m < count; m++) rank += (mycoll[m] < me);
            if (rank < NN) dst[rank] = (int)(me & 0xFFFFFFFFull);
        }
    }
}

// ---------------------------------------------------------------------------
// K2: operator3d + relu -> fm0 (8,2048,32). One thread per vertex.
// ---------------------------------------------------------------------------
__global__ __launch_bounds__(256) void op3d_kernel(const float* __restrict__ verts,
                                                   const int* __restrict__ nbr,
                                                   const float* __restrict__ w0w,
                                                   const float* __restrict__ w0d,
                                                   float* __restrict__ fm0) {
    __shared__ float swd[3 * SUP * K0];
    __shared__ float sww[SUP * K0];
    for (int t = threadIdx.x; t < 3 * SUP * K0; t += 256) swd[t] = w0d[t];
    for (int t = threadIdx.x; t < SUP * K0; t += 256) sww[t] = w0w[t];
    __syncthreads();

    int gid = blockIdx.x * 256 + threadIdx.x;
    int b = gid >> 11, v = gid & (NV - 1);
    const float* vb = verts + b * NV * 3;
    float vx = vb[v * 3], vy = vb[v * 3 + 1], vz = vb[v * 3 + 2];

    const int* nb = nbr + gid * NN;
    float dx[NN], dy[NN], dz[NN];
    #pragma unroll
    for (int n = 0; n < NN; n++) {
        int j = nb[n];
        dx[n] = vb[j * 3 + 0] - vx;
        dy[n] = vb[j * 3 + 1] - vy;
        dz[n] = vb[j * 3 + 2] - vz;
    }
    float* out = fm0 + gid * K0;
    #pragma unroll 1
    for (int k = 0; k < K0; k++) {
        float acc = 0.f;
        #pragma unroll
        for (int s = 0; s < SUP; s++) {
            float w0 = swd[0 * 224 + s * K0 + k];
            float w1 = swd[1 * 224 + s * K0 + k];
            float w2 = swd[2 * 224 + s * K0 + k];
            float m = 0.f;
            #pragma unroll
            for (int n = 0; n < NN; n++) {
                float t = dx[n] * w0 + dy[n] * w1 + dz[n] * w2;
                t = fmaxf(t, 0.f);
                m = fmaxf(m, t);
            }
            acc += m * sww[s * K0 + k];
        }
        out[k] = fmaxf(acc, 0.f);
    }
}

// ---------------------------------------------------------------------------
// feat GEMM (R27, proven)
// ---------------------------------------------------------------------------
template<int K, int N>
__global__ __launch_bounds__(256) void feat_gemm(const float* __restrict__ fm,
                                                 const float* __restrict__ w,
                                                 const float* __restrict__ bias,
                                                 float* __restrict__ feat) {
    __shared__ float sf[64][K];
    __shared__ float swt[K][64];
    int cb = blockIdx.x % (N / 64), rb = blockIdx.x / (N / 64);
    int r0 = rb * 64, c0 = cb * 64;

    for (int t = threadIdx.x; t < 64 * K; t += 256)
        sf[t / K][t % K] = fm[(size_t)(r0 + t / K) * K + (t % K)];
    for (int t = threadIdx.x; t < K * 64; t += 256)
        swt[t >> 6][t & 63] = w[(size_t)(t >> 6) * N + c0 + (t & 63)];
    __syncthreads();

    int col = threadIdx.x & 63, rg = threadIdx.x >> 6;
    float bv = bias[c0 + col];
    float acc[16];
    #pragma unroll
    for (int r = 0; r < 16; r++) acc[r] = bv;
    #pragma unroll 1
    for (int k = 0; k < K; k++) {
        float wk = swt[k][col];
        #pragma unroll
        for (int r = 0; r < 16; r++) acc[r] += sf[rg * 16 + r][k] * wk;
    }
    #pragma unroll
    for (int r = 0; r < 16; r++)
        feat[(size_t)(r0 + rg * 16 + r) * N + c0 + col] = acc[r];
}

// ---------------------------------------------------------------------------
// opnd1 gather-max (n-outer, unroll 4 for load pipelining). fmax over n is
// order-exact; ss-sum order unchanged => bit-identical.
// ---------------------------------------------------------------------------
__global__ __launch_bounds__(256) void opnd1_gather(const float* __restrict__ verts,
                                                    const int* __restrict__ nbr,
                                                    const float* __restrict__ feat1,
                                                    const float* __restrict__ w1d,
                                                    float* __restrict__ fm1) {
    __shared__ float swd[3 * SUP * C1];
    for (int t = threadIdx.x; t < 3 * SUP * C1; t += 256) swd[t] = w1d[t];
    __syncthreads();

    int wid = threadIdx.x >> 6, lane = threadIdx.x & 63;
    int vtx = blockIdx.x * 4 + wid;
    int b = vtx >> 11, v = vtx & (NV - 1);
    const float* vb = verts + b * NV * 3;
    const int* nb = nbr + vtx * NN;
    float vx = vb[v * 3], vy = vb[v * 3 + 1], vz = vb[v * 3 + 2];

    float w0r[SUP], w1r[SUP], w2r[SUP];
    #pragma unroll
    for (int ss = 0; ss < SUP; ss++) {
        w0r[ss] = swd[0 * (SUP * C1) + ss * C1 + lane];
        w1r[ss] = swd[1 * (SUP * C1) + ss * C1 + lane];
        w2r[ss] = swd[2 * (SUP * C1) + ss * C1 + lane];
    }

    const float* fb = feat1 + (size_t)b * NV * (8 * C1);
    float m[SUP];
    #pragma unroll
    for (int ss = 0; ss < SUP; ss++) m[ss] = -3.4e38f;

    #pragma unroll 4
    for (int n = 0; n < NN; n++) {
        int j = nb[n];
        float dx = vb[j * 3 + 0] - vx;
        float dy = vb[j * 3 + 1] - vy;
        float dz = vb[j * 3 + 2] - vz;
        const float* row = fb + (size_t)j * (8 * C1) + C1 + lane;
        #pragma unroll
        for (int ss = 0; ss < SUP; ss++) {
            float th = fmaxf(dx * w0r[ss] + dy * w1r[ss] + dz * w2r[ss], 0.f);
            m[ss] = fmaxf(m[ss], th * row[ss * C1]);
        }
    }
    float fcen = fb[(size_t)v * (8 * C1) + lane];
    float total = 0.f;
    #pragma unroll
    for (int ss = 0; ss < SUP; ss++) total += m[ss];
    fm1[vtx * C1 + lane] = fmaxf(fcen + total, 0.f);
}

// ---------------------------------------------------------------------------
// opnd2 gather-max: one wave per (vertex, jj) — 4x the waves of R28; n-loop
// unrolled 4 for load pipelining. -> fm2 (+relu)
// ---------------------------------------------------------------------------
__global__ __launch_bounds__(256) void opnd2_gather(const float* __restrict__ v1,
                                                    const int* __restrict__ nbr2,
                                                    const float* __restrict__ feat2,
                                                    const float* __restrict__ w2d,
                                                    float* __restrict__ fm2) {
    __shared__ float swd[3 * SUP * C2];
    for (int t = threadIdx.x; t < 3 * SUP * C2; t += 256) swd[t] = w2d[t];
    __syncthreads();

    int jj = threadIdx.x >> 6, lane = threadIdx.x & 63;
    int vtx = blockIdx.x;                 // one vertex per block, 4 jj-waves
    int b = vtx >> 8, v = vtx & (NV2 - 1);
    const float* vb = v1 + b * NV2 * 3;
    const int* nb = nbr2 + vtx * NN;
    float vx = vb[v * 3], vy = vb[v * 3 + 1], vz = vb[v * 3 + 2];

    int cj = jj * 64 + lane;
    float w0r[SUP], w1r[SUP], w2r[SUP];
    #pragma unroll
    for (int ss = 0; ss < SUP; ss++) {
        w0r[ss] = swd[0 * (SUP * C2) + ss * C2 + cj];
        w1r[ss] = swd[1 * (SUP * C2) + ss * C2 + cj];
        w2r[ss] = swd[2 * (SUP * C2) + ss * C2 + cj];
    }
    const float* fb = feat2 + (size_t)b * NV2 * (8 * C2);

    float m[SUP];
    #pragma unroll
    for (int ss = 0; ss < SUP; ss++) m[ss] = -3.4e38f;

    #pragma unroll 4
    for (int n = 0; n < NN; n++) {
        int j = nb[n];
        float dx = vb[j * 3 + 0] - vx;
        float dy = vb[j * 3 + 1] - vy;
        float dz = vb[j * 3 + 2] - vz;
        const float* row = fb + (size_t)j * (8 * C2) + C2 + cj;
        #pragma unroll
        for (int ss = 0; ss < SUP; ss++) {
            float th = fmaxf(dx * w0r[ss] + dy * w1r[ss] + dz * w2r[ss], 0.f);
            m[ss] = fmaxf(m[ss], th * row[ss * C2]);
        }
    }
    float total = 0.f;
    #pragma unroll
    for (int ss = 0; ss < SUP; ss++) total += m[ss];
    float fcen = fb[(size_t)v * (8 * C2) + cj];
    fm2[(size_t)vtx * C2 + cj] = fmaxf(fcen + total, 0.f);
}

// ---------------------------------------------------------------------------
// K5: pooling 1 -> v1, fm1p. One wave per sampled vertex.
// ---------------------------------------------------------------------------
__global__ __launch_bounds__(256) void pool1_kernel(const float* __restrict__ verts,
                                                    const int* __restrict__ nbr1,
                                                    const float* __restrict__ fm1,
                                                    float* __restrict__ v1,
                                                    float* __restrict__ fm1p,
                                                    PermArg1 pa) {
    int wid = threadIdx.x >> 6, lane = threadIdx.x & 63;
    int gid = blockIdx.x * 4 + wid;
    int b = gid >> 8, p = gid & 255;
    int sv = pa.v[p];
    const int* nb = nbr1 + (b * NV + sv) * NN;
    float m = -3.4e38f;
    #pragma unroll
    for (int n = 0; n < 8; n++) {
        m = fmaxf(m, fm1[(b * NV + nb[n]) * C1 + lane]);
    }
    fm1p[gid * C1 + lane] = m;
    if (lane < 3) v1[gid * 3 + lane] = verts[(b * NV + sv) * 3 + lane];
}

// ---------------------------------------------------------------------------
// K9: pooling 2 -> fm3 (outputs[1]) — f32
// ---------------------------------------------------------------------------
__global__ __launch_bounds__(256) void pool2_kernel(const int* __restrict__ nbr2,
                                                    const float* __restrict__ fm2,
                                                    float* __restrict__ out,
                                                    PermArg2 pa) {
    int wid = threadIdx.x >> 6, lane = threadIdx.x & 63;
    int gid = blockIdx.x * 4 + wid;
    int b = gid >> 4, p = gid & 15;
    int sv = pa.v[p];
    const int* nb = nbr2 + (b * NV2 + sv) * NN;
    #pragma unroll 1
    for (int jj = 0; jj < 4; jj++) {
        int c = lane + jj * 64;
        float m = -3.4e38f;
        #pragma unroll
        for (int n = 0; n < 16; n++) {
            m = fmaxf(m, fm2[(b * NV2 + nb[n]) * C2 + c]);
        }
        out[NB * NP2 * 3 + gid * C2 + c] = m;
    }
}

// ---------------------------------------------------------------------------
// Launch
// ---------------------------------------------------------------------------
extern "C" void kernel_launch(void* const* d_in, const int* in_sizes, int n_in,
                              void* d_out, int out_size, void* d_ws, size_t ws_size,
                              hipStream_t stream) {
    (void)in_sizes; (void)n_in; (void)out_size; (void)ws_size;
    const float* verts = (const float*)d_in[0];
    const float* w0w = (const float*)d_in[1];
    const float* w0d = (const float*)d_in[2];
    const float* w1w = (const float*)d_in[3];
    const float* w1b = (const float*)d_in[4];
    const float* w1d = (const float*)d_in[5];
    const float* w2w = (const float*)d_in[6];
    const float* w2b = (const float*)d_in[7];
    const float* w2d = (const float*)d_in[8];
    float* out = (float*)d_out;

    static const PermOut perms = compute_perms();

    PermArg1 pa1;
    PermArg2 pa2, pac;
    memcpy(pa1.v, perms.p1, sizeof(pa1.v));
    memcpy(pa2.v, perms.p2, sizeof(pa2.v));
    for (int j = 0; j < 16; j++) pac.v[j] = perms.p1[perms.p2[j]];

    char* ws = (char*)d_ws;
    size_t off = 0;
    auto alloc = [&](size_t bytes) -> void* {
        void* p = ws + off;
        off += (bytes + 255) & ~(size_t)255;
        return p;
    };
    int*   nbr1  = (int*)  alloc((size_t)NB * NV * NN * 4);
    float* fm0   = (float*)alloc((size_t)NB * NV * K0 * 4);
    float* feat1 = (float*)alloc((size_t)NB * NV * 8 * C1 * 4);
    float* fm1   = (float*)alloc((size_t)NB * NV * C1 * 4);
    float* v1    = (float*)alloc((size_t)NB * NV2 * 3 * 4);
    float* fm1p  = (float*)alloc((size_t)NB * NV2 * C1 * 4);
    int*   nbr2  = (int*)  alloc((size_t)NB * NV2 * NN * 4);
    float* feat2 = (float*)alloc((size_t)NB * NV2 * 8 * C2 * 4);
    float* fm2   = (float*)alloc((size_t)NB * NV2 * C2 * 4);

    v2_kernel<<<1, 384, 0, stream>>>(verts, out, pac);
    knn_bucket_kernel<NV, NV / 64><<<NB * (NV / 16), 256, 0, stream>>>(verts, nbr1);
    op3d_kernel<<<64, 256, 0, stream>>>(verts, nbr1, w0w, w0d, fm0);
    feat_gemm<K0, 8 * C1><<<(NB * NV / 64) * (8 * C1 / 64), 256, 0, stream>>>(fm0, w1w, w1b, feat1);
    opnd1_gather<<<NB * NV / 4, 256, 0, stream>>>(verts, nbr1, feat1, w1d, fm1);
    pool1_kernel<<<NB * NV2 / 4, 256, 0, stream>>>(verts, nbr1, fm1, v1, fm1p, pa1);
    knn_bucket_kernel<NV2, NV2 / 64><<<NB * (NV2 / 16), 256, 0, stream>>>(v1, nbr2);
    feat_gemm<C1, 8 * C2><<<(NB * NV2 / 64) * (8 * C2 / 64), 256, 0, stream>>>(fm1p, w2w, w2b, feat2);
    opnd2_gather<<<NB * NV2, 256, 0, stream>>>(v1, nbr2, feat2, w2d, fm2);
    pool2_kernel<<<32, 256, 0, stream>>>(nbr2, fm2, out, pa2);
}

// Round 30
// 247.887 us; speedup vs baseline: 22.7306x; 1.1351x over previous
//
#include <hip/hip_runtime.h>
#include <hip/hip_bf16.h>
#include <stdint.h>
#include <string.h>

// ---------------------------------------------------------------------------
// Problem constants
// ---------------------------------------------------------------------------
#define NB   8
#define NV   2048
#define NN   20      // NEIGHBOR_NUM
#define SUP  7       // SUPPORT
#define K0   32
#define C1   64
#define C2   256
#define NV2  256     // vertices after pooling 1
#define NP2  16      // vertices after pooling 2
#define COLL_CAP 320

// ---------------------------------------------------------------------------
// Permutations (proven R21..R29)
// ---------------------------------------------------------------------------
typedef unsigned __int128 u128;

struct CPcg { u128 state; u128 inc; bool has32; uint32_t cached; };

constexpr u128 PCG_MULT = (((u128)2549297995355413924ULL) << 64) | 4865540595714422341ULL;

constexpr uint64_t c_rotr64(uint64_t v, unsigned r) {
    return (v >> (r & 63u)) | (v << ((64u - r) & 63u));
}
constexpr uint64_t pcg_next64(CPcg& g) {
    g.state = g.state * PCG_MULT + g.inc;
    uint64_t hi = (uint64_t)(g.state >> 64);
    uint64_t lo = (uint64_t)g.state;
    return c_rotr64(hi ^ lo, (unsigned)(hi >> 58));
}
constexpr uint32_t pcg_next32(CPcg& g) {
    if (g.has32) { g.has32 = false; return g.cached; }
    uint64_t n = pcg_next64(g);
    g.has32 = true;
    g.cached = (uint32_t)(n >> 32);
    return (uint32_t)n;
}
constexpr uint64_t rand_interval(CPcg& g, uint64_t mx) {
    if (mx == 0) return 0;
    uint64_t mask = mx;
    mask |= mask >> 1; mask |= mask >> 2; mask |= mask >> 4;
    mask |= mask >> 8; mask |= mask >> 16; mask |= mask >> 32;
    uint64_t v = 0;
    while ((v = ((uint64_t)pcg_next32(g) & mask)) > mx) {
    }
    return v;
}
constexpr uint32_t hashmix(uint32_t value, uint32_t& hc) {
    value ^= hc; hc *= 0x931e8875u; value *= hc; value ^= value >> 16; return value;
}
constexpr uint32_t mixpool(uint32_t x, uint32_t y) {
    uint32_t r = (x * 0xca01f9ddu) - (y * 0x4973f715u);
    r ^= r >> 16; return r;
}
constexpr CPcg make_rng(uint32_t entropy) {
    uint32_t pool[4] = {0, 0, 0, 0};
    uint32_t hc = 0x43b0d7e5u;
    for (int i = 0; i < 4; i++) {
        uint32_t v = (i == 0) ? entropy : 0u;
        pool[i] = hashmix(v, hc);
    }
    for (int isrc = 0; isrc < 4; isrc++)
        for (int idst = 0; idst < 4; idst++)
            if (isrc != idst) pool[idst] = mixpool(pool[idst], hashmix(pool[isrc], hc));
    uint32_t w[8] = {};
    uint32_t hb = 0x8b51f9ddu;
    for (int i = 0; i < 8; i++) {
        uint32_t dv = pool[i & 3];
        dv ^= hb; hb *= 0x58f38dedu; dv *= hb; dv ^= dv >> 16; w[i] = dv;
    }
    uint64_t sd[4] = {};
    for (int k = 0; k < 4; k++) sd[k] = (uint64_t)w[2 * k] | ((uint64_t)w[2 * k + 1] << 32);
    u128 s = (((u128)sd[0]) << 64) | sd[1];
    u128 iq = (((u128)sd[2]) << 64) | sd[3];
    CPcg g{};
    g.state = 0;
    g.inc = (iq << 1) | 1;
    g.state = g.state * PCG_MULT + g.inc;
    g.state += s;
    g.state = g.state * PCG_MULT + g.inc;
    g.has32 = false; g.cached = 0;
    return g;
}

struct PermOut { int p1[256]; int p2[16]; };

constexpr PermOut compute_perms() {
    PermOut o{};
    {
        CPcg g = make_rng(1u);
        int arr[2048] = {};
        for (int i = 0; i < 2048; i++) arr[i] = i;
        for (int i = 2047; i >= 1; i--) {
            int j = (int)rand_interval(g, (uint64_t)i);
            int t = arr[i]; arr[i] = arr[j]; arr[j] = t;
        }
        for (int i = 0; i < 256; i++) o.p1[i] = arr[i];
    }
    {
        CPcg g = make_rng(2u);
        int arr[256] = {};
        for (int i = 0; i < 256; i++) arr[i] = i;
        for (int i = 255; i >= 1; i--) {
            int j = (int)rand_interval(g, (uint64_t)i);
            int t = arr[i]; arr[i] = arr[j]; arr[j] = t;
        }
        for (int i = 0; i < 16; i++) o.p2[i] = arr[i];
    }
    return o;
}

struct PermArg1 { int v[256]; };
struct PermArg2 { int v[16]; };

// ---------------------------------------------------------------------------
// K0: v2 (outputs[0]) = verts[:, p1[p2[j]], :] — f32
// ---------------------------------------------------------------------------
__global__ __launch_bounds__(384) void v2_kernel(const float* __restrict__ verts,
                                                 float* __restrict__ out,
                                                 PermArg2 cidx) {
    int t = threadIdx.x;
    if (t < NB * NP2 * 3) {
        int b = t / (NP2 * 3);
        int rem = t - b * (NP2 * 3);
        int j = rem / 3;
        int c = rem - j * 3;
        out[t] = verts[(b * NV + cidx.v[j]) * 3 + c];
    }
}

// ---------------------------------------------------------------------------
// KNN via linear-bucket select. R30: bins recomputed (not stored), COLL_CAP
// 320, launch_bounds(256,4) to cap VGPR at 128 -> ~2x occupancy.
// ---------------------------------------------------------------------------
template<int N, int CPL>
__global__ __launch_bounds__(256, 4) void knn_bucket_kernel(const float* __restrict__ verts,
                                                            int* __restrict__ nbr) {
    __shared__ float sv[N * 3];
    __shared__ int hist[4][256];
    __shared__ unsigned long long coll[4][COLL_CAP];
    __shared__ int cnt[4];

    constexpr int RPB = 16;
    int bpb = N / RPB;
    int b = blockIdx.x / bpb;
    int rbase = (blockIdx.x % bpb) * RPB;

    const float* vb = verts + (size_t)b * N * 3;
    for (int t = threadIdx.x; t < N * 3; t += 256) sv[t] = vb[t];
    __syncthreads();

    int wid = threadIdx.x >> 6, lane = threadIdx.x & 63;
    int* myhist = hist[wid];
    unsigned long long* mycoll = coll[wid];

    for (int rr = 0; rr < 4; rr++) {
        int i = rbase + wid * 4 + rr;
        float vx = sv[i * 3 + 0], vy = sv[i * 3 + 1], vz = sv[i * 3 + 2];
        float qi = vx * vx + vy * vy + vz * vz;

        unsigned key[CPL];
        unsigned lmin = 0xFFFFFFFFu, lmax = 0u;
        #pragma unroll
        for (int t = 0; t < CPL; t++) {
            int j = lane + 64 * t;
            float xj = sv[j * 3 + 0], yj = sv[j * 3 + 1], zj = sv[j * 3 + 2];
            float inner = vx * xj + vy * yj + vz * zj;
            float qj = xj * xj + yj * yj + zj * zj;
            float dist = (-2.0f * inner + qi) + qj;
            unsigned u = __float_as_uint(dist);
            u = (u & 0x80000000u) ? ~u : (u | 0x80000000u);
            if (j == i) u = 0xFFFFFFFFu;
            key[t] = u;
            if (u != 0xFFFFFFFFu) {
                lmin = (u < lmin) ? u : lmin;
                lmax = (u > lmax) ? u : lmax;
            }
        }
        #pragma unroll
        for (int off = 32; off >= 1; off >>= 1) {
            unsigned o1 = (unsigned)__shfl_xor((int)lmin, off);
            unsigned o2 = (unsigned)__shfl_xor((int)lmax, off);
            lmin = (o1 < lmin) ? o1 : lmin;
            lmax = (o2 > lmax) ? o2 : lmax;
        }
        float scale = (lmax > lmin) ? 255.0f / (float)(lmax - lmin) : 0.0f;

        #pragma unroll
        for (int q = 0; q < 4; q++) myhist[lane * 4 + q] = 0;
        __asm__ volatile("s_waitcnt lgkmcnt(0)" ::: "memory");
        #pragma unroll
        for (int t = 0; t < CPL; t++) {
            int bi = (key[t] == 0xFFFFFFFFu) ? 255
                     : (int)((float)(key[t] - lmin) * scale);
            bi = (bi > 255) ? 255 : bi;
            atomicAdd(&myhist[bi], 1);
        }
        __asm__ volatile("s_waitcnt lgkmcnt(0)" ::: "memory");

        int h0 = myhist[lane * 4 + 0];
        int h1 = myhist[lane * 4 + 1];
        int h2 = myhist[lane * 4 + 2];
        int h3 = myhist[lane * 4 + 3];
        int s = h0 + h1 + h2 + h3;
        int cum = s;
        #pragma unroll
        for (int off = 1; off < 64; off <<= 1) {
            int v = __shfl_up(cum, off);
            if (lane >= off) cum += v;
        }
        unsigned long long bal = __ballot(cum >= NN);
        int L = __ffsll((long long)bal) - 1;
        int baseL = __shfl(cum, L) - __shfl(s, L);
        int g0 = __shfl(h0, L), g1 = __shfl(h1, L), g2 = __shfl(h2, L);
        int B;
        if (baseL + g0 >= NN)            B = 4 * L + 0;
        else if (baseL + g0 + g1 >= NN)  B = 4 * L + 1;
        else if (baseL + g0 + g1 + g2 >= NN) B = 4 * L + 2;
        else                              B = 4 * L + 3;

        if (lane == 0) cnt[wid] = 0;
        __asm__ volatile("s_waitcnt lgkmcnt(0)" ::: "memory");
        #pragma unroll
        for (int t = 0; t < CPL; t++) {
            int bi = (key[t] == 0xFFFFFFFFu) ? 255
                     : (int)((float)(key[t] - lmin) * scale);
            bi = (bi > 255) ? 255 : bi;
            if (bi <= B) {
                int pos = atomicAdd(&cnt[wid], 1);
                if (pos < COLL_CAP)
                    mycoll[pos] = ((unsigned long long)key[t] << 32) | (unsigned)(lane + 64 * t);
            }
        }
        __asm__ volatile("s_waitcnt lgkmcnt(0)" ::: "memory");
        int count = cnt[wid];
        if (count > COLL_CAP) count = COLL_CAP;

        int* dst = nbr + ((size_t)b * N + i) * NN;
        for (int e = lane; e < count; e += 64) {
            unsigned long long me = mycoll[e];
            int rank = 0;
            for (int m = 0; m < count; m++) rank += (mycoll[m] < me);
            if (rank < NN) dst[rank] = (int)(me & 0xFFFFFFFFull);
        }
    }
}

// ---------------------------------------------------------------------------
// K2: operator3d + relu -> fm0 (8,2048,32). One thread per vertex.
// ---------------------------------------------------------------------------
__global__ __launch_bounds__(256) void op3d_kernel(const float* __restrict__ verts,
                                                   const int* __restrict__ nbr,
                                                   const float* __restrict__ w0w,
                                                   const float* __restrict__ w0d,
                                                   float* __restrict__ fm0) {
    __shared__ float swd[3 * SUP * K0];
    __shared__ float sww[SUP * K0];
    for (int t = threadIdx.x; t < 3 * SUP * K0; t += 256) swd[t] = w0d[t];
    for (int t = threadIdx.x; t < SUP * K0; t += 256) sww[t] = w0w[t];
    __syncthreads();

    int gid = blockIdx.x * 256 + threadIdx.x;
    int b = gid >> 11, v = gid & (NV - 1);
    const float* vb = verts + b * NV * 3;
    float vx = vb[v * 3], vy = vb[v * 3 + 1], vz = vb[v * 3 + 2];

    const int* nb = nbr + gid * NN;
    float dx[NN], dy[NN], dz[NN];
    #pragma unroll
    for (int n = 0; n < NN; n++) {
        int j = nb[n];
        dx[n] = vb[j * 3 + 0] - vx;
        dy[n] = vb[j * 3 + 1] - vy;
        dz[n] = vb[j * 3 + 2] - vz;
    }
    float* out = fm0 + gid * K0;
    #pragma unroll 1
    for (int k = 0; k < K0; k++) {
        float acc = 0.f;
        #pragma unroll
        for (int s = 0; s < SUP; s++) {
            float w0 = swd[0 * 224 + s * K0 + k];
            float w1 = swd[1 * 224 + s * K0 + k];
            float w2 = swd[2 * 224 + s * K0 + k];
            float m = 0.f;
            #pragma unroll
            for (int n = 0; n < NN; n++) {
                float t = dx[n] * w0 + dy[n] * w1 + dz[n] * w2;
                t = fmaxf(t, 0.f);
                m = fmaxf(m, t);
            }
            acc += m * sww[s * K0 + k];
        }
        out[k] = fmaxf(acc, 0.f);
    }
}

// ---------------------------------------------------------------------------
// feat GEMM (R27, proven)
// ---------------------------------------------------------------------------
template<int K, int N>
__global__ __launch_bounds__(256) void feat_gemm(const float* __restrict__ fm,
                                                 const float* __restrict__ w,
                                                 const float* __restrict__ bias,
                                                 float* __restrict__ feat) {
    __shared__ float sf[64][K];
    __shared__ float swt[K][64];
    int cb = blockIdx.x % (N / 64), rb = blockIdx.x / (N / 64);
    int r0 = rb * 64, c0 = cb * 64;

    for (int t = threadIdx.x; t < 64 * K; t += 256)
        sf[t / K][t % K] = fm[(size_t)(r0 + t / K) * K + (t % K)];
    for (int t = threadIdx.x; t < K * 64; t += 256)
        swt[t >> 6][t & 63] = w[(size_t)(t >> 6) * N + c0 + (t & 63)];
    __syncthreads();

    int col = threadIdx.x & 63, rg = threadIdx.x >> 6;
    float bv = bias[c0 + col];
    float acc[16];
    #pragma unroll
    for (int r = 0; r < 16; r++) acc[r] = bv;
    #pragma unroll 1
    for (int k = 0; k < K; k++) {
        float wk = swt[k][col];
        #pragma unroll
        for (int r = 0; r < 16; r++) acc[r] += sf[rg * 16 + r][k] * wk;
    }
    #pragma unroll
    for (int r = 0; r < 16; r++)
        feat[(size_t)(r0 + rg * 16 + r) * N + c0 + col] = acc[r];
}

// ---------------------------------------------------------------------------
// opnd1 gather-max (n-outer, unroll 4). (R28/R29, proven)
// ---------------------------------------------------------------------------
__global__ __launch_bounds__(256) void opnd1_gather(const float* __restrict__ verts,
                                                    const int* __restrict__ nbr,
                                                    const float* __restrict__ feat1,
                                                    const float* __restrict__ w1d,
                                                    float* __restrict__ fm1) {
    __shared__ float swd[3 * SUP * C1];
    for (int t = threadIdx.x; t < 3 * SUP * C1; t += 256) swd[t] = w1d[t];
    __syncthreads();

    int wid = threadIdx.x >> 6, lane = threadIdx.x & 63;
    int vtx = blockIdx.x * 4 + wid;
    int b = vtx >> 11, v = vtx & (NV - 1);
    const float* vb = verts + b * NV * 3;
    const int* nb = nbr + vtx * NN;
    float vx = vb[v * 3], vy = vb[v * 3 + 1], vz = vb[v * 3 + 2];

    float w0r[SUP], w1r[SUP], w2r[SUP];
    #pragma unroll
    for (int ss = 0; ss < SUP; ss++) {
        w0r[ss] = swd[0 * (SUP * C1) + ss * C1 + lane];
        w1r[ss] = swd[1 * (SUP * C1) + ss * C1 + lane];
        w2r[ss] = swd[2 * (SUP * C1) + ss * C1 + lane];
    }

    const float* fb = feat1 + (size_t)b * NV * (8 * C1);
    float m[SUP];
    #pragma unroll
    for (int ss = 0; ss < SUP; ss++) m[ss] = -3.4e38f;

    #pragma unroll 4
    for (int n = 0; n < NN; n++) {
        int j = nb[n];
        float dx = vb[j * 3 + 0] - vx;
        float dy = vb[j * 3 + 1] - vy;
        float dz = vb[j * 3 + 2] - vz;
        const float* row = fb + (size_t)j * (8 * C1) + C1 + lane;
        #pragma unroll
        for (int ss = 0; ss < SUP; ss++) {
            float th = fmaxf(dx * w0r[ss] + dy * w1r[ss] + dz * w2r[ss], 0.f);
            m[ss] = fmaxf(m[ss], th * row[ss * C1]);
        }
    }
    float fcen = fb[(size_t)v * (8 * C1) + lane];
    float total = 0.f;
    #pragma unroll
    for (int ss = 0; ss < SUP; ss++) total += m[ss];
    fm1[vtx * C1 + lane] = fmaxf(fcen + total, 0.f);
}

// ---------------------------------------------------------------------------
// opnd2 gather-max: one wave per (vertex, jj), unroll 4 (R29, proven)
// ---------------------------------------------------------------------------
__global__ __launch_bounds__(256) void opnd2_gather(const float* __restrict__ v1,
                                                    const int* __restrict__ nbr2,
                                                    const float* __restrict__ feat2,
                                                    const float* __restrict__ w2d,
                                                    float* __restrict__ fm2) {
    __shared__ float swd[3 * SUP * C2];
    for (int t = threadIdx.x; t < 3 * SUP * C2; t += 256) swd[t] = w2d[t];
    __syncthreads();

    int jj = threadIdx.x >> 6, lane = threadIdx.x & 63;
    int vtx = blockIdx.x;
    int b = vtx >> 8, v = vtx & (NV2 - 1);
    const float* vb = v1 + b * NV2 * 3;
    const int* nb = nbr2 + vtx * NN;
    float vx = vb[v * 3], vy = vb[v * 3 + 1], vz = vb[v * 3 + 2];

    int cj = jj * 64 + lane;
    float w0r[SUP], w1r[SUP], w2r[SUP];
    #pragma unroll
    for (int ss = 0; ss < SUP; ss++) {
        w0r[ss] = swd[0 * (SUP * C2) + ss * C2 + cj];
        w1r[ss] = swd[1 * (SUP * C2) + ss * C2 + cj];
        w2r[ss] = swd[2 * (SUP * C2) + ss * C2 + cj];
    }
    const float* fb = feat2 + (size_t)b * NV2 * (8 * C2);

    float m[SUP];
    #pragma unroll
    for (int ss = 0; ss < SUP; ss++) m[ss] = -3.4e38f;

    #pragma unroll 4
    for (int n = 0; n < NN; n++) {
        int j = nb[n];
        float dx = vb[j * 3 + 0] - vx;
        float dy = vb[j * 3 + 1] - vy;
        float dz = vb[j * 3 + 2] - vz;
        const float* row = fb + (size_t)j * (8 * C2) + C2 + cj;
        #pragma unroll
        for (int ss = 0; ss < SUP; ss++) {
            float th = fmaxf(dx * w0r[ss] + dy * w1r[ss] + dz * w2r[ss], 0.f);
            m[ss] = fmaxf(m[ss], th * row[ss * C2]);
        }
    }
    float total = 0.f;
    #pragma unroll
    for (int ss = 0; ss < SUP; ss++) total += m[ss];
    float fcen = fb[(size_t)v * (8 * C2) + cj];
    fm2[(size_t)vtx * C2 + cj] = fmaxf(fcen + total, 0.f);
}

// ---------------------------------------------------------------------------
// K5: pooling 1 -> v1, fm1p. One wave per sampled vertex.
// ---------------------------------------------------------------------------
__global__ __launch_bounds__(256) void pool1_kernel(const float* __restrict__ verts,
                                                    const int* __restrict__ nbr1,
                                                    const float* __restrict__ fm1,
                                                    float* __restrict__ v1,
                                                    float* __restrict__ fm1p,
                                                    PermArg1 pa) {
    int wid = threadIdx.x >> 6, lane = threadIdx.x & 63;
    int gid = blockIdx.x * 4 + wid;
    int b = gid >> 8, p = gid & 255;
    int sv = pa.v[p];
    const int* nb = nbr1 + (b * NV + sv) * NN;
    float m = -3.4e38f;
    #pragma unroll
    for (int n = 0; n < 8; n++) {
        m = fmaxf(m, fm1[(b * NV + nb[n]) * C1 + lane]);
    }
    fm1p[gid * C1 + lane] = m;
    if (lane < 3) v1[gid * 3 + lane] = verts[(b * NV + sv) * 3 + lane];
}

// ---------------------------------------------------------------------------
// K9: pooling 2 -> fm3 (outputs[1]) — f32
// ---------------------------------------------------------------------------
__global__ __launch_bounds__(256) void pool2_kernel(const int* __restrict__ nbr2,
                                                    const float* __restrict__ fm2,
                                                    float* __restrict__ out,
                                                    PermArg2 pa) {
    int wid = threadIdx.x >> 6, lane = threadIdx.x & 63;
    int gid = blockIdx.x * 4 + wid;
    int b = gid >> 4, p = gid & 15;
    int sv = pa.v[p];
    const int* nb = nbr2 + (b * NV2 + sv) * NN;
    #pragma unroll 1
    for (int jj = 0; jj < 4; jj++) {
        int c = lane + jj * 64;
        float m = -3.4e38f;
        #pragma unroll
        for (int n = 0; n < 16; n++) {
            m = fmaxf(m, fm2[(b * NV2 + nb[n]) * C2 + c]);
        }
        out[NB * NP2 * 3 + gid * C2 + c] = m;
    }
}

// ---------------------------------------------------------------------------
// Launch
// ---------------------------------------------------------------------------
extern "C" void kernel_launch(void* const* d_in, const int* in_sizes, int n_in,
                              void* d_out, int out_size, void* d_ws, size_t ws_size,
                              hipStream_t stream) {
    (void)in_sizes; (void)n_in; (void)out_size; (void)ws_size;
    const float* verts = (const float*)d_in[0];
    const float* w0w = (const float*)d_in[1];
    const float* w0d = (const float*)d_in[2];
    const float* w1w = (const float*)d_in[3];
    const float* w1b = (const float*)d_in[4];
    const float* w1d = (const float*)d_in[5];
    const float* w2w = (const float*)d_in[6];
    const float* w2b = (const float*)d_in[7];
    const float* w2d = (const float*)d_in[8];
    float* out = (float*)d_out;

    static const PermOut perms = compute_perms();

    PermArg1 pa1;
    PermArg2 pa2, pac;
    memcpy(pa1.v, perms.p1, sizeof(pa1.v));
    memcpy(pa2.v, perms.p2, sizeof(pa2.v));
    for (int j = 0; j < 16; j++) pac.v[j] = perms.p1[perms.p2[j]];

    char* ws = (char*)d_ws;
    size_t off = 0;
    auto alloc = [&](size_t bytes) -> void* {
        void* p = ws + off;
        off += (bytes + 255) & ~(size_t)255;
        return p;
    };
    int*   nbr1  = (int*)  alloc((size_t)NB * NV * NN * 4);
    float* fm0   = (float*)alloc((size_t)NB * NV * K0 * 4);
    float* feat1 = (float*)alloc((size_t)NB * NV * 8 * C1 * 4);
    float* fm1   = (float*)alloc((size_t)NB * NV * C1 * 4);
    float* v1    = (float*)alloc((size_t)NB * NV2 * 3 * 4);
    float* fm1p  = (float*)alloc((size_t)NB * NV2 * C1 * 4);
    int*   nbr2  = (int*)  alloc((size_t)NB * NV2 * NN * 4);
    float* feat2 = (float*)alloc((size_t)NB * NV2 * 8 * C2 * 4);
    float* fm2   = (float*)alloc((size_t)NB * NV2 * C2 * 4);

    v2_kernel<<<1, 384, 0, stream>>>(verts, out, pac);
    knn_bucket_kernel<NV, NV / 64><<<NB * (NV / 16), 256, 0, stream>>>(verts, nbr1);
    op3d_kernel<<<64, 256, 0, stream>>>(verts, nbr1, w0w, w0d, fm0);
    feat_gemm<K0, 8 * C1><<<(NB * NV / 64) * (8 * C1 / 64), 256, 0, stream>>>(fm0, w1w, w1b, feat1);
    opnd1_gather<<<NB * NV / 4, 256, 0, stream>>>(verts, nbr1, feat1, w1d, fm1);
    pool1_kernel<<<NB * NV2 / 4, 256, 0, stream>>>(verts, nbr1, fm1, v1, fm1p, pa1);
    knn_bucket_kernel<NV2, NV2 / 64><<<NB * (NV2 / 16), 256, 0, stream>>>(v1, nbr2);
    feat_gemm<C1, 8 * C2><<<(NB * NV2 / 64) * (8 * C2 / 64), 256, 0, stream>>>(fm1p, w2w, w2b, feat2);
    opnd2_gather<<<NB * NV2, 256, 0, stream>>>(v1, nbr2, feat2, w2d, fm2);
    pool2_kernel<<<32, 256, 0, stream>>>(nbr2, fm2, out, pa2);
}